// Round 8
// baseline (421.502 us; speedup 1.0000x reference)
//
#include <hip/hip_runtime.h>
#include <hip/hip_bf16.h>
#include <math.h>

typedef __hip_bfloat16 bf16;
typedef __attribute__((ext_vector_type(8))) short short8;
typedef __attribute__((ext_vector_type(4))) float f32x4;

#define B_ 512
#define T_ 10
#define N_ 50
#define H_ 200
#define E_ 10000
#define R_ 200
#define K3 600   // 3*H
#define EP_ 10048  // E_ padded to 64 for guard-free B staging

__device__ __forceinline__ float b2f(bf16 x){ return __bfloat162float(x); }
__device__ __forceinline__ float u2f(unsigned short u){
  unsigned int x = ((unsigned int)u) << 16;
  return __builtin_bit_cast(float, x);
}
// fast sigmoid/tanh: v_exp_f32 + v_rcp_f32 (~1 ulp), instead of libm calls
__device__ __forceinline__ float fsigm(float x){
  return __builtin_amdgcn_rcpf(1.f + __expf(-x));
}
__device__ __forceinline__ float ftanh(float x){
  x = fminf(15.f, fmaxf(-15.f, x));
  float e = __expf(-2.f * x);
  return (1.f - e) * __builtin_amdgcn_rcpf(1.f + e);
}

// ---------------------------------------------------------------- fused weight packs (one dispatch)
// sections by blockIdx.x:
//  [0,448)      Wn2[448][256]
//  [448,960)    Wb2[2][256][448]
//  [960,2240)   Wg2[2][640][448]
//  [2240,3520)  Wstep[2][640][256]
//  [3520,4736)  Whh2[2][608][224]
//  [4736,5760)  Abias/Agi  (side*512+b rows of 448)
//  5760         sumexp zero-init
__global__ __launch_bounds__(256) void k_packall(
    const float* __restrict__ aw_s, const float* __restrict__ aw_o,
    const float* __restrict__ sub_wih, const float* __restrict__ ob_wih,
    const float* __restrict__ sub_whh, const float* __restrict__ ob_whh,
    const float* __restrict__ ent, const float* __restrict__ rel,
    const int* __restrict__ trip,
    bf16* __restrict__ Wn2, bf16* __restrict__ Wb2, bf16* __restrict__ Wg2,
    bf16* __restrict__ Wstep, bf16* __restrict__ Whh2,
    bf16* __restrict__ Ab, bf16* __restrict__ Ag, float* __restrict__ sumexp)
{
  int bid = blockIdx.x;
  int tid = threadIdx.x;
  if (bid < 448) {
    int r = bid;
    const float* Wa = (r < 200) ? aw_s : aw_o;
    int g = (r < 200) ? r : r - 200;
    bf16* out = Wn2 + (size_t)r * 256;
    for (int k = tid; k < 256; k += 256) {
      float v = (r < 400 && k < 200) ? Wa[(size_t)g * K3 + k] : 0.f;
      out[k] = __float2bfloat16(v);
    }
  } else if (bid < 960) {
    int idx = bid - 448;
    int side = idx >> 8, r = idx & 255;
    const float* W = side ? aw_o : aw_s;
    bf16* out = Wb2 + ((size_t)side * 256 + r) * 448;
    for (int k = tid; k < 448; k += 256) {
      float v = (r < 200 && k < 400) ? W[(size_t)r * K3 + 200 + k] : 0.f;
      out[k] = __float2bfloat16(v);
    }
  } else if (bid < 2240) {
    int idx = bid - 960;
    int side = idx / 640, r = idx % 640;
    const float* W = side ? ob_wih : sub_wih;
    bf16* out = Wg2 + ((size_t)side * 640 + r) * 448;
    for (int k = tid; k < 448; k += 256) {
      float v = (r < 600 && k < 400) ? W[(size_t)r * K3 + 200 + k] : 0.f;
      out[k] = __float2bfloat16(v);
    }
  } else if (bid < 3520) {
    int idx = bid - 2240;
    int side = idx / 640, r = idx % 640;
    const float* W = side ? ob_wih : sub_wih;
    bf16* out = Wstep + ((size_t)side * 640 + r) * 256;
    for (int k = tid; k < 256; k += 256) {
      float v = (r < 600 && k < 200) ? W[(size_t)r * K3 + k] : 0.f;
      out[k] = __float2bfloat16(v);
    }
  } else if (bid < 4736) {
    int idx = bid - 3520;
    int side = idx / 608, r = idx % 608;
    const float* W = side ? ob_whh : sub_whh;
    bf16* out = Whh2 + ((size_t)side * 608 + r) * 224;
    for (int k = tid; k < 224; k += 256) {
      float v = (r < 600 && k < 200) ? W[(size_t)r * H_ + k] : 0.f;
      out[k] = __float2bfloat16(v);
    }
  } else if (bid < 5760) {
    int idx = bid - 4736;
    int side = idx >> 9, b = idx & 511;
    int ids = trip[b * 3 + (side ? 2 : 0)];
    int rid = trip[b * 3 + 1];
    size_t ro = ((size_t)side * B_ + b) * 448;
    for (int k = tid; k < 448; k += 256) {
      float vb = 0.f, vg = 0.f;
      if (k < 200) { float e = ent[(size_t)ids * H_ + k]; vb = e; vg = e; }
      else if (k < 400) {
        vb = ent[(size_t)rid * H_ + (k - 200)];
        vg = rel[(size_t)rid * H_ + (k - 200)];
      }
      Ab[ro + k] = __float2bfloat16(vb);
      Ag[ro + k] = __float2bfloat16(vg);
    }
  } else {
    for (int i = tid; i < 2 * B_; i += 256) sumexp[i] = 0.f;
  }
}

// ---------------------------------------------------------------- pred-weight bf16 prepack
// Wlin[side][EP_][640]: rows<E_ = W[r][0:600], rest 0. side0=lin_ob_w, side1=lin_sub_w.
__global__ __launch_bounds__(256) void k_pack_lin(
    const float* __restrict__ W0, const float* __restrict__ W1, bf16* __restrict__ Wlin)
{
  int row = blockIdx.x, side = blockIdx.y;
  const float* W = side ? W1 : W0;
  bf16* out = Wlin + ((size_t)side * EP_ + row) * 640;
  for (int k = threadIdx.x; k < 640; k += 256) {
    float v = (row < E_ && k < K3) ? W[(size_t)row * K3 + k] : 0.f;
    out[k] = __float2bfloat16(v);
  }
}

// ---------------------------------------------------------------- generic MFMA GEMM
// C[m][n] = sum_k A[m][k]*B[n][k] (+ bias[n]); tile M=128, N=64, BK=64.
template<bool OUTBF, bool AF32>
__global__ __launch_bounds__(256) void k_gg(
    const void* __restrict__ Aptr, const bf16* __restrict__ Bptr,
    const float* __restrict__ bias0, const float* __restrict__ bias1,
    void* __restrict__ Cptr,
    int M, int Nout, int KP, int Acols,
    long Astride, long Bstride, long Cstride, int Nstride)
{
  int side = blockIdx.z;
  int m0 = blockIdx.x * 128, n0 = blockIdx.y * 64;

  __shared__ bf16 As[128][72];
  __shared__ bf16 Bs[64][72];

  int tid = threadIdx.x;
  int wave = tid >> 6, lane = tid & 63;
  int quad = lane >> 4, l15 = lane & 15;

  f32x4 acc[8];
  #pragma unroll
  for (int mt = 0; mt < 8; mt++) acc[mt] = (f32x4){0,0,0,0};

  int arow = tid >> 1, ac0 = (tid & 1) * 32;
  int gr = m0 + arow; if (gr > M - 1) gr = M - 1;
  int brow = tid >> 2, bc0 = (tid & 3) * 16;

  for (int k0 = 0; k0 < KP; k0 += 64) {
    if (AF32) {
      const float* src = (const float*)Aptr + (size_t)gr * Acols;
      #pragma unroll
      for (int u = 0; u < 8; u++) {
        int kk = k0 + ac0 + u * 4;
        float4 v;
        if (kk + 4 <= Acols) v = *(const float4*)&src[kk];
        else {
          v.x = (kk + 0 < Acols) ? src[kk + 0] : 0.f;
          v.y = (kk + 1 < Acols) ? src[kk + 1] : 0.f;
          v.z = (kk + 2 < Acols) ? src[kk + 2] : 0.f;
          v.w = (kk + 3 < Acols) ? src[kk + 3] : 0.f;
        }
        As[arow][ac0 + u * 4 + 0] = __float2bfloat16(v.x);
        As[arow][ac0 + u * 4 + 1] = __float2bfloat16(v.y);
        As[arow][ac0 + u * 4 + 2] = __float2bfloat16(v.z);
        As[arow][ac0 + u * 4 + 3] = __float2bfloat16(v.w);
      }
    } else {
      const bf16* src = (const bf16*)Aptr + (size_t)side * Astride + (size_t)gr * KP + k0 + ac0;
      #pragma unroll
      for (int u = 0; u < 4; u++)
        *(short8*)&As[arow][ac0 + u * 8] = *(const short8*)&src[u * 8];
    }
    {
      const bf16* src = Bptr + (size_t)side * Bstride + (size_t)(n0 + brow) * KP + k0 + bc0;
      *(short8*)&Bs[brow][bc0]     = *(const short8*)&src[0];
      *(short8*)&Bs[brow][bc0 + 8] = *(const short8*)&src[8];
    }
    __syncthreads();
    #pragma unroll
    for (int ks = 0; ks < 2; ks++) {
      int kk = ks * 32 + quad * 8;
      short8 bfr = *(const short8*)&Bs[wave * 16 + l15][kk];
      #pragma unroll
      for (int mt = 0; mt < 8; mt++) {
        short8 afr = *(const short8*)&As[mt * 16 + l15][kk];
        acc[mt] = __builtin_amdgcn_mfma_f32_16x16x32_bf16(afr, bfr, acc[mt], 0, 0, 0);
      }
    }
    __syncthreads();
  }

  int n = n0 + wave * 16 + l15;
  if (n < Nout) {
    float bv = bias0 ? (side ? bias1[n] : bias0[n]) : 0.f;
    #pragma unroll
    for (int mt = 0; mt < 8; mt++) {
      #pragma unroll
      for (int r = 0; r < 4; r++) {
        int m = m0 + mt * 16 + quad * 4 + r;
        if (m < M) {
          float val = acc[mt][r] + bv;
          if (OUTBF)
            ((bf16*)Cptr)[(size_t)side * Cstride + (size_t)m * Nstride + n] = __float2bfloat16(val);
          else
            ((float*)Cptr)[(size_t)side * Cstride + (size_t)m * Nstride + n] = val;
        }
      }
    }
  }
}

// ---------------------------------------------------------------- attention v3: one block per (side,b,t)
__global__ __launch_bounds__(256) void k_attn3(
    const float* __restrict__ ent,
    const int* __restrict__ neigh0, const int* __restrict__ neigh1,
    const int* __restrict__ nlen0, const int* __restrict__ nlen1,
    const int* __restrict__ hlen0, const int* __restrict__ hlen1,
    const float* __restrict__ v0, const float* __restrict__ v1,
    const bf16* __restrict__ ep2, const float* __restrict__ biasb,
    bf16* __restrict__ stepb)
{
  int side = blockIdx.y;
  int bt = blockIdx.x;
  int b = bt / T_, t = bt % T_;
  int hl = (side ? hlen1 : hlen0)[b];
  bf16* srow = stepb + (((size_t)side * B_ + b) * T_ + t) * 256;
  int tid = threadIdx.x;
  if (t >= hl) {     // masked timestep: zero row (uniform branch)
    srow[tid] = __float2bfloat16(0.f);
    return;
  }
  const int* neigh = side ? neigh1 : neigh0;
  const float* v = side ? v1 : v0;
  const float* brow = biasb + ((size_t)side * B_ + b) * H_;
  int nl = (side ? nlen1 : nlen0)[b * T_ + t];

  __shared__ float bsh[H_], vsh[H_], lg[64], wsh[64];
  __shared__ int nb[N_];
  if (tid < H_) { bsh[tid] = brow[tid]; vsh[tid] = v[tid]; }
  if (tid < N_) nb[tid] = neigh[((size_t)b * T_ + t) * N_ + tid];
  __syncthreads();

  int grp = tid >> 4;        // 0..15
  int l16 = tid & 15;

  float bs[13], vs[13];
  #pragma unroll
  for (int i = 0; i < 13; i++) {
    int g = l16 + i * 16;
    bool ok = (g < H_);
    bs[i] = ok ? bsh[g] : 0.f;
    vs[i] = ok ? vsh[g] : 0.f;
  }

  for (int n = grp; n < nl; n += 16) {
    const bf16* er = ep2 + (size_t)nb[n] * 400 + side * 200;
    float acc = 0.f;
    #pragma unroll
    for (int i = 0; i < 13; i++) {
      int g = l16 + i * 16;
      float e = (g < H_) ? b2f(er[g]) : 0.f;
      acc += ftanh(e + bs[i]) * vs[i];
    }
    #pragma unroll
    for (int off = 8; off > 0; off >>= 1) acc += __shfl_down(acc, off, 16);
    if (l16 == 0) lg[n] = acc;
  }
  __syncthreads();

  if (tid < 64) {
    float x = (tid < nl) ? lg[tid] : -1e30f;
    float m = x;
    #pragma unroll
    for (int off = 32; off > 0; off >>= 1) m = fmaxf(m, __shfl_down(m, off));
    m = __shfl(m, 0);
    float e = (tid < nl) ? __expf(x - m) : 0.f;
    float s = e;
    #pragma unroll
    for (int off = 32; off > 0; off >>= 1) s += __shfl_down(s, off);
    s = __shfl(s, 0);
    if (tid < N_) wsh[tid] = e / s;
  }
  __syncthreads();

  int h = tid;
  if (h < H_) {
    float a0 = 0.f, a1 = 0.f, a2 = 0.f, a3 = 0.f;
    int n = 0;
    for (; n + 4 <= nl; n += 4) {
      a0 += wsh[n + 0] * ent[(size_t)nb[n + 0] * H_ + h];
      a1 += wsh[n + 1] * ent[(size_t)nb[n + 1] * H_ + h];
      a2 += wsh[n + 2] * ent[(size_t)nb[n + 2] * H_ + h];
      a3 += wsh[n + 3] * ent[(size_t)nb[n + 3] * H_ + h];
    }
    for (; n < nl; n++) a0 += wsh[n] * ent[(size_t)nb[n] * H_ + h];
    srow[h] = __float2bfloat16((a0 + a1) + (a2 + a3));
  } else {
    srow[h] = __float2bfloat16(0.f);   // pad cols 200..255
  }
}

// ---------------------------------------------------------------- MFMA GRU v4
__global__ __launch_bounds__(832) void k_gru4(
    const bf16* __restrict__ giall, const bf16* __restrict__ gibase,
    const bf16* __restrict__ Whh2,
    const float* __restrict__ bhh0, const float* __restrict__ bhh1,
    const int* __restrict__ len0, const int* __restrict__ len1,
    float* __restrict__ hfin)
{
  int side = blockIdx.y;
  int b0 = blockIdx.x * 16;
  const bf16* gia = giall + ((size_t)side * B_ * T_ + (size_t)b0 * T_) * 600;
  const bf16* gib = gibase + ((size_t)side * B_ + b0) * K3;
  const bf16* Wh  = Whh2 + (size_t)side * 608 * 224;
  const float* bhh = side ? bhh1 : bhh0;
  const int* len = side ? len1 : len0;

  __shared__ __align__(16) bf16 Hs[2][16][232];

  int tid = threadIdx.x;
  int wave = tid >> 6, lane = tid & 63;
  int quad = lane >> 4, l15 = lane & 15;

  for (int i = tid; i < 2 * 16 * 232 / 8; i += 832) ((short8*)&Hs[0][0][0])[i] = (short8)0;

  int j0 = wave * 16;
  int j = j0 + l15;
  bool jok = (j < H_);
  float bhr = 0.f, bhz = 0.f, bhn = 0.f;
  float gr[4] = {}, gz[4] = {}, gn[4] = {};
  int lens4[4];
  #pragma unroll
  for (int r = 0; r < 4; r++) lens4[r] = len[b0 + quad * 4 + r];
  if (jok) {
    bhr = bhh[j]; bhz = bhh[H_ + j]; bhn = bhh[2 * H_ + j];
    #pragma unroll
    for (int r = 0; r < 4; r++) {
      const bf16* g = gib + (size_t)(quad * 4 + r) * K3;
      gr[r] = b2f(g[j]); gz[r] = b2f(g[H_ + j]); gn[r] = b2f(g[2 * H_ + j]);
    }
  }
  const bf16* wr = Wh + (size_t)j * 224;
  const bf16* wz = Wh + (size_t)(200 + j) * 224;
  const bf16* wn = Wh + (size_t)(400 + j) * 224;
  __syncthreads();

  int cur = 0;
  for (int t = 0; t < T_; t++) {
    unsigned short guR[4], guZ[4], guN[4];
    if (jok) {
      #pragma unroll
      for (int r = 0; r < 4; r++) {
        const unsigned short* g =
            (const unsigned short*)(gia + ((size_t)(quad * 4 + r) * T_ + t) * 600);
        guR[r] = g[j]; guZ[r] = g[200 + j]; guN[r] = g[400 + j];
      }
    }
    f32x4 ar = {0,0,0,0}, az = {0,0,0,0}, anh = {0,0,0,0};
    #pragma unroll
    for (int ks = 0; ks < 7; ks++) {
      int kk = ks * 32 + quad * 8;
      short8 a0 = *(const short8*)&Hs[cur][l15][kk];
      short8 br = *(const short8*)&wr[kk];
      short8 bz = *(const short8*)&wz[kk];
      short8 bn = *(const short8*)&wn[kk];
      ar  = __builtin_amdgcn_mfma_f32_16x16x32_bf16(a0, br, ar, 0, 0, 0);
      az  = __builtin_amdgcn_mfma_f32_16x16x32_bf16(a0, bz, az, 0, 0, 0);
      anh = __builtin_amdgcn_mfma_f32_16x16x32_bf16(a0, bn, anh, 0, 0, 0);
    }
    if (jok) {
      #pragma unroll
      for (int r = 0; r < 4; r++) {
        int row = quad * 4 + r;
        float rz  = ar[r] + u2f(guR[r]) + gr[r] + bhr;
        float zz  = az[r] + u2f(guZ[r]) + gz[r] + bhz;
        float inn = u2f(guN[r]) + gn[r];
        float hn  = anh[r] + bhn;
        float rg = fsigm(rz);
        float zg = fsigm(zz);
        float ng = ftanh(inn + rg * hn);
        float hold = b2f(Hs[cur][row][j]);
        float hnew = (1.f - zg) * ng + zg * hold;
        Hs[cur ^ 1][row][j] = __float2bfloat16((t < lens4[r]) ? hnew : hold);
      }
    }
    __syncthreads();
    cur ^= 1;
  }
  for (int i = tid; i < 16 * H_; i += 832) {
    int row = i / H_, jj = i % H_;
    hfin[((size_t)side * B_ + b0 + row) * H_ + jj] = b2f(Hs[cur][row][jj]);
  }
}

// ---------------------------------------------------------------- stable descending argsort of hist_len
__global__ __launch_bounds__(512) void k_argsort(
    const int* __restrict__ hlen0, const int* __restrict__ hlen1,
    int* __restrict__ idxbuf, float* __restrict__ dout)
{
  int side = blockIdx.x;
  const int* len = side ? hlen1 : hlen0;
  __shared__ int lens[B_];
  __shared__ int perm[B_];
  int tid = threadIdx.x;
  lens[tid] = len[tid];
  __syncthreads();
  int L = lens[tid];
  int rank = 0;
  for (int j = 0; j < B_; j++) {
    int Lj = lens[j];
    rank += (Lj > L) || (Lj == L && j < tid);
  }
  perm[rank] = tid;
  __syncthreads();
  idxbuf[side * B_ + tid] = perm[tid];
  size_t base = 1 + (size_t)2 * B_ * E_ + (side ? 0 : B_);
  dout[base + tid] = (float)perm[tid];
}

// ---------------------------------------------------------------- assemble pred-GEMM input rows (bf16, K padded to 640)
__global__ __launch_bounds__(256) void k_feat(
    const float* __restrict__ ent, const float* __restrict__ rel, const int* __restrict__ trip,
    const int* __restrict__ idxbuf, const float* __restrict__ hfin,
    bf16* __restrict__ xfeat)
{
  int i = blockIdx.x, p = blockIdx.y;
  int bi = idxbuf[(p == 0 ? 1 : 0) * B_ + i];
  int ent_id = (p == 0) ? trip[bi * 3 + 2] : trip[bi * 3 + 0];
  int rid = trip[bi * 3 + 1];
  const float* hsrc = hfin + (size_t)(p == 0 ? 1 : 0) * B_ * H_;
  bf16* x = xfeat + ((size_t)p * B_ + i) * 640;
  int h = threadIdx.x;
  if (h < H_) {
    x[h]          = __float2bfloat16(ent[(size_t)ent_id * H_ + h]);
    x[H_ + h]     = __float2bfloat16(hsrc[(size_t)bi * H_ + h]);
    x[2 * H_ + h] = __float2bfloat16(rel[(size_t)rid * H_ + h]);
  }
  if (h < 40) x[600 + h] = __float2bfloat16(0.f);
}

// ---------------------------------------------------------------- MFMA pred GEMM v7 (bf16 prepacked B + fused sumexp)
// tile 256M x 64N x 64K, 512 threads / 8 waves (4Mx2N), wave = 64Mx32N -> acc[4][2].
// Epilogue: nontemporal C stores (write-once, never re-read) + per-row exp-sum
// partials merged into sumexp[side*512+row] via one atomicAdd per (row, wave).
__global__ __launch_bounds__(512) void k_gemm6(
    const bf16* __restrict__ Abf, const bf16* __restrict__ Wlin,
    const float* __restrict__ bias0, const float* __restrict__ bias1,
    float* __restrict__ dout, float* __restrict__ sumexp)
{
  int side = blockIdx.z;
  const bf16* Bm = Wlin + (size_t)side * EP_ * 640;
  const float* bias = side ? bias1 : bias0;
  float* C = dout + 1 + (size_t)side * B_ * E_;
  int mBase = blockIdx.x * 256;
  int m0 = side * B_ + mBase;
  int n0 = blockIdx.y * 64;

  __shared__ bf16 As[256][72];
  __shared__ bf16 Bs[64][72];

  int tid = threadIdx.x;
  int wave = tid >> 6, lane = tid & 63;
  int quad = lane >> 4, l15 = lane & 15;
  int wm = wave >> 1, wn = wave & 1;   // 4x2 wave grid

  f32x4 acc[4][2];
  #pragma unroll
  for (int mt = 0; mt < 4; mt++)
    #pragma unroll
    for (int nt = 0; nt < 2; nt++) acc[mt][nt] = (f32x4){0,0,0,0};

  int arow = tid >> 1, ac0 = (tid & 1) * 32;       // A: 256 rows, 32-elem halves
  int brow = tid >> 3, bc0 = (tid & 7) * 8;        // B: 64 rows, 8 bf16 each
  const bf16* asrc = Abf + (size_t)(m0 + arow) * 640 + ac0;
  const bf16* bsrc = Bm + (size_t)(n0 + brow) * 640 + bc0;

  for (int k0 = 0; k0 < 640; k0 += 64) {
    #pragma unroll
    for (int u = 0; u < 4; u++)
      *(short8*)&As[arow][ac0 + u * 8] = *(const short8*)&asrc[k0 + u * 8];
    *(short8*)&Bs[brow][bc0] = *(const short8*)&bsrc[k0];
    __syncthreads();
    #pragma unroll
    for (int ks = 0; ks < 2; ks++) {
      int kk = ks * 32 + quad * 8;
      short8 bfr[2];
      #pragma unroll
      for (int nt = 0; nt < 2; nt++)
        bfr[nt] = *(const short8*)&Bs[wn * 32 + nt * 16 + l15][kk];
      #pragma unroll
      for (int mt = 0; mt < 4; mt++) {
        short8 afr = *(const short8*)&As[wm * 64 + mt * 16 + l15][kk];
        #pragma unroll
        for (int nt = 0; nt < 2; nt++)
          acc[mt][nt] = __builtin_amdgcn_mfma_f32_16x16x32_bf16(afr, bfr[nt], acc[mt][nt], 0, 0, 0);
      }
    }
    __syncthreads();
  }

  // epilogue: row = mBase + wm*64 + mt*16 + quad*4 + r; col = n0 + wn*32 + nt*16 + l15
  float bv[2];
  int ncol[2];
  #pragma unroll
  for (int nt = 0; nt < 2; nt++) {
    ncol[nt] = n0 + wn * 32 + nt * 16 + l15;
    bv[nt] = (ncol[nt] < E_) ? bias[ncol[nt]] : 0.f;
  }
  #pragma unroll
  for (int mt = 0; mt < 4; mt++) {
    #pragma unroll
    for (int r = 0; r < 4; r++) {
      int mrow = mBase + wm * 64 + mt * 16 + quad * 4 + r;
      float p = 0.f;
      #pragma unroll
      for (int nt = 0; nt < 2; nt++) {
        if (ncol[nt] < E_) {
          float val = acc[mt][nt][r] + bv[nt];
          __builtin_nontemporal_store(val, &C[(size_t)mrow * E_ + ncol[nt]]);
          p += __expf(val);
        }
      }
      // reduce 32 cols of this row held by this wave (16 lanes x 2 cols)
      #pragma unroll
      for (int off = 8; off > 0; off >>= 1) p += __shfl_down(p, off, 16);
      if (l15 == 0) atomicAdd(&sumexp[side * B_ + mrow], p);
    }
  }
}

// ---------------------------------------------------------------- MFMA pred GEMM v5 (fp32 B fallback, ws too small)
__global__ __launch_bounds__(512) void k_gemm5(
    const bf16* __restrict__ Abf,
    const float* __restrict__ B0, const float* __restrict__ B1,
    const float* __restrict__ bias0, const float* __restrict__ bias1,
    float* __restrict__ dout, float* __restrict__ sumexp)
{
  int side = blockIdx.z;
  const float* Bm = side ? B1 : B0;
  const float* bias = side ? bias1 : bias0;
  float* C = dout + 1 + (size_t)side * B_ * E_;
  int mBase = blockIdx.x * 256;
  int m0 = side * B_ + mBase;
  int n0 = blockIdx.y * 64;

  __shared__ bf16 As[256][72];
  __shared__ bf16 Bs[64][72];

  int tid = threadIdx.x;
  int wave = tid >> 6, lane = tid & 63;
  int quad = lane >> 4, l15 = lane & 15;
  int wm = wave >> 1, wn = wave & 1;

  f32x4 acc[4][2];
  #pragma unroll
  for (int mt = 0; mt < 4; mt++)
    #pragma unroll
    for (int nt = 0; nt < 2; nt++) acc[mt][nt] = (f32x4){0,0,0,0};

  int arow = tid >> 1, ac0 = (tid & 1) * 32;
  int brow = tid >> 3, bc0 = (tid & 7) * 8;
  const bf16* asrc = Abf + (size_t)(m0 + arow) * 640 + ac0;
  int nsrc = n0 + brow; if (nsrc > E_ - 1) nsrc = E_ - 1;
  const float* bsrc = Bm + (size_t)nsrc * K3 + bc0;

  for (int k0 = 0; k0 < 640; k0 += 64) {
    #pragma unroll
    for (int u = 0; u < 4; u++)
      *(short8*)&As[arow][ac0 + u * 8] = *(const short8*)&asrc[k0 + u * 8];
    {
      int kb = k0 + bc0;
      if (kb + 8 <= K3) {
        float4 v0 = *(const float4*)&bsrc[k0];
        float4 v1 = *(const float4*)&bsrc[k0 + 4];
        Bs[brow][bc0 + 0] = __float2bfloat16(v0.x);
        Bs[brow][bc0 + 1] = __float2bfloat16(v0.y);
        Bs[brow][bc0 + 2] = __float2bfloat16(v0.z);
        Bs[brow][bc0 + 3] = __float2bfloat16(v0.w);
        Bs[brow][bc0 + 4] = __float2bfloat16(v1.x);
        Bs[brow][bc0 + 5] = __float2bfloat16(v1.y);
        Bs[brow][bc0 + 6] = __float2bfloat16(v1.z);
        Bs[brow][bc0 + 7] = __float2bfloat16(v1.w);
      } else {
        #pragma unroll
        for (int u = 0; u < 8; u++) {
          int k = kb + u;
          float v = (k < K3) ? bsrc[k0 + u] : 0.f;
          Bs[brow][bc0 + u] = __float2bfloat16(v);
        }
      }
    }
    __syncthreads();
    #pragma unroll
    for (int ks = 0; ks < 2; ks++) {
      int kk = ks * 32 + quad * 8;
      short8 bfr[2];
      #pragma unroll
      for (int nt = 0; nt < 2; nt++)
        bfr[nt] = *(const short8*)&Bs[wn * 32 + nt * 16 + l15][kk];
      #pragma unroll
      for (int mt = 0; mt < 4; mt++) {
        short8 afr = *(const short8*)&As[wm * 64 + mt * 16 + l15][kk];
        #pragma unroll
        for (int nt = 0; nt < 2; nt++)
          acc[mt][nt] = __builtin_amdgcn_mfma_f32_16x16x32_bf16(afr, bfr[nt], acc[mt][nt], 0, 0, 0);
      }
    }
    __syncthreads();
  }

  float bv[2];
  int ncol[2];
  #pragma unroll
  for (int nt = 0; nt < 2; nt++) {
    ncol[nt] = n0 + wn * 32 + nt * 16 + l15;
    bv[nt] = (ncol[nt] < E_) ? bias[ncol[nt]] : 0.f;
  }
  #pragma unroll
  for (int mt = 0; mt < 4; mt++) {
    #pragma unroll
    for (int r = 0; r < 4; r++) {
      int mrow = mBase + wm * 64 + mt * 16 + quad * 4 + r;
      float p = 0.f;
      #pragma unroll
      for (int nt = 0; nt < 2; nt++) {
        if (ncol[nt] < E_) {
          float val = acc[mt][nt][r] + bv[nt];
          __builtin_nontemporal_store(val, &C[(size_t)mrow * E_ + ncol[nt]]);
          p += __expf(val);
        }
      }
      #pragma unroll
      for (int off = 8; off > 0; off >>= 1) p += __shfl_down(p, off, 16);
      if (l15 == 0) atomicAdd(&sumexp[side * B_ + mrow], p);
    }
  }
}

// ---------------------------------------------------------------- final CE loss from fused sumexp
// one block: gather label logits + log(sumexp), reduce, write dout[0]
__global__ __launch_bounds__(256) void k_loss2(
    const float* __restrict__ dout_ro, const int* __restrict__ trip,
    const int* __restrict__ idxbuf, const float* __restrict__ sumexp,
    float* __restrict__ dout)
{
  int tid = threadIdx.x;
  float part = 0.f;
  for (int idx = tid; idx < 2 * B_; idx += 256) {
    int p = idx >> 9, i = idx & 511;
    int bi = idxbuf[(p == 0 ? 1 : 0) * B_ + i];
    int label = (p == 0) ? trip[bi * 3 + 0] : trip[bi * 3 + 2];
    float val = dout_ro[1 + (size_t)p * B_ * E_ + (size_t)i * E_ + label];
    float lp = val - logf(sumexp[p * B_ + i]);
    part += -lp / (float)B_;
  }
  __shared__ float ps[256];
  ps[tid] = part; __syncthreads();
  for (int st = 128; st > 0; st >>= 1) {
    if (tid < st) ps[tid] += ps[tid + st];
    __syncthreads();
  }
  if (tid == 0) dout[0] = ps[0];
}

// ----------------------------------------------------------------
extern "C" void kernel_launch(void* const* d_in, const int* in_sizes, int n_in,
                              void* d_out, int out_size, void* d_ws, size_t ws_size,
                              hipStream_t stream)
{
  const int* trip = (const int*)d_in[0];
  const int* s_ne = (const int*)d_in[1];
  const int* s_nl = (const int*)d_in[2];
  const int* s_hl = (const int*)d_in[3];
  const int* o_ne = (const int*)d_in[4];
  const int* o_nl = (const int*)d_in[5];
  const int* o_hl = (const int*)d_in[6];
  const float* ent = (const float*)d_in[7];
  const float* rel = (const float*)d_in[8];
  const float* aw_s = (const float*)d_in[9];
  const float* ab_s = (const float*)d_in[10];
  const float* v_s  = (const float*)d_in[11];
  const float* aw_o = (const float*)d_in[12];
  const float* ab_o = (const float*)d_in[13];
  const float* v_o  = (const float*)d_in[14];
  const float* sub_wih = (const float*)d_in[15];
  const float* sub_whh = (const float*)d_in[16];
  const float* sub_bih = (const float*)d_in[17];
  const float* sub_bhh = (const float*)d_in[18];
  const float* ob_wih  = (const float*)d_in[19];
  const float* ob_whh  = (const float*)d_in[20];
  const float* ob_bih  = (const float*)d_in[21];
  const float* ob_bhh  = (const float*)d_in[22];
  const float* lin_sub_w = (const float*)d_in[23];
  const float* lin_sub_b = (const float*)d_in[24];
  const float* lin_ob_w  = (const float*)d_in[25];
  const float* lin_ob_b  = (const float*)d_in[26];
  float* dout = (float*)d_out;

  // workspace carve — base ~34.6 MB, +25.7 MB for bf16 pred weights if it fits
  char* w = (char*)d_ws;
  bf16* ep2     = (bf16*)w;  w += (size_t)E_ * 400 * 2;           //  8,000,000 B
  bf16* stepb   = (bf16*)w;  w += (size_t)2 * B_ * T_ * 256 * 2;  //  5,242,880 B
  float* biasb  = (float*)w; w += (size_t)2 * B_ * H_ * 4;        //    819,200 B
  bf16* gibase  = (bf16*)w;  w += (size_t)2 * B_ * K3 * 2;        //  1,228,800 B
  float* hfin   = (float*)w; w += (size_t)2 * B_ * H_ * 4;        //    819,200 B
  bf16* xfeat   = (bf16*)w;  w += (size_t)1024 * 640 * 2;         //  1,310,720 B
  bf16* Wn2     = (bf16*)w;  w += (size_t)448 * 256 * 2;          //    229,376 B
  bf16* Wb2     = (bf16*)w;  w += (size_t)2 * 256 * 448 * 2;      //    458,752 B
  bf16* Wg2     = (bf16*)w;  w += (size_t)2 * 640 * 448 * 2;      //  1,146,880 B
  bf16* Wstep   = (bf16*)w;  w += (size_t)2 * 640 * 256 * 2;      //    655,360 B
  bf16* Whh2    = (bf16*)w;  w += (size_t)2 * 608 * 224 * 2;      //    544,768 B
  bf16* giall   = (bf16*)w;  w += (size_t)2 * B_ * T_ * 600 * 2;  // 12,288,000 B
  bf16* Abias   = (bf16*)w;  w += (size_t)2 * B_ * 448 * 2;       //    917,504 B
  bf16* Agi     = (bf16*)w;  w += (size_t)2 * B_ * 448 * 2;       //    917,504 B
  float* sumexp = (float*)w; w += 4096;                           // 2*B_ floats
  int* idxbuf   = (int*)w;   w += 4096;
  bf16* Wlin    = (bf16*)w;  w += (size_t)2 * EP_ * 640 * 2;      // 25,722,880 B
  bool useBf16B = ((size_t)(w - (char*)d_ws) <= ws_size);

  // fused packs (+ sumexp zero-init)
  k_packall<<<5761, 256, 0, stream>>>(aw_s, aw_o, sub_wih, ob_wih, sub_whh, ob_whh,
                                      ent, rel, trip, Wn2, Wb2, Wg2, Wstep, Whh2,
                                      Abias, Agi, sumexp);
  if (useBf16B)
    k_pack_lin<<<dim3(EP_, 2), 256, 0, stream>>>(lin_ob_w, lin_sub_w, Wlin);
  // ep2 = ent @ Wn.T   (M=10000, N=400, K=256pad)
  k_gg<true, true><<<dim3(79, 7, 1), 256, 0, stream>>>(
      (const void*)ent, Wn2, nullptr, nullptr, (void*)ep2,
      E_, 400, 256, 200, 0L, 0L, 0L, 400);
  // biasb = [se;re] @ Wa[:,200:600].T + ba   (M=512/side, N=200, K=448pad)
  k_gg<false, false><<<dim3(4, 4, 2), 256, 0, stream>>>(
      (const void*)Abias, Wb2, ab_s, ab_o, (void*)biasb,
      B_, 200, 448, 448, (long)B_ * 448, 256L * 448, (long)B_ * 200, 200);
  // gibase = [se;rr] @ Wih[:,200:600].T + bih   (M=512/side, N=600, K=448pad)
  k_gg<true, false><<<dim3(4, 10, 2), 256, 0, stream>>>(
      (const void*)Agi, Wg2, sub_bih, ob_bih, (void*)gibase,
      B_, 600, 448, 448, (long)B_ * 448, 640L * 448, (long)B_ * 600, 600);
  // attention (one block per (side,b,t))
  k_attn3<<<dim3(B_ * T_, 2), 256, 0, stream>>>(ent, s_ne, o_ne, s_nl, o_nl,
                                                s_hl, o_hl, v_s, v_o, ep2, biasb, stepb);
  // giall = step @ Wih[:, :200].T  for all (b,t)  (M=5120/side, N=600, K=256pad)
  k_gg<true, false><<<dim3(40, 10, 2), 256, 0, stream>>>(
      (const void*)stepb, Wstep, nullptr, nullptr, (void*)giall,
      B_ * T_, 600, 256, 256, (long)B_ * T_ * 256, 640L * 256, (long)B_ * T_ * 600, 600);
  // GRU (recurrent part only: K=224)
  k_gru4<<<dim3(B_ / 16, 2), 832, 0, stream>>>(giall, gibase, Whh2, sub_bhh, ob_bhh,
                                               s_hl, o_hl, hfin);
  k_argsort<<<2, 512, 0, stream>>>(s_hl, o_hl, idxbuf, dout);
  k_feat<<<dim3(B_, 2), 256, 0, stream>>>(ent, rel, trip, idxbuf, hfin, xfeat);
  // pred GEMM with fused sumexp + NT stores
  if (useBf16B)
    k_gemm6<<<dim3(2, (E_ + 63) / 64, 2), 512, 0, stream>>>(
        xfeat, Wlin, lin_ob_b, lin_sub_b, dout, sumexp);
  else
    k_gemm5<<<dim3(2, (E_ + 63) / 64, 2), 512, 0, stream>>>(
        xfeat, lin_ob_w, lin_sub_w, lin_ob_b, lin_sub_b, dout, sumexp);
  k_loss2<<<1, 256, 0, stream>>>(dout, trip, idxbuf, sumexp, dout);
}

// Round 9
// 417.390 us; speedup vs baseline: 1.0099x; 1.0099x over previous
//
#include <hip/hip_runtime.h>
#include <hip/hip_bf16.h>
#include <math.h>

typedef __hip_bfloat16 bf16;
typedef __attribute__((ext_vector_type(8))) short short8;
typedef __attribute__((ext_vector_type(4))) float f32x4;

#define B_ 512
#define T_ 10
#define N_ 50
#define H_ 200
#define E_ 10000
#define R_ 200
#define K3 600   // 3*H
#define EP_ 10048  // E_ padded to 64 for guard-free B staging

__device__ __forceinline__ float b2f(bf16 x){ return __bfloat162float(x); }
__device__ __forceinline__ float u2f(unsigned short u){
  unsigned int x = ((unsigned int)u) << 16;
  return __builtin_bit_cast(float, x);
}
// fast sigmoid/tanh: v_exp_f32 + v_rcp_f32 (~1 ulp), instead of libm calls
__device__ __forceinline__ float fsigm(float x){
  return __builtin_amdgcn_rcpf(1.f + __expf(-x));
}
__device__ __forceinline__ float ftanh(float x){
  x = fminf(15.f, fmaxf(-15.f, x));
  float e = __expf(-2.f * x);
  return (1.f - e) * __builtin_amdgcn_rcpf(1.f + e);
}

// ---------------------------------------------------------------- fused weight packs (one dispatch)
// sections by blockIdx.x:
//  [0,448)      Wn2[448][256]
//  [448,960)    Wb2[2][256][448]
//  [960,2240)   Wg2[2][640][448]
//  [2240,3520)  Wstep[2][640][256]
//  [3520,4736)  Whh2[2][608][224]
//  [4736,5760)  Abias/Agi  (side*512+b rows of 448)
//  5760         sumexp zero-init
__global__ __launch_bounds__(256) void k_packall(
    const float* __restrict__ aw_s, const float* __restrict__ aw_o,
    const float* __restrict__ sub_wih, const float* __restrict__ ob_wih,
    const float* __restrict__ sub_whh, const float* __restrict__ ob_whh,
    const float* __restrict__ ent, const float* __restrict__ rel,
    const int* __restrict__ trip,
    bf16* __restrict__ Wn2, bf16* __restrict__ Wb2, bf16* __restrict__ Wg2,
    bf16* __restrict__ Wstep, bf16* __restrict__ Whh2,
    bf16* __restrict__ Ab, bf16* __restrict__ Ag, float* __restrict__ sumexp)
{
  int bid = blockIdx.x;
  int tid = threadIdx.x;
  if (bid < 448) {
    int r = bid;
    const float* Wa = (r < 200) ? aw_s : aw_o;
    int g = (r < 200) ? r : r - 200;
    bf16* out = Wn2 + (size_t)r * 256;
    for (int k = tid; k < 256; k += 256) {
      float v = (r < 400 && k < 200) ? Wa[(size_t)g * K3 + k] : 0.f;
      out[k] = __float2bfloat16(v);
    }
  } else if (bid < 960) {
    int idx = bid - 448;
    int side = idx >> 8, r = idx & 255;
    const float* W = side ? aw_o : aw_s;
    bf16* out = Wb2 + ((size_t)side * 256 + r) * 448;
    for (int k = tid; k < 448; k += 256) {
      float v = (r < 200 && k < 400) ? W[(size_t)r * K3 + 200 + k] : 0.f;
      out[k] = __float2bfloat16(v);
    }
  } else if (bid < 2240) {
    int idx = bid - 960;
    int side = idx / 640, r = idx % 640;
    const float* W = side ? ob_wih : sub_wih;
    bf16* out = Wg2 + ((size_t)side * 640 + r) * 448;
    for (int k = tid; k < 448; k += 256) {
      float v = (r < 600 && k < 400) ? W[(size_t)r * K3 + 200 + k] : 0.f;
      out[k] = __float2bfloat16(v);
    }
  } else if (bid < 3520) {
    int idx = bid - 2240;
    int side = idx / 640, r = idx % 640;
    const float* W = side ? ob_wih : sub_wih;
    bf16* out = Wstep + ((size_t)side * 640 + r) * 256;
    for (int k = tid; k < 256; k += 256) {
      float v = (r < 600 && k < 200) ? W[(size_t)r * K3 + k] : 0.f;
      out[k] = __float2bfloat16(v);
    }
  } else if (bid < 4736) {
    int idx = bid - 3520;
    int side = idx / 608, r = idx % 608;
    const float* W = side ? ob_whh : sub_whh;
    bf16* out = Whh2 + ((size_t)side * 608 + r) * 224;
    for (int k = tid; k < 224; k += 256) {
      float v = (r < 600 && k < 200) ? W[(size_t)r * H_ + k] : 0.f;
      out[k] = __float2bfloat16(v);
    }
  } else if (bid < 5760) {
    int idx = bid - 4736;
    int side = idx >> 9, b = idx & 511;
    int ids = trip[b * 3 + (side ? 2 : 0)];
    int rid = trip[b * 3 + 1];
    size_t ro = ((size_t)side * B_ + b) * 448;
    for (int k = tid; k < 448; k += 256) {
      float vb = 0.f, vg = 0.f;
      if (k < 200) { float e = ent[(size_t)ids * H_ + k]; vb = e; vg = e; }
      else if (k < 400) {
        vb = ent[(size_t)rid * H_ + (k - 200)];
        vg = rel[(size_t)rid * H_ + (k - 200)];
      }
      Ab[ro + k] = __float2bfloat16(vb);
      Ag[ro + k] = __float2bfloat16(vg);
    }
  } else {
    for (int i = tid; i < 2 * B_; i += 256) sumexp[i] = 0.f;
  }
}

// ---------------------------------------------------------------- pred-weight bf16 prepack
// Wlin[side][EP_][640]: rows<E_ = W[r][0:600], rest 0. side0=lin_ob_w, side1=lin_sub_w.
__global__ __launch_bounds__(256) void k_pack_lin(
    const float* __restrict__ W0, const float* __restrict__ W1, bf16* __restrict__ Wlin)
{
  int row = blockIdx.x, side = blockIdx.y;
  const float* W = side ? W1 : W0;
  bf16* out = Wlin + ((size_t)side * EP_ + row) * 640;
  for (int k = threadIdx.x; k < 640; k += 256) {
    float v = (row < E_ && k < K3) ? W[(size_t)row * K3 + k] : 0.f;
    out[k] = __float2bfloat16(v);
  }
}

// ---------------------------------------------------------------- generic MFMA GEMM
// C[m][n] = sum_k A[m][k]*B[n][k] (+ bias[n]); tile M=128, N=64, BK=64.
template<bool OUTBF, bool AF32>
__global__ __launch_bounds__(256) void k_gg(
    const void* __restrict__ Aptr, const bf16* __restrict__ Bptr,
    const float* __restrict__ bias0, const float* __restrict__ bias1,
    void* __restrict__ Cptr,
    int M, int Nout, int KP, int Acols,
    long Astride, long Bstride, long Cstride, int Nstride)
{
  int side = blockIdx.z;
  int m0 = blockIdx.x * 128, n0 = blockIdx.y * 64;

  __shared__ bf16 As[128][72];
  __shared__ bf16 Bs[64][72];

  int tid = threadIdx.x;
  int wave = tid >> 6, lane = tid & 63;
  int quad = lane >> 4, l15 = lane & 15;

  f32x4 acc[8];
  #pragma unroll
  for (int mt = 0; mt < 8; mt++) acc[mt] = (f32x4){0,0,0,0};

  int arow = tid >> 1, ac0 = (tid & 1) * 32;
  int gr = m0 + arow; if (gr > M - 1) gr = M - 1;
  int brow = tid >> 2, bc0 = (tid & 3) * 16;

  for (int k0 = 0; k0 < KP; k0 += 64) {
    if (AF32) {
      const float* src = (const float*)Aptr + (size_t)gr * Acols;
      #pragma unroll
      for (int u = 0; u < 8; u++) {
        int kk = k0 + ac0 + u * 4;
        float4 v;
        if (kk + 4 <= Acols) v = *(const float4*)&src[kk];
        else {
          v.x = (kk + 0 < Acols) ? src[kk + 0] : 0.f;
          v.y = (kk + 1 < Acols) ? src[kk + 1] : 0.f;
          v.z = (kk + 2 < Acols) ? src[kk + 2] : 0.f;
          v.w = (kk + 3 < Acols) ? src[kk + 3] : 0.f;
        }
        As[arow][ac0 + u * 4 + 0] = __float2bfloat16(v.x);
        As[arow][ac0 + u * 4 + 1] = __float2bfloat16(v.y);
        As[arow][ac0 + u * 4 + 2] = __float2bfloat16(v.z);
        As[arow][ac0 + u * 4 + 3] = __float2bfloat16(v.w);
      }
    } else {
      const bf16* src = (const bf16*)Aptr + (size_t)side * Astride + (size_t)gr * KP + k0 + ac0;
      #pragma unroll
      for (int u = 0; u < 4; u++)
        *(short8*)&As[arow][ac0 + u * 8] = *(const short8*)&src[u * 8];
    }
    {
      const bf16* src = Bptr + (size_t)side * Bstride + (size_t)(n0 + brow) * KP + k0 + bc0;
      *(short8*)&Bs[brow][bc0]     = *(const short8*)&src[0];
      *(short8*)&Bs[brow][bc0 + 8] = *(const short8*)&src[8];
    }
    __syncthreads();
    #pragma unroll
    for (int ks = 0; ks < 2; ks++) {
      int kk = ks * 32 + quad * 8;
      short8 bfr = *(const short8*)&Bs[wave * 16 + l15][kk];
      #pragma unroll
      for (int mt = 0; mt < 8; mt++) {
        short8 afr = *(const short8*)&As[mt * 16 + l15][kk];
        acc[mt] = __builtin_amdgcn_mfma_f32_16x16x32_bf16(afr, bfr, acc[mt], 0, 0, 0);
      }
    }
    __syncthreads();
  }

  int n = n0 + wave * 16 + l15;
  if (n < Nout) {
    float bv = bias0 ? (side ? bias1[n] : bias0[n]) : 0.f;
    #pragma unroll
    for (int mt = 0; mt < 8; mt++) {
      #pragma unroll
      for (int r = 0; r < 4; r++) {
        int m = m0 + mt * 16 + quad * 4 + r;
        if (m < M) {
          float val = acc[mt][r] + bv;
          if (OUTBF)
            ((bf16*)Cptr)[(size_t)side * Cstride + (size_t)m * Nstride + n] = __float2bfloat16(val);
          else
            ((float*)Cptr)[(size_t)side * Cstride + (size_t)m * Nstride + n] = val;
        }
      }
    }
  }
}

// ---------------------------------------------------------------- attention v3: one block per (side,b,t)
__global__ __launch_bounds__(256) void k_attn3(
    const float* __restrict__ ent,
    const int* __restrict__ neigh0, const int* __restrict__ neigh1,
    const int* __restrict__ nlen0, const int* __restrict__ nlen1,
    const int* __restrict__ hlen0, const int* __restrict__ hlen1,
    const float* __restrict__ v0, const float* __restrict__ v1,
    const bf16* __restrict__ ep2, const float* __restrict__ biasb,
    bf16* __restrict__ stepb)
{
  int side = blockIdx.y;
  int bt = blockIdx.x;
  int b = bt / T_, t = bt % T_;
  int hl = (side ? hlen1 : hlen0)[b];
  bf16* srow = stepb + (((size_t)side * B_ + b) * T_ + t) * 256;
  int tid = threadIdx.x;
  if (t >= hl) {     // masked timestep: zero row (uniform branch)
    srow[tid] = __float2bfloat16(0.f);
    return;
  }
  const int* neigh = side ? neigh1 : neigh0;
  const float* v = side ? v1 : v0;
  const float* brow = biasb + ((size_t)side * B_ + b) * H_;
  int nl = (side ? nlen1 : nlen0)[b * T_ + t];

  __shared__ float bsh[H_], vsh[H_], lg[64], wsh[64];
  __shared__ int nb[N_];
  if (tid < H_) { bsh[tid] = brow[tid]; vsh[tid] = v[tid]; }
  if (tid < N_) nb[tid] = neigh[((size_t)b * T_ + t) * N_ + tid];
  __syncthreads();

  int grp = tid >> 4;        // 0..15
  int l16 = tid & 15;

  float bs[13], vs[13];
  #pragma unroll
  for (int i = 0; i < 13; i++) {
    int g = l16 + i * 16;
    bool ok = (g < H_);
    bs[i] = ok ? bsh[g] : 0.f;
    vs[i] = ok ? vsh[g] : 0.f;
  }

  for (int n = grp; n < nl; n += 16) {
    const bf16* er = ep2 + (size_t)nb[n] * 400 + side * 200;
    float acc = 0.f;
    #pragma unroll
    for (int i = 0; i < 13; i++) {
      int g = l16 + i * 16;
      float e = (g < H_) ? b2f(er[g]) : 0.f;
      acc += ftanh(e + bs[i]) * vs[i];
    }
    #pragma unroll
    for (int off = 8; off > 0; off >>= 1) acc += __shfl_down(acc, off, 16);
    if (l16 == 0) lg[n] = acc;
  }
  __syncthreads();

  if (tid < 64) {
    float x = (tid < nl) ? lg[tid] : -1e30f;
    float m = x;
    #pragma unroll
    for (int off = 32; off > 0; off >>= 1) m = fmaxf(m, __shfl_down(m, off));
    m = __shfl(m, 0);
    float e = (tid < nl) ? __expf(x - m) : 0.f;
    float s = e;
    #pragma unroll
    for (int off = 32; off > 0; off >>= 1) s += __shfl_down(s, off);
    s = __shfl(s, 0);
    if (tid < N_) wsh[tid] = e / s;
  }
  __syncthreads();

  int h = tid;
  if (h < H_) {
    float a0 = 0.f, a1 = 0.f, a2 = 0.f, a3 = 0.f;
    int n = 0;
    for (; n + 4 <= nl; n += 4) {
      a0 += wsh[n + 0] * ent[(size_t)nb[n + 0] * H_ + h];
      a1 += wsh[n + 1] * ent[(size_t)nb[n + 1] * H_ + h];
      a2 += wsh[n + 2] * ent[(size_t)nb[n + 2] * H_ + h];
      a3 += wsh[n + 3] * ent[(size_t)nb[n + 3] * H_ + h];
    }
    for (; n < nl; n++) a0 += wsh[n] * ent[(size_t)nb[n] * H_ + h];
    srow[h] = __float2bfloat16((a0 + a1) + (a2 + a3));
  } else {
    srow[h] = __float2bfloat16(0.f);   // pad cols 200..255
  }
}

// ---------------------------------------------------------------- MFMA GRU v4
__global__ __launch_bounds__(832) void k_gru4(
    const bf16* __restrict__ giall, const bf16* __restrict__ gibase,
    const bf16* __restrict__ Whh2,
    const float* __restrict__ bhh0, const float* __restrict__ bhh1,
    const int* __restrict__ len0, const int* __restrict__ len1,
    float* __restrict__ hfin)
{
  int side = blockIdx.y;
  int b0 = blockIdx.x * 16;
  const bf16* gia = giall + ((size_t)side * B_ * T_ + (size_t)b0 * T_) * 600;
  const bf16* gib = gibase + ((size_t)side * B_ + b0) * K3;
  const bf16* Wh  = Whh2 + (size_t)side * 608 * 224;
  const float* bhh = side ? bhh1 : bhh0;
  const int* len = side ? len1 : len0;

  __shared__ __align__(16) bf16 Hs[2][16][232];

  int tid = threadIdx.x;
  int wave = tid >> 6, lane = tid & 63;
  int quad = lane >> 4, l15 = lane & 15;

  for (int i = tid; i < 2 * 16 * 232 / 8; i += 832) ((short8*)&Hs[0][0][0])[i] = (short8)0;

  int j0 = wave * 16;
  int j = j0 + l15;
  bool jok = (j < H_);
  float bhr = 0.f, bhz = 0.f, bhn = 0.f;
  float gr[4] = {}, gz[4] = {}, gn[4] = {};
  int lens4[4];
  #pragma unroll
  for (int r = 0; r < 4; r++) lens4[r] = len[b0 + quad * 4 + r];
  if (jok) {
    bhr = bhh[j]; bhz = bhh[H_ + j]; bhn = bhh[2 * H_ + j];
    #pragma unroll
    for (int r = 0; r < 4; r++) {
      const bf16* g = gib + (size_t)(quad * 4 + r) * K3;
      gr[r] = b2f(g[j]); gz[r] = b2f(g[H_ + j]); gn[r] = b2f(g[2 * H_ + j]);
    }
  }
  const bf16* wr = Wh + (size_t)j * 224;
  const bf16* wz = Wh + (size_t)(200 + j) * 224;
  const bf16* wn = Wh + (size_t)(400 + j) * 224;
  __syncthreads();

  int cur = 0;
  for (int t = 0; t < T_; t++) {
    unsigned short guR[4], guZ[4], guN[4];
    if (jok) {
      #pragma unroll
      for (int r = 0; r < 4; r++) {
        const unsigned short* g =
            (const unsigned short*)(gia + ((size_t)(quad * 4 + r) * T_ + t) * 600);
        guR[r] = g[j]; guZ[r] = g[200 + j]; guN[r] = g[400 + j];
      }
    }
    f32x4 ar = {0,0,0,0}, az = {0,0,0,0}, anh = {0,0,0,0};
    #pragma unroll
    for (int ks = 0; ks < 7; ks++) {
      int kk = ks * 32 + quad * 8;
      short8 a0 = *(const short8*)&Hs[cur][l15][kk];
      short8 br = *(const short8*)&wr[kk];
      short8 bz = *(const short8*)&wz[kk];
      short8 bn = *(const short8*)&wn[kk];
      ar  = __builtin_amdgcn_mfma_f32_16x16x32_bf16(a0, br, ar, 0, 0, 0);
      az  = __builtin_amdgcn_mfma_f32_16x16x32_bf16(a0, bz, az, 0, 0, 0);
      anh = __builtin_amdgcn_mfma_f32_16x16x32_bf16(a0, bn, anh, 0, 0, 0);
    }
    if (jok) {
      #pragma unroll
      for (int r = 0; r < 4; r++) {
        int row = quad * 4 + r;
        float rz  = ar[r] + u2f(guR[r]) + gr[r] + bhr;
        float zz  = az[r] + u2f(guZ[r]) + gz[r] + bhz;
        float inn = u2f(guN[r]) + gn[r];
        float hn  = anh[r] + bhn;
        float rg = fsigm(rz);
        float zg = fsigm(zz);
        float ng = ftanh(inn + rg * hn);
        float hold = b2f(Hs[cur][row][j]);
        float hnew = (1.f - zg) * ng + zg * hold;
        Hs[cur ^ 1][row][j] = __float2bfloat16((t < lens4[r]) ? hnew : hold);
      }
    }
    __syncthreads();
    cur ^= 1;
  }
  for (int i = tid; i < 16 * H_; i += 832) {
    int row = i / H_, jj = i % H_;
    hfin[((size_t)side * B_ + b0 + row) * H_ + jj] = b2f(Hs[cur][row][jj]);
  }
}

// ---------------------------------------------------------------- stable descending argsort of hist_len
__global__ __launch_bounds__(512) void k_argsort(
    const int* __restrict__ hlen0, const int* __restrict__ hlen1,
    int* __restrict__ idxbuf, float* __restrict__ dout)
{
  int side = blockIdx.x;
  const int* len = side ? hlen1 : hlen0;
  __shared__ int lens[B_];
  __shared__ int perm[B_];
  int tid = threadIdx.x;
  lens[tid] = len[tid];
  __syncthreads();
  int L = lens[tid];
  int rank = 0;
  for (int j = 0; j < B_; j++) {
    int Lj = lens[j];
    rank += (Lj > L) || (Lj == L && j < tid);
  }
  perm[rank] = tid;
  __syncthreads();
  idxbuf[side * B_ + tid] = perm[tid];
  size_t base = 1 + (size_t)2 * B_ * E_ + (side ? 0 : B_);
  dout[base + tid] = (float)perm[tid];
}

// ---------------------------------------------------------------- assemble pred-GEMM input rows (bf16, K padded to 640)
__global__ __launch_bounds__(256) void k_feat(
    const float* __restrict__ ent, const float* __restrict__ rel, const int* __restrict__ trip,
    const int* __restrict__ idxbuf, const float* __restrict__ hfin,
    bf16* __restrict__ xfeat)
{
  int i = blockIdx.x, p = blockIdx.y;
  int bi = idxbuf[(p == 0 ? 1 : 0) * B_ + i];
  int ent_id = (p == 0) ? trip[bi * 3 + 2] : trip[bi * 3 + 0];
  int rid = trip[bi * 3 + 1];
  const float* hsrc = hfin + (size_t)(p == 0 ? 1 : 0) * B_ * H_;
  bf16* x = xfeat + ((size_t)p * B_ + i) * 640;
  int h = threadIdx.x;
  if (h < H_) {
    x[h]          = __float2bfloat16(ent[(size_t)ent_id * H_ + h]);
    x[H_ + h]     = __float2bfloat16(hsrc[(size_t)bi * H_ + h]);
    x[2 * H_ + h] = __float2bfloat16(rel[(size_t)rid * H_ + h]);
  }
  if (h < 40) x[600 + h] = __float2bfloat16(0.f);
}

// ---------------------------------------------------------------- MFMA pred GEMM v8 (bf16 prepacked B + fused sumexp, plain stores)
// tile 256M x 64N x 64K, 512 threads / 8 waves (4Mx2N), wave = 64Mx32N -> acc[4][2].
// Epilogue: regular C stores (L2 write-combining; NT stores caused +40% WRITE_SIZE)
// + per-row exp-sum partials merged into sumexp via one atomicAdd per (row, wave).
__global__ __launch_bounds__(512) void k_gemm6(
    const bf16* __restrict__ Abf, const bf16* __restrict__ Wlin,
    const float* __restrict__ bias0, const float* __restrict__ bias1,
    float* __restrict__ dout, float* __restrict__ sumexp)
{
  int side = blockIdx.z;
  const bf16* Bm = Wlin + (size_t)side * EP_ * 640;
  const float* bias = side ? bias1 : bias0;
  float* C = dout + 1 + (size_t)side * B_ * E_;
  int mBase = blockIdx.x * 256;
  int m0 = side * B_ + mBase;
  int n0 = blockIdx.y * 64;

  __shared__ bf16 As[256][72];
  __shared__ bf16 Bs[64][72];

  int tid = threadIdx.x;
  int wave = tid >> 6, lane = tid & 63;
  int quad = lane >> 4, l15 = lane & 15;
  int wm = wave >> 1, wn = wave & 1;   // 4x2 wave grid

  f32x4 acc[4][2];
  #pragma unroll
  for (int mt = 0; mt < 4; mt++)
    #pragma unroll
    for (int nt = 0; nt < 2; nt++) acc[mt][nt] = (f32x4){0,0,0,0};

  int arow = tid >> 1, ac0 = (tid & 1) * 32;       // A: 256 rows, 32-elem halves
  int brow = tid >> 3, bc0 = (tid & 7) * 8;        // B: 64 rows, 8 bf16 each
  const bf16* asrc = Abf + (size_t)(m0 + arow) * 640 + ac0;
  const bf16* bsrc = Bm + (size_t)(n0 + brow) * 640 + bc0;

  for (int k0 = 0; k0 < 640; k0 += 64) {
    #pragma unroll
    for (int u = 0; u < 4; u++)
      *(short8*)&As[arow][ac0 + u * 8] = *(const short8*)&asrc[k0 + u * 8];
    *(short8*)&Bs[brow][bc0] = *(const short8*)&bsrc[k0];
    __syncthreads();
    #pragma unroll
    for (int ks = 0; ks < 2; ks++) {
      int kk = ks * 32 + quad * 8;
      short8 bfr[2];
      #pragma unroll
      for (int nt = 0; nt < 2; nt++)
        bfr[nt] = *(const short8*)&Bs[wn * 32 + nt * 16 + l15][kk];
      #pragma unroll
      for (int mt = 0; mt < 4; mt++) {
        short8 afr = *(const short8*)&As[wm * 64 + mt * 16 + l15][kk];
        #pragma unroll
        for (int nt = 0; nt < 2; nt++)
          acc[mt][nt] = __builtin_amdgcn_mfma_f32_16x16x32_bf16(afr, bfr[nt], acc[mt][nt], 0, 0, 0);
      }
    }
    __syncthreads();
  }

  // epilogue: row = mBase + wm*64 + mt*16 + quad*4 + r; col = n0 + wn*32 + nt*16 + l15
  float bv[2];
  int ncol[2];
  #pragma unroll
  for (int nt = 0; nt < 2; nt++) {
    ncol[nt] = n0 + wn * 32 + nt * 16 + l15;
    bv[nt] = (ncol[nt] < E_) ? bias[ncol[nt]] : 0.f;
  }
  #pragma unroll
  for (int mt = 0; mt < 4; mt++) {
    #pragma unroll
    for (int r = 0; r < 4; r++) {
      int mrow = mBase + wm * 64 + mt * 16 + quad * 4 + r;
      float p = 0.f;
      #pragma unroll
      for (int nt = 0; nt < 2; nt++) {
        if (ncol[nt] < E_) {
          float val = acc[mt][nt][r] + bv[nt];
          C[(size_t)mrow * E_ + ncol[nt]] = val;
          p += __expf(val);
        }
      }
      // reduce 32 cols of this row held by this wave (16 lanes x 2 cols)
      #pragma unroll
      for (int off = 8; off > 0; off >>= 1) p += __shfl_down(p, off, 16);
      if (l15 == 0) atomicAdd(&sumexp[side * B_ + mrow], p);
    }
  }
}

// ---------------------------------------------------------------- MFMA pred GEMM v5 (fp32 B fallback, ws too small)
__global__ __launch_bounds__(512) void k_gemm5(
    const bf16* __restrict__ Abf,
    const float* __restrict__ B0, const float* __restrict__ B1,
    const float* __restrict__ bias0, const float* __restrict__ bias1,
    float* __restrict__ dout, float* __restrict__ sumexp)
{
  int side = blockIdx.z;
  const float* Bm = side ? B1 : B0;
  const float* bias = side ? bias1 : bias0;
  float* C = dout + 1 + (size_t)side * B_ * E_;
  int mBase = blockIdx.x * 256;
  int m0 = side * B_ + mBase;
  int n0 = blockIdx.y * 64;

  __shared__ bf16 As[256][72];
  __shared__ bf16 Bs[64][72];

  int tid = threadIdx.x;
  int wave = tid >> 6, lane = tid & 63;
  int quad = lane >> 4, l15 = lane & 15;
  int wm = wave >> 1, wn = wave & 1;

  f32x4 acc[4][2];
  #pragma unroll
  for (int mt = 0; mt < 4; mt++)
    #pragma unroll
    for (int nt = 0; nt < 2; nt++) acc[mt][nt] = (f32x4){0,0,0,0};

  int arow = tid >> 1, ac0 = (tid & 1) * 32;
  int brow = tid >> 3, bc0 = (tid & 7) * 8;
  const bf16* asrc = Abf + (size_t)(m0 + arow) * 640 + ac0;
  int nsrc = n0 + brow; if (nsrc > E_ - 1) nsrc = E_ - 1;
  const float* bsrc = Bm + (size_t)nsrc * K3 + bc0;

  for (int k0 = 0; k0 < 640; k0 += 64) {
    #pragma unroll
    for (int u = 0; u < 4; u++)
      *(short8*)&As[arow][ac0 + u * 8] = *(const short8*)&asrc[k0 + u * 8];
    {
      int kb = k0 + bc0;
      if (kb + 8 <= K3) {
        float4 v0 = *(const float4*)&bsrc[k0];
        float4 v1 = *(const float4*)&bsrc[k0 + 4];
        Bs[brow][bc0 + 0] = __float2bfloat16(v0.x);
        Bs[brow][bc0 + 1] = __float2bfloat16(v0.y);
        Bs[brow][bc0 + 2] = __float2bfloat16(v0.z);
        Bs[brow][bc0 + 3] = __float2bfloat16(v0.w);
        Bs[brow][bc0 + 4] = __float2bfloat16(v1.x);
        Bs[brow][bc0 + 5] = __float2bfloat16(v1.y);
        Bs[brow][bc0 + 6] = __float2bfloat16(v1.z);
        Bs[brow][bc0 + 7] = __float2bfloat16(v1.w);
      } else {
        #pragma unroll
        for (int u = 0; u < 8; u++) {
          int k = kb + u;
          float v = (k < K3) ? bsrc[k0 + u] : 0.f;
          Bs[brow][bc0 + u] = __float2bfloat16(v);
        }
      }
    }
    __syncthreads();
    #pragma unroll
    for (int ks = 0; ks < 2; ks++) {
      int kk = ks * 32 + quad * 8;
      short8 bfr[2];
      #pragma unroll
      for (int nt = 0; nt < 2; nt++)
        bfr[nt] = *(const short8*)&Bs[wn * 32 + nt * 16 + l15][kk];
      #pragma unroll
      for (int mt = 0; mt < 4; mt++) {
        short8 afr = *(const short8*)&As[wm * 64 + mt * 16 + l15][kk];
        #pragma unroll
        for (int nt = 0; nt < 2; nt++)
          acc[mt][nt] = __builtin_amdgcn_mfma_f32_16x16x32_bf16(afr, bfr[nt], acc[mt][nt], 0, 0, 0);
      }
    }
    __syncthreads();
  }

  float bv[2];
  int ncol[2];
  #pragma unroll
  for (int nt = 0; nt < 2; nt++) {
    ncol[nt] = n0 + wn * 32 + nt * 16 + l15;
    bv[nt] = (ncol[nt] < E_) ? bias[ncol[nt]] : 0.f;
  }
  #pragma unroll
  for (int mt = 0; mt < 4; mt++) {
    #pragma unroll
    for (int r = 0; r < 4; r++) {
      int mrow = mBase + wm * 64 + mt * 16 + quad * 4 + r;
      float p = 0.f;
      #pragma unroll
      for (int nt = 0; nt < 2; nt++) {
        if (ncol[nt] < E_) {
          float val = acc[mt][nt][r] + bv[nt];
          C[(size_t)mrow * E_ + ncol[nt]] = val;
          p += __expf(val);
        }
      }
      #pragma unroll
      for (int off = 8; off > 0; off >>= 1) p += __shfl_down(p, off, 16);
      if (l15 == 0) atomicAdd(&sumexp[side * B_ + mrow], p);
    }
  }
}

// ---------------------------------------------------------------- final CE loss from fused sumexp
// one block: gather label logits + log(sumexp), reduce, write dout[0]
__global__ __launch_bounds__(256) void k_loss2(
    const float* __restrict__ dout_ro, const int* __restrict__ trip,
    const int* __restrict__ idxbuf, const float* __restrict__ sumexp,
    float* __restrict__ dout)
{
  int tid = threadIdx.x;
  float part = 0.f;
  for (int idx = tid; idx < 2 * B_; idx += 256) {
    int p = idx >> 9, i = idx & 511;
    int bi = idxbuf[(p == 0 ? 1 : 0) * B_ + i];
    int label = (p == 0) ? trip[bi * 3 + 0] : trip[bi * 3 + 2];
    float val = dout_ro[1 + (size_t)p * B_ * E_ + (size_t)i * E_ + label];
    float lp = val - logf(sumexp[p * B_ + i]);
    part += -lp / (float)B_;
  }
  __shared__ float ps[256];
  ps[tid] = part; __syncthreads();
  for (int st = 128; st > 0; st >>= 1) {
    if (tid < st) ps[tid] += ps[tid + st];
    __syncthreads();
  }
  if (tid == 0) dout[0] = ps[0];
}

// ----------------------------------------------------------------
extern "C" void kernel_launch(void* const* d_in, const int* in_sizes, int n_in,
                              void* d_out, int out_size, void* d_ws, size_t ws_size,
                              hipStream_t stream)
{
  const int* trip = (const int*)d_in[0];
  const int* s_ne = (const int*)d_in[1];
  const int* s_nl = (const int*)d_in[2];
  const int* s_hl = (const int*)d_in[3];
  const int* o_ne = (const int*)d_in[4];
  const int* o_nl = (const int*)d_in[5];
  const int* o_hl = (const int*)d_in[6];
  const float* ent = (const float*)d_in[7];
  const float* rel = (const float*)d_in[8];
  const float* aw_s = (const float*)d_in[9];
  const float* ab_s = (const float*)d_in[10];
  const float* v_s  = (const float*)d_in[11];
  const float* aw_o = (const float*)d_in[12];
  const float* ab_o = (const float*)d_in[13];
  const float* v_o  = (const float*)d_in[14];
  const float* sub_wih = (const float*)d_in[15];
  const float* sub_whh = (const float*)d_in[16];
  const float* sub_bih = (const float*)d_in[17];
  const float* sub_bhh = (const float*)d_in[18];
  const float* ob_wih  = (const float*)d_in[19];
  const float* ob_whh  = (const float*)d_in[20];
  const float* ob_bih  = (const float*)d_in[21];
  const float* ob_bhh  = (const float*)d_in[22];
  const float* lin_sub_w = (const float*)d_in[23];
  const float* lin_sub_b = (const float*)d_in[24];
  const float* lin_ob_w  = (const float*)d_in[25];
  const float* lin_ob_b  = (const float*)d_in[26];
  float* dout = (float*)d_out;

  // workspace carve — base ~34.6 MB, +25.7 MB for bf16 pred weights if it fits
  char* w = (char*)d_ws;
  bf16* ep2     = (bf16*)w;  w += (size_t)E_ * 400 * 2;           //  8,000,000 B
  bf16* stepb   = (bf16*)w;  w += (size_t)2 * B_ * T_ * 256 * 2;  //  5,242,880 B
  float* biasb  = (float*)w; w += (size_t)2 * B_ * H_ * 4;        //    819,200 B
  bf16* gibase  = (bf16*)w;  w += (size_t)2 * B_ * K3 * 2;        //  1,228,800 B
  float* hfin   = (float*)w; w += (size_t)2 * B_ * H_ * 4;        //    819,200 B
  bf16* xfeat   = (bf16*)w;  w += (size_t)1024 * 640 * 2;         //  1,310,720 B
  bf16* Wn2     = (bf16*)w;  w += (size_t)448 * 256 * 2;          //    229,376 B
  bf16* Wb2     = (bf16*)w;  w += (size_t)2 * 256 * 448 * 2;      //    458,752 B
  bf16* Wg2     = (bf16*)w;  w += (size_t)2 * 640 * 448 * 2;      //  1,146,880 B
  bf16* Wstep   = (bf16*)w;  w += (size_t)2 * 640 * 256 * 2;      //    655,360 B
  bf16* Whh2    = (bf16*)w;  w += (size_t)2 * 608 * 224 * 2;      //    544,768 B
  bf16* giall   = (bf16*)w;  w += (size_t)2 * B_ * T_ * 600 * 2;  // 12,288,000 B
  bf16* Abias   = (bf16*)w;  w += (size_t)2 * B_ * 448 * 2;       //    917,504 B
  bf16* Agi     = (bf16*)w;  w += (size_t)2 * B_ * 448 * 2;       //    917,504 B
  float* sumexp = (float*)w; w += 4096;                           // 2*B_ floats
  int* idxbuf   = (int*)w;   w += 4096;
  bf16* Wlin    = (bf16*)w;  w += (size_t)2 * EP_ * 640 * 2;      // 25,722,880 B
  bool useBf16B = ((size_t)(w - (char*)d_ws) <= ws_size);

  // fused packs (+ sumexp zero-init)
  k_packall<<<5761, 256, 0, stream>>>(aw_s, aw_o, sub_wih, ob_wih, sub_whh, ob_whh,
                                      ent, rel, trip, Wn2, Wb2, Wg2, Wstep, Whh2,
                                      Abias, Agi, sumexp);
  if (useBf16B)
    k_pack_lin<<<dim3(EP_, 2), 256, 0, stream>>>(lin_ob_w, lin_sub_w, Wlin);
  // ep2 = ent @ Wn.T   (M=10000, N=400, K=256pad)
  k_gg<true, true><<<dim3(79, 7, 1), 256, 0, stream>>>(
      (const void*)ent, Wn2, nullptr, nullptr, (void*)ep2,
      E_, 400, 256, 200, 0L, 0L, 0L, 400);
  // biasb = [se;re] @ Wa[:,200:600].T + ba   (M=512/side, N=200, K=448pad)
  k_gg<false, false><<<dim3(4, 4, 2), 256, 0, stream>>>(
      (const void*)Abias, Wb2, ab_s, ab_o, (void*)biasb,
      B_, 200, 448, 448, (long)B_ * 448, 256L * 448, (long)B_ * 200, 200);
  // gibase = [se;rr] @ Wih[:,200:600].T + bih   (M=512/side, N=600, K=448pad)
  k_gg<true, false><<<dim3(4, 10, 2), 256, 0, stream>>>(
      (const void*)Agi, Wg2, sub_bih, ob_bih, (void*)gibase,
      B_, 600, 448, 448, (long)B_ * 448, 640L * 448, (long)B_ * 600, 600);
  // attention (one block per (side,b,t))
  k_attn3<<<dim3(B_ * T_, 2), 256, 0, stream>>>(ent, s_ne, o_ne, s_nl, o_nl,
                                                s_hl, o_hl, v_s, v_o, ep2, biasb, stepb);
  // giall = step @ Wih[:, :200].T  for all (b,t)  (M=5120/side, N=600, K=256pad)
  k_gg<true, false><<<dim3(40, 10, 2), 256, 0, stream>>>(
      (const void*)stepb, Wstep, nullptr, nullptr, (void*)giall,
      B_ * T_, 600, 256, 256, (long)B_ * T_ * 256, 640L * 256, (long)B_ * T_ * 600, 600);
  // GRU (recurrent part only: K=224)
  k_gru4<<<dim3(B_ / 16, 2), 832, 0, stream>>>(giall, gibase, Whh2, sub_bhh, ob_bhh,
                                               s_hl, o_hl, hfin);
  k_argsort<<<2, 512, 0, stream>>>(s_hl, o_hl, idxbuf, dout);
  k_feat<<<dim3(B_, 2), 256, 0, stream>>>(ent, rel, trip, idxbuf, hfin, xfeat);
  // pred GEMM with fused sumexp (plain stores)
  if (useBf16B)
    k_gemm6<<<dim3(2, (E_ + 63) / 64, 2), 512, 0, stream>>>(
        xfeat, Wlin, lin_ob_b, lin_sub_b, dout, sumexp);
  else
    k_gemm5<<<dim3(2, (E_ + 63) / 64, 2), 512, 0, stream>>>(
        xfeat, lin_ob_w, lin_sub_w, lin_ob_b, lin_sub_b, dout, sumexp);
  k_loss2<<<1, 256, 0, stream>>>(dout, trip, idxbuf, sumexp, dout);
}

// Round 10
// 399.761 us; speedup vs baseline: 1.0544x; 1.0441x over previous
//
#include <hip/hip_runtime.h>
#include <hip/hip_bf16.h>
#include <math.h>

typedef __hip_bfloat16 bf16;
typedef __attribute__((ext_vector_type(8))) short short8;
typedef __attribute__((ext_vector_type(4))) float f32x4;

#define B_ 512
#define T_ 10
#define N_ 50
#define H_ 200
#define E_ 10000
#define R_ 200
#define K3 600   // 3*H
#define EP_ 10048  // E_ padded to 64 for guard-free B staging
#define NBLK_ 157  // (E_+63)/64 N-blocks in pred GEMM

__device__ __forceinline__ float b2f(bf16 x){ return __bfloat162float(x); }
__device__ __forceinline__ float u2f(unsigned short u){
  unsigned int x = ((unsigned int)u) << 16;
  return __builtin_bit_cast(float, x);
}
// fast sigmoid/tanh: v_exp_f32 + v_rcp_f32 (~1 ulp), instead of libm calls
__device__ __forceinline__ float fsigm(float x){
  return __builtin_amdgcn_rcpf(1.f + __expf(-x));
}
__device__ __forceinline__ float ftanh(float x){
  x = fminf(15.f, fmaxf(-15.f, x));
  float e = __expf(-2.f * x);
  return (1.f - e) * __builtin_amdgcn_rcpf(1.f + e);
}

// ---------------------------------------------------------------- fused weight packs (one dispatch)
// sections by blockIdx.x:
//  [0,448)      Wn2[448][256]
//  [448,960)    Wb2[2][256][448]
//  [960,2240)   Wg2[2][640][448]
//  [2240,3520)  Wstep[2][640][256]
//  [3520,4736)  Whh2[2][608][224]
//  [4736,5760)  Abias/Agi  (side*512+b rows of 448)
__global__ __launch_bounds__(256) void k_packall(
    const float* __restrict__ aw_s, const float* __restrict__ aw_o,
    const float* __restrict__ sub_wih, const float* __restrict__ ob_wih,
    const float* __restrict__ sub_whh, const float* __restrict__ ob_whh,
    const float* __restrict__ ent, const float* __restrict__ rel,
    const int* __restrict__ trip,
    bf16* __restrict__ Wn2, bf16* __restrict__ Wb2, bf16* __restrict__ Wg2,
    bf16* __restrict__ Wstep, bf16* __restrict__ Whh2,
    bf16* __restrict__ Ab, bf16* __restrict__ Ag)
{
  int bid = blockIdx.x;
  int tid = threadIdx.x;
  if (bid < 448) {
    int r = bid;
    const float* Wa = (r < 200) ? aw_s : aw_o;
    int g = (r < 200) ? r : r - 200;
    bf16* out = Wn2 + (size_t)r * 256;
    for (int k = tid; k < 256; k += 256) {
      float v = (r < 400 && k < 200) ? Wa[(size_t)g * K3 + k] : 0.f;
      out[k] = __float2bfloat16(v);
    }
  } else if (bid < 960) {
    int idx = bid - 448;
    int side = idx >> 8, r = idx & 255;
    const float* W = side ? aw_o : aw_s;
    bf16* out = Wb2 + ((size_t)side * 256 + r) * 448;
    for (int k = tid; k < 448; k += 256) {
      float v = (r < 200 && k < 400) ? W[(size_t)r * K3 + 200 + k] : 0.f;
      out[k] = __float2bfloat16(v);
    }
  } else if (bid < 2240) {
    int idx = bid - 960;
    int side = idx / 640, r = idx % 640;
    const float* W = side ? ob_wih : sub_wih;
    bf16* out = Wg2 + ((size_t)side * 640 + r) * 448;
    for (int k = tid; k < 448; k += 256) {
      float v = (r < 600 && k < 400) ? W[(size_t)r * K3 + 200 + k] : 0.f;
      out[k] = __float2bfloat16(v);
    }
  } else if (bid < 3520) {
    int idx = bid - 2240;
    int side = idx / 640, r = idx % 640;
    const float* W = side ? ob_wih : sub_wih;
    bf16* out = Wstep + ((size_t)side * 640 + r) * 256;
    for (int k = tid; k < 256; k += 256) {
      float v = (r < 600 && k < 200) ? W[(size_t)r * K3 + k] : 0.f;
      out[k] = __float2bfloat16(v);
    }
  } else if (bid < 4736) {
    int idx = bid - 3520;
    int side = idx / 608, r = idx % 608;
    const float* W = side ? ob_whh : sub_whh;
    bf16* out = Whh2 + ((size_t)side * 608 + r) * 224;
    for (int k = tid; k < 224; k += 256) {
      float v = (r < 600 && k < 200) ? W[(size_t)r * H_ + k] : 0.f;
      out[k] = __float2bfloat16(v);
    }
  } else {
    int idx = bid - 4736;
    int side = idx >> 9, b = idx & 511;
    int ids = trip[b * 3 + (side ? 2 : 0)];
    int rid = trip[b * 3 + 1];
    size_t ro = ((size_t)side * B_ + b) * 448;
    for (int k = tid; k < 448; k += 256) {
      float vb = 0.f, vg = 0.f;
      if (k < 200) { float e = ent[(size_t)ids * H_ + k]; vb = e; vg = e; }
      else if (k < 400) {
        vb = ent[(size_t)rid * H_ + (k - 200)];
        vg = rel[(size_t)rid * H_ + (k - 200)];
      }
      Ab[ro + k] = __float2bfloat16(vb);
      Ag[ro + k] = __float2bfloat16(vg);
    }
  }
}

// ---------------------------------------------------------------- pred-weight bf16 prepack
// Wlin[side][EP_][640]: rows<E_ = W[r][0:600], rest 0. side0=lin_ob_w, side1=lin_sub_w.
__global__ __launch_bounds__(256) void k_pack_lin(
    const float* __restrict__ W0, const float* __restrict__ W1, bf16* __restrict__ Wlin)
{
  int row = blockIdx.x, side = blockIdx.y;
  const float* W = side ? W1 : W0;
  bf16* out = Wlin + ((size_t)side * EP_ + row) * 640;
  for (int k = threadIdx.x; k < 640; k += 256) {
    float v = (row < E_ && k < K3) ? W[(size_t)row * K3 + k] : 0.f;
    out[k] = __float2bfloat16(v);
  }
}

// ---------------------------------------------------------------- generic MFMA GEMM
// C[m][n] = sum_k A[m][k]*B[n][k] (+ bias[n]); tile M=128, N=64, BK=64.
template<bool OUTBF, bool AF32>
__global__ __launch_bounds__(256) void k_gg(
    const void* __restrict__ Aptr, const bf16* __restrict__ Bptr,
    const float* __restrict__ bias0, const float* __restrict__ bias1,
    void* __restrict__ Cptr,
    int M, int Nout, int KP, int Acols,
    long Astride, long Bstride, long Cstride, int Nstride)
{
  int side = blockIdx.z;
  int m0 = blockIdx.x * 128, n0 = blockIdx.y * 64;

  __shared__ bf16 As[128][72];
  __shared__ bf16 Bs[64][72];

  int tid = threadIdx.x;
  int wave = tid >> 6, lane = tid & 63;
  int quad = lane >> 4, l15 = lane & 15;

  f32x4 acc[8];
  #pragma unroll
  for (int mt = 0; mt < 8; mt++) acc[mt] = (f32x4){0,0,0,0};

  int arow = tid >> 1, ac0 = (tid & 1) * 32;
  int gr = m0 + arow; if (gr > M - 1) gr = M - 1;
  int brow = tid >> 2, bc0 = (tid & 3) * 16;

  for (int k0 = 0; k0 < KP; k0 += 64) {
    if (AF32) {
      const float* src = (const float*)Aptr + (size_t)gr * Acols;
      #pragma unroll
      for (int u = 0; u < 8; u++) {
        int kk = k0 + ac0 + u * 4;
        float4 v;
        if (kk + 4 <= Acols) v = *(const float4*)&src[kk];
        else {
          v.x = (kk + 0 < Acols) ? src[kk + 0] : 0.f;
          v.y = (kk + 1 < Acols) ? src[kk + 1] : 0.f;
          v.z = (kk + 2 < Acols) ? src[kk + 2] : 0.f;
          v.w = (kk + 3 < Acols) ? src[kk + 3] : 0.f;
        }
        As[arow][ac0 + u * 4 + 0] = __float2bfloat16(v.x);
        As[arow][ac0 + u * 4 + 1] = __float2bfloat16(v.y);
        As[arow][ac0 + u * 4 + 2] = __float2bfloat16(v.z);
        As[arow][ac0 + u * 4 + 3] = __float2bfloat16(v.w);
      }
    } else {
      const bf16* src = (const bf16*)Aptr + (size_t)side * Astride + (size_t)gr * KP + k0 + ac0;
      #pragma unroll
      for (int u = 0; u < 4; u++)
        *(short8*)&As[arow][ac0 + u * 8] = *(const short8*)&src[u * 8];
    }
    {
      const bf16* src = Bptr + (size_t)side * Bstride + (size_t)(n0 + brow) * KP + k0 + bc0;
      *(short8*)&Bs[brow][bc0]     = *(const short8*)&src[0];
      *(short8*)&Bs[brow][bc0 + 8] = *(const short8*)&src[8];
    }
    __syncthreads();
    #pragma unroll
    for (int ks = 0; ks < 2; ks++) {
      int kk = ks * 32 + quad * 8;
      short8 bfr = *(const short8*)&Bs[wave * 16 + l15][kk];
      #pragma unroll
      for (int mt = 0; mt < 8; mt++) {
        short8 afr = *(const short8*)&As[mt * 16 + l15][kk];
        acc[mt] = __builtin_amdgcn_mfma_f32_16x16x32_bf16(afr, bfr, acc[mt], 0, 0, 0);
      }
    }
    __syncthreads();
  }

  int n = n0 + wave * 16 + l15;
  if (n < Nout) {
    float bv = bias0 ? (side ? bias1[n] : bias0[n]) : 0.f;
    #pragma unroll
    for (int mt = 0; mt < 8; mt++) {
      #pragma unroll
      for (int r = 0; r < 4; r++) {
        int m = m0 + mt * 16 + quad * 4 + r;
        if (m < M) {
          float val = acc[mt][r] + bv;
          if (OUTBF)
            ((bf16*)Cptr)[(size_t)side * Cstride + (size_t)m * Nstride + n] = __float2bfloat16(val);
          else
            ((float*)Cptr)[(size_t)side * Cstride + (size_t)m * Nstride + n] = val;
        }
      }
    }
  }
}

// ---------------------------------------------------------------- attention v3: one block per (side,b,t)
__global__ __launch_bounds__(256) void k_attn3(
    const float* __restrict__ ent,
    const int* __restrict__ neigh0, const int* __restrict__ neigh1,
    const int* __restrict__ nlen0, const int* __restrict__ nlen1,
    const int* __restrict__ hlen0, const int* __restrict__ hlen1,
    const float* __restrict__ v0, const float* __restrict__ v1,
    const bf16* __restrict__ ep2, const float* __restrict__ biasb,
    bf16* __restrict__ stepb)
{
  int side = blockIdx.y;
  int bt = blockIdx.x;
  int b = bt / T_, t = bt % T_;
  int hl = (side ? hlen1 : hlen0)[b];
  bf16* srow = stepb + (((size_t)side * B_ + b) * T_ + t) * 256;
  int tid = threadIdx.x;
  if (t >= hl) {     // masked timestep: zero row (uniform branch)
    srow[tid] = __float2bfloat16(0.f);
    return;
  }
  const int* neigh = side ? neigh1 : neigh0;
  const float* v = side ? v1 : v0;
  const float* brow = biasb + ((size_t)side * B_ + b) * H_;
  int nl = (side ? nlen1 : nlen0)[b * T_ + t];

  __shared__ float bsh[H_], vsh[H_], lg[64], wsh[64];
  __shared__ int nb[N_];
  if (tid < H_) { bsh[tid] = brow[tid]; vsh[tid] = v[tid]; }
  if (tid < N_) nb[tid] = neigh[((size_t)b * T_ + t) * N_ + tid];
  __syncthreads();

  int grp = tid >> 4;        // 0..15
  int l16 = tid & 15;

  float bs[13], vs[13];
  #pragma unroll
  for (int i = 0; i < 13; i++) {
    int g = l16 + i * 16;
    bool ok = (g < H_);
    bs[i] = ok ? bsh[g] : 0.f;
    vs[i] = ok ? vsh[g] : 0.f;
  }

  for (int n = grp; n < nl; n += 16) {
    const bf16* er = ep2 + (size_t)nb[n] * 400 + side * 200;
    float acc = 0.f;
    #pragma unroll
    for (int i = 0; i < 13; i++) {
      int g = l16 + i * 16;
      float e = (g < H_) ? b2f(er[g]) : 0.f;
      acc += ftanh(e + bs[i]) * vs[i];
    }
    #pragma unroll
    for (int off = 8; off > 0; off >>= 1) acc += __shfl_down(acc, off, 16);
    if (l16 == 0) lg[n] = acc;
  }
  __syncthreads();

  if (tid < 64) {
    float x = (tid < nl) ? lg[tid] : -1e30f;
    float m = x;
    #pragma unroll
    for (int off = 32; off > 0; off >>= 1) m = fmaxf(m, __shfl_down(m, off));
    m = __shfl(m, 0);
    float e = (tid < nl) ? __expf(x - m) : 0.f;
    float s = e;
    #pragma unroll
    for (int off = 32; off > 0; off >>= 1) s += __shfl_down(s, off);
    s = __shfl(s, 0);
    if (tid < N_) wsh[tid] = e / s;
  }
  __syncthreads();

  int h = tid;
  if (h < H_) {
    float a0 = 0.f, a1 = 0.f, a2 = 0.f, a3 = 0.f;
    int n = 0;
    for (; n + 4 <= nl; n += 4) {
      a0 += wsh[n + 0] * ent[(size_t)nb[n + 0] * H_ + h];
      a1 += wsh[n + 1] * ent[(size_t)nb[n + 1] * H_ + h];
      a2 += wsh[n + 2] * ent[(size_t)nb[n + 2] * H_ + h];
      a3 += wsh[n + 3] * ent[(size_t)nb[n + 3] * H_ + h];
    }
    for (; n < nl; n++) a0 += wsh[n] * ent[(size_t)nb[n] * H_ + h];
    srow[h] = __float2bfloat16((a0 + a1) + (a2 + a3));
  } else {
    srow[h] = __float2bfloat16(0.f);   // pad cols 200..255
  }
}

// ---------------------------------------------------------------- MFMA GRU v4
__global__ __launch_bounds__(832) void k_gru4(
    const bf16* __restrict__ giall, const bf16* __restrict__ gibase,
    const bf16* __restrict__ Whh2,
    const float* __restrict__ bhh0, const float* __restrict__ bhh1,
    const int* __restrict__ len0, const int* __restrict__ len1,
    float* __restrict__ hfin)
{
  int side = blockIdx.y;
  int b0 = blockIdx.x * 16;
  const bf16* gia = giall + ((size_t)side * B_ * T_ + (size_t)b0 * T_) * 600;
  const bf16* gib = gibase + ((size_t)side * B_ + b0) * K3;
  const bf16* Wh  = Whh2 + (size_t)side * 608 * 224;
  const float* bhh = side ? bhh1 : bhh0;
  const int* len = side ? len1 : len0;

  __shared__ __align__(16) bf16 Hs[2][16][232];

  int tid = threadIdx.x;
  int wave = tid >> 6, lane = tid & 63;
  int quad = lane >> 4, l15 = lane & 15;

  for (int i = tid; i < 2 * 16 * 232 / 8; i += 832) ((short8*)&Hs[0][0][0])[i] = (short8)0;

  int j0 = wave * 16;
  int j = j0 + l15;
  bool jok = (j < H_);
  float bhr = 0.f, bhz = 0.f, bhn = 0.f;
  float gr[4] = {}, gz[4] = {}, gn[4] = {};
  int lens4[4];
  #pragma unroll
  for (int r = 0; r < 4; r++) lens4[r] = len[b0 + quad * 4 + r];
  if (jok) {
    bhr = bhh[j]; bhz = bhh[H_ + j]; bhn = bhh[2 * H_ + j];
    #pragma unroll
    for (int r = 0; r < 4; r++) {
      const bf16* g = gib + (size_t)(quad * 4 + r) * K3;
      gr[r] = b2f(g[j]); gz[r] = b2f(g[H_ + j]); gn[r] = b2f(g[2 * H_ + j]);
    }
  }
  const bf16* wr = Wh + (size_t)j * 224;
  const bf16* wz = Wh + (size_t)(200 + j) * 224;
  const bf16* wn = Wh + (size_t)(400 + j) * 224;
  __syncthreads();

  int cur = 0;
  for (int t = 0; t < T_; t++) {
    unsigned short guR[4], guZ[4], guN[4];
    if (jok) {
      #pragma unroll
      for (int r = 0; r < 4; r++) {
        const unsigned short* g =
            (const unsigned short*)(gia + ((size_t)(quad * 4 + r) * T_ + t) * 600);
        guR[r] = g[j]; guZ[r] = g[200 + j]; guN[r] = g[400 + j];
      }
    }
    f32x4 ar = {0,0,0,0}, az = {0,0,0,0}, anh = {0,0,0,0};
    #pragma unroll
    for (int ks = 0; ks < 7; ks++) {
      int kk = ks * 32 + quad * 8;
      short8 a0 = *(const short8*)&Hs[cur][l15][kk];
      short8 br = *(const short8*)&wr[kk];
      short8 bz = *(const short8*)&wz[kk];
      short8 bn = *(const short8*)&wn[kk];
      ar  = __builtin_amdgcn_mfma_f32_16x16x32_bf16(a0, br, ar, 0, 0, 0);
      az  = __builtin_amdgcn_mfma_f32_16x16x32_bf16(a0, bz, az, 0, 0, 0);
      anh = __builtin_amdgcn_mfma_f32_16x16x32_bf16(a0, bn, anh, 0, 0, 0);
    }
    if (jok) {
      #pragma unroll
      for (int r = 0; r < 4; r++) {
        int row = quad * 4 + r;
        float rz  = ar[r] + u2f(guR[r]) + gr[r] + bhr;
        float zz  = az[r] + u2f(guZ[r]) + gz[r] + bhz;
        float inn = u2f(guN[r]) + gn[r];
        float hn  = anh[r] + bhn;
        float rg = fsigm(rz);
        float zg = fsigm(zz);
        float ng = ftanh(inn + rg * hn);
        float hold = b2f(Hs[cur][row][j]);
        float hnew = (1.f - zg) * ng + zg * hold;
        Hs[cur ^ 1][row][j] = __float2bfloat16((t < lens4[r]) ? hnew : hold);
      }
    }
    __syncthreads();
    cur ^= 1;
  }
  for (int i = tid; i < 16 * H_; i += 832) {
    int row = i / H_, jj = i % H_;
    hfin[((size_t)side * B_ + b0 + row) * H_ + jj] = b2f(Hs[cur][row][jj]);
  }
}

// ---------------------------------------------------------------- stable descending argsort of hist_len
__global__ __launch_bounds__(512) void k_argsort(
    const int* __restrict__ hlen0, const int* __restrict__ hlen1,
    int* __restrict__ idxbuf, float* __restrict__ dout)
{
  int side = blockIdx.x;
  const int* len = side ? hlen1 : hlen0;
  __shared__ int lens[B_];
  __shared__ int perm[B_];
  int tid = threadIdx.x;
  lens[tid] = len[tid];
  __syncthreads();
  int L = lens[tid];
  int rank = 0;
  for (int j = 0; j < B_; j++) {
    int Lj = lens[j];
    rank += (Lj > L) || (Lj == L && j < tid);
  }
  perm[rank] = tid;
  __syncthreads();
  idxbuf[side * B_ + tid] = perm[tid];
  size_t base = 1 + (size_t)2 * B_ * E_ + (side ? 0 : B_);
  dout[base + tid] = (float)perm[tid];
}

// ---------------------------------------------------------------- assemble pred-GEMM input rows (bf16, K padded to 640)
__global__ __launch_bounds__(256) void k_feat(
    const float* __restrict__ ent, const float* __restrict__ rel, const int* __restrict__ trip,
    const int* __restrict__ idxbuf, const float* __restrict__ hfin,
    bf16* __restrict__ xfeat)
{
  int i = blockIdx.x, p = blockIdx.y;
  int bi = idxbuf[(p == 0 ? 1 : 0) * B_ + i];
  int ent_id = (p == 0) ? trip[bi * 3 + 2] : trip[bi * 3 + 0];
  int rid = trip[bi * 3 + 1];
  const float* hsrc = hfin + (size_t)(p == 0 ? 1 : 0) * B_ * H_;
  bf16* x = xfeat + ((size_t)p * B_ + i) * 640;
  int h = threadIdx.x;
  if (h < H_) {
    x[h]          = __float2bfloat16(ent[(size_t)ent_id * H_ + h]);
    x[H_ + h]     = __float2bfloat16(hsrc[(size_t)bi * H_ + h]);
    x[2 * H_ + h] = __float2bfloat16(rel[(size_t)rid * H_ + h]);
  }
  if (h < 40) x[600 + h] = __float2bfloat16(0.f);
}

// ---------------------------------------------------------------- MFMA pred GEMM v9 (bf16 B + fused sumexp, NO atomics)
// tile 256M x 64N x 64K, 512 threads / 8 waves (4Mx2N), wave = 64Mx32N -> acc[4][2].
// Epilogue: plain C stores; per-row exp partials combined across the 2 wn-waves in LDS,
// then ONE coalesced store per (row, n-block) into pexp[side][nblk][512]. Zero atomics.
__global__ __launch_bounds__(512) void k_gemm6(
    const bf16* __restrict__ Abf, const bf16* __restrict__ Wlin,
    const float* __restrict__ bias0, const float* __restrict__ bias1,
    float* __restrict__ dout, float* __restrict__ pexp)
{
  int side = blockIdx.z;
  const bf16* Bm = Wlin + (size_t)side * EP_ * 640;
  const float* bias = side ? bias1 : bias0;
  float* C = dout + 1 + (size_t)side * B_ * E_;
  int mBase = blockIdx.x * 256;
  int m0 = side * B_ + mBase;
  int n0 = blockIdx.y * 64;

  __shared__ bf16 As[256][72];
  __shared__ bf16 Bs[64][72];
  __shared__ float Ps[2][256];   // [wn][row_local] exp partials

  int tid = threadIdx.x;
  int wave = tid >> 6, lane = tid & 63;
  int quad = lane >> 4, l15 = lane & 15;
  int wm = wave >> 1, wn = wave & 1;   // 4x2 wave grid

  f32x4 acc[4][2];
  #pragma unroll
  for (int mt = 0; mt < 4; mt++)
    #pragma unroll
    for (int nt = 0; nt < 2; nt++) acc[mt][nt] = (f32x4){0,0,0,0};

  int arow = tid >> 1, ac0 = (tid & 1) * 32;       // A: 256 rows, 32-elem halves
  int brow = tid >> 3, bc0 = (tid & 7) * 8;        // B: 64 rows, 8 bf16 each
  const bf16* asrc = Abf + (size_t)(m0 + arow) * 640 + ac0;
  const bf16* bsrc = Bm + (size_t)(n0 + brow) * 640 + bc0;

  for (int k0 = 0; k0 < 640; k0 += 64) {
    #pragma unroll
    for (int u = 0; u < 4; u++)
      *(short8*)&As[arow][ac0 + u * 8] = *(const short8*)&asrc[k0 + u * 8];
    *(short8*)&Bs[brow][bc0] = *(const short8*)&bsrc[k0];
    __syncthreads();
    #pragma unroll
    for (int ks = 0; ks < 2; ks++) {
      int kk = ks * 32 + quad * 8;
      short8 bfr[2];
      #pragma unroll
      for (int nt = 0; nt < 2; nt++)
        bfr[nt] = *(const short8*)&Bs[wn * 32 + nt * 16 + l15][kk];
      #pragma unroll
      for (int mt = 0; mt < 4; mt++) {
        short8 afr = *(const short8*)&As[wm * 64 + mt * 16 + l15][kk];
        #pragma unroll
        for (int nt = 0; nt < 2; nt++)
          acc[mt][nt] = __builtin_amdgcn_mfma_f32_16x16x32_bf16(afr, bfr[nt], acc[mt][nt], 0, 0, 0);
      }
    }
    __syncthreads();
  }

  // epilogue: row_local = wm*64 + mt*16 + quad*4 + r; col = n0 + wn*32 + nt*16 + l15
  float bv[2];
  int ncol[2];
  #pragma unroll
  for (int nt = 0; nt < 2; nt++) {
    ncol[nt] = n0 + wn * 32 + nt * 16 + l15;
    bv[nt] = (ncol[nt] < E_) ? bias[ncol[nt]] : 0.f;
  }
  #pragma unroll
  for (int mt = 0; mt < 4; mt++) {
    #pragma unroll
    for (int r = 0; r < 4; r++) {
      int rloc = wm * 64 + mt * 16 + quad * 4 + r;
      int mrow = mBase + rloc;
      float p = 0.f;
      #pragma unroll
      for (int nt = 0; nt < 2; nt++) {
        if (ncol[nt] < E_) {
          float val = acc[mt][nt][r] + bv[nt];
          C[(size_t)mrow * E_ + ncol[nt]] = val;
          p += __expf(val);
        }
      }
      // reduce 32 cols of this row held by this wave (16 lanes x 2 cols)
      #pragma unroll
      for (int off = 8; off > 0; off >>= 1) p += __shfl_down(p, off, 16);
      if (l15 == 0) Ps[wn][rloc] = p;
    }
  }
  __syncthreads();
  if (tid < 256) {
    float p = Ps[0][tid] + Ps[1][tid];
    pexp[((size_t)side * NBLK_ + blockIdx.y) * 512 + mBase + tid] = p;
  }
}

// ---------------------------------------------------------------- MFMA pred GEMM v5 (fp32 B fallback, ws too small)
__global__ __launch_bounds__(512) void k_gemm5(
    const bf16* __restrict__ Abf,
    const float* __restrict__ B0, const float* __restrict__ B1,
    const float* __restrict__ bias0, const float* __restrict__ bias1,
    float* __restrict__ dout, float* __restrict__ pexp)
{
  int side = blockIdx.z;
  const float* Bm = side ? B1 : B0;
  const float* bias = side ? bias1 : bias0;
  float* C = dout + 1 + (size_t)side * B_ * E_;
  int mBase = blockIdx.x * 256;
  int m0 = side * B_ + mBase;
  int n0 = blockIdx.y * 64;

  __shared__ bf16 As[256][72];
  __shared__ bf16 Bs[64][72];
  __shared__ float Ps[2][256];

  int tid = threadIdx.x;
  int wave = tid >> 6, lane = tid & 63;
  int quad = lane >> 4, l15 = lane & 15;
  int wm = wave >> 1, wn = wave & 1;

  f32x4 acc[4][2];
  #pragma unroll
  for (int mt = 0; mt < 4; mt++)
    #pragma unroll
    for (int nt = 0; nt < 2; nt++) acc[mt][nt] = (f32x4){0,0,0,0};

  int arow = tid >> 1, ac0 = (tid & 1) * 32;
  int brow = tid >> 3, bc0 = (tid & 7) * 8;
  const bf16* asrc = Abf + (size_t)(m0 + arow) * 640 + ac0;
  int nsrc = n0 + brow; if (nsrc > E_ - 1) nsrc = E_ - 1;
  const float* bsrc = Bm + (size_t)nsrc * K3 + bc0;

  for (int k0 = 0; k0 < 640; k0 += 64) {
    #pragma unroll
    for (int u = 0; u < 4; u++)
      *(short8*)&As[arow][ac0 + u * 8] = *(const short8*)&asrc[k0 + u * 8];
    {
      int kb = k0 + bc0;
      if (kb + 8 <= K3) {
        float4 v0 = *(const float4*)&bsrc[k0];
        float4 v1 = *(const float4*)&bsrc[k0 + 4];
        Bs[brow][bc0 + 0] = __float2bfloat16(v0.x);
        Bs[brow][bc0 + 1] = __float2bfloat16(v0.y);
        Bs[brow][bc0 + 2] = __float2bfloat16(v0.z);
        Bs[brow][bc0 + 3] = __float2bfloat16(v0.w);
        Bs[brow][bc0 + 4] = __float2bfloat16(v1.x);
        Bs[brow][bc0 + 5] = __float2bfloat16(v1.y);
        Bs[brow][bc0 + 6] = __float2bfloat16(v1.z);
        Bs[brow][bc0 + 7] = __float2bfloat16(v1.w);
      } else {
        #pragma unroll
        for (int u = 0; u < 8; u++) {
          int k = kb + u;
          float v = (k < K3) ? bsrc[k0 + u] : 0.f;
          Bs[brow][bc0 + u] = __float2bfloat16(v);
        }
      }
    }
    __syncthreads();
    #pragma unroll
    for (int ks = 0; ks < 2; ks++) {
      int kk = ks * 32 + quad * 8;
      short8 bfr[2];
      #pragma unroll
      for (int nt = 0; nt < 2; nt++)
        bfr[nt] = *(const short8*)&Bs[wn * 32 + nt * 16 + l15][kk];
      #pragma unroll
      for (int mt = 0; mt < 4; mt++) {
        short8 afr = *(const short8*)&As[wm * 64 + mt * 16 + l15][kk];
        #pragma unroll
        for (int nt = 0; nt < 2; nt++)
          acc[mt][nt] = __builtin_amdgcn_mfma_f32_16x16x32_bf16(afr, bfr[nt], acc[mt][nt], 0, 0, 0);
      }
    }
    __syncthreads();
  }

  float bv[2];
  int ncol[2];
  #pragma unroll
  for (int nt = 0; nt < 2; nt++) {
    ncol[nt] = n0 + wn * 32 + nt * 16 + l15;
    bv[nt] = (ncol[nt] < E_) ? bias[ncol[nt]] : 0.f;
  }
  #pragma unroll
  for (int mt = 0; mt < 4; mt++) {
    #pragma unroll
    for (int r = 0; r < 4; r++) {
      int rloc = wm * 64 + mt * 16 + quad * 4 + r;
      int mrow = mBase + rloc;
      float p = 0.f;
      #pragma unroll
      for (int nt = 0; nt < 2; nt++) {
        if (ncol[nt] < E_) {
          float val = acc[mt][nt][r] + bv[nt];
          C[(size_t)mrow * E_ + ncol[nt]] = val;
          p += __expf(val);
        }
      }
      #pragma unroll
      for (int off = 8; off > 0; off >>= 1) p += __shfl_down(p, off, 16);
      if (l15 == 0) Ps[wn][rloc] = p;
    }
  }
  __syncthreads();
  if (tid < 256) {
    float p = Ps[0][tid] + Ps[1][tid];
    pexp[((size_t)side * NBLK_ + blockIdx.y) * 512 + mBase + tid] = p;
  }
}

// ---------------------------------------------------------------- final CE loss from pexp partials
// one block, 1024 threads: thread = one (p,i) row; sum 157 partials (coalesced),
// add label logit, reduce, write dout[0]
__global__ __launch_bounds__(1024) void k_loss3(
    const float* __restrict__ dout_ro, const int* __restrict__ trip,
    const int* __restrict__ idxbuf, const float* __restrict__ pexp,
    float* __restrict__ dout)
{
  int tid = threadIdx.x;            // 0..1023
  int p = tid >> 9, i = tid & 511;
  float s = 0.f;
  for (int nb = 0; nb < NBLK_; nb++)
    s += pexp[((size_t)p * NBLK_ + nb) * 512 + i];
  int bi = idxbuf[(p == 0 ? 1 : 0) * B_ + i];
  int label = (p == 0) ? trip[bi * 3 + 0] : trip[bi * 3 + 2];
  float val = dout_ro[1 + (size_t)p * B_ * E_ + (size_t)i * E_ + label];
  float part = -(val - logf(s)) / (float)B_;
  __shared__ float ps[1024];
  ps[tid] = part; __syncthreads();
  for (int st = 512; st > 0; st >>= 1) {
    if (tid < st) ps[tid] += ps[tid + st];
    __syncthreads();
  }
  if (tid == 0) dout[0] = ps[0];
}

// ----------------------------------------------------------------
extern "C" void kernel_launch(void* const* d_in, const int* in_sizes, int n_in,
                              void* d_out, int out_size, void* d_ws, size_t ws_size,
                              hipStream_t stream)
{
  const int* trip = (const int*)d_in[0];
  const int* s_ne = (const int*)d_in[1];
  const int* s_nl = (const int*)d_in[2];
  const int* s_hl = (const int*)d_in[3];
  const int* o_ne = (const int*)d_in[4];
  const int* o_nl = (const int*)d_in[5];
  const int* o_hl = (const int*)d_in[6];
  const float* ent = (const float*)d_in[7];
  const float* rel = (const float*)d_in[8];
  const float* aw_s = (const float*)d_in[9];
  const float* ab_s = (const float*)d_in[10];
  const float* v_s  = (const float*)d_in[11];
  const float* aw_o = (const float*)d_in[12];
  const float* ab_o = (const float*)d_in[13];
  const float* v_o  = (const float*)d_in[14];
  const float* sub_wih = (const float*)d_in[15];
  const float* sub_whh = (const float*)d_in[16];
  const float* sub_bih = (const float*)d_in[17];
  const float* sub_bhh = (const float*)d_in[18];
  const float* ob_wih  = (const float*)d_in[19];
  const float* ob_whh  = (const float*)d_in[20];
  const float* ob_bih  = (const float*)d_in[21];
  const float* ob_bhh  = (const float*)d_in[22];
  const float* lin_sub_w = (const float*)d_in[23];
  const float* lin_sub_b = (const float*)d_in[24];
  const float* lin_ob_w  = (const float*)d_in[25];
  const float* lin_ob_b  = (const float*)d_in[26];
  float* dout = (float*)d_out;

  // workspace carve — base ~35.2 MB, +25.7 MB for bf16 pred weights if it fits
  char* w = (char*)d_ws;
  bf16* ep2     = (bf16*)w;  w += (size_t)E_ * 400 * 2;           //  8,000,000 B
  bf16* stepb   = (bf16*)w;  w += (size_t)2 * B_ * T_ * 256 * 2;  //  5,242,880 B
  float* biasb  = (float*)w; w += (size_t)2 * B_ * H_ * 4;        //    819,200 B
  bf16* gibase  = (bf16*)w;  w += (size_t)2 * B_ * K3 * 2;        //  1,228,800 B
  float* hfin   = (float*)w; w += (size_t)2 * B_ * H_ * 4;        //    819,200 B
  bf16* xfeat   = (bf16*)w;  w += (size_t)1024 * 640 * 2;         //  1,310,720 B
  bf16* Wn2     = (bf16*)w;  w += (size_t)448 * 256 * 2;          //    229,376 B
  bf16* Wb2     = (bf16*)w;  w += (size_t)2 * 256 * 448 * 2;      //    458,752 B
  bf16* Wg2     = (bf16*)w;  w += (size_t)2 * 640 * 448 * 2;      //  1,146,880 B
  bf16* Wstep   = (bf16*)w;  w += (size_t)2 * 640 * 256 * 2;      //    655,360 B
  bf16* Whh2    = (bf16*)w;  w += (size_t)2 * 608 * 224 * 2;      //    544,768 B
  bf16* giall   = (bf16*)w;  w += (size_t)2 * B_ * T_ * 600 * 2;  // 12,288,000 B
  bf16* Abias   = (bf16*)w;  w += (size_t)2 * B_ * 448 * 2;       //    917,504 B
  bf16* Agi     = (bf16*)w;  w += (size_t)2 * B_ * 448 * 2;       //    917,504 B
  float* pexp   = (float*)w; w += (size_t)2 * NBLK_ * 512 * 4;    //    643,072 B
  int* idxbuf   = (int*)w;   w += 4096;
  bf16* Wlin    = (bf16*)w;  w += (size_t)2 * EP_ * 640 * 2;      // 25,722,880 B
  bool useBf16B = ((size_t)(w - (char*)d_ws) <= ws_size);

  // fused packs
  k_packall<<<5760, 256, 0, stream>>>(aw_s, aw_o, sub_wih, ob_wih, sub_whh, ob_whh,
                                      ent, rel, trip, Wn2, Wb2, Wg2, Wstep, Whh2,
                                      Abias, Agi);
  if (useBf16B)
    k_pack_lin<<<dim3(EP_, 2), 256, 0, stream>>>(lin_ob_w, lin_sub_w, Wlin);
  // ep2 = ent @ Wn.T   (M=10000, N=400, K=256pad)
  k_gg<true, true><<<dim3(79, 7, 1), 256, 0, stream>>>(
      (const void*)ent, Wn2, nullptr, nullptr, (void*)ep2,
      E_, 400, 256, 200, 0L, 0L, 0L, 400);
  // biasb = [se;re] @ Wa[:,200:600].T + ba   (M=512/side, N=200, K=448pad)
  k_gg<false, false><<<dim3(4, 4, 2), 256, 0, stream>>>(
      (const void*)Abias, Wb2, ab_s, ab_o, (void*)biasb,
      B_, 200, 448, 448, (long)B_ * 448, 256L * 448, (long)B_ * 200, 200);
  // gibase = [se;rr] @ Wih[:,200:600].T + bih   (M=512/side, N=600, K=448pad)
  k_gg<true, false><<<dim3(4, 10, 2), 256, 0, stream>>>(
      (const void*)Agi, Wg2, sub_bih, ob_bih, (void*)gibase,
      B_, 600, 448, 448, (long)B_ * 448, 640L * 448, (long)B_ * 600, 600);
  // attention (one block per (side,b,t))
  k_attn3<<<dim3(B_ * T_, 2), 256, 0, stream>>>(ent, s_ne, o_ne, s_nl, o_nl,
                                                s_hl, o_hl, v_s, v_o, ep2, biasb, stepb);
  // giall = step @ Wih[:, :200].T  for all (b,t)  (M=5120/side, N=600, K=256pad)
  k_gg<true, false><<<dim3(40, 10, 2), 256, 0, stream>>>(
      (const void*)stepb, Wstep, nullptr, nullptr, (void*)giall,
      B_ * T_, 600, 256, 256, (long)B_ * T_ * 256, 640L * 256, (long)B_ * T_ * 600, 600);
  // GRU (recurrent part only: K=224)
  k_gru4<<<dim3(B_ / 16, 2), 832, 0, stream>>>(giall, gibase, Whh2, sub_bhh, ob_bhh,
                                               s_hl, o_hl, hfin);
  k_argsort<<<2, 512, 0, stream>>>(s_hl, o_hl, idxbuf, dout);
  k_feat<<<dim3(B_, 2), 256, 0, stream>>>(ent, rel, trip, idxbuf, hfin, xfeat);
  // pred GEMM with fused exp-partials (no atomics)
  if (useBf16B)
    k_gemm6<<<dim3(2, NBLK_, 2), 512, 0, stream>>>(
        xfeat, Wlin, lin_ob_b, lin_sub_b, dout, pexp);
  else
    k_gemm5<<<dim3(2, NBLK_, 2), 512, 0, stream>>>(
        xfeat, lin_ob_w, lin_sub_w, lin_ob_b, lin_sub_b, dout, pexp);
  k_loss3<<<1, 1024, 0, stream>>>(dout, trip, idxbuf, pexp, dout);
}

// Round 11
// 359.019 us; speedup vs baseline: 1.1740x; 1.1135x over previous
//
#include <hip/hip_runtime.h>
#include <hip/hip_bf16.h>
#include <math.h>

typedef __hip_bfloat16 bf16;
typedef __attribute__((ext_vector_type(8))) short short8;
typedef __attribute__((ext_vector_type(4))) float f32x4;

#define B_ 512
#define T_ 10
#define N_ 50
#define H_ 200
#define E_ 10000
#define R_ 200
#define K3 600   // 3*H
#define EP_ 10048  // E_ padded to 64 for guard-free B staging
#define NBLK_ 157  // (E_+63)/64 N-blocks in pred GEMM

__device__ __forceinline__ float b2f(bf16 x){ return __bfloat162float(x); }
__device__ __forceinline__ float u2f(unsigned short u){
  unsigned int x = ((unsigned int)u) << 16;
  return __builtin_bit_cast(float, x);
}
// fast sigmoid/tanh: v_exp_f32 + v_rcp_f32 (~1 ulp), instead of libm calls
__device__ __forceinline__ float fsigm(float x){
  return __builtin_amdgcn_rcpf(1.f + __expf(-x));
}
__device__ __forceinline__ float ftanh(float x){
  x = fminf(15.f, fmaxf(-15.f, x));
  float e = __expf(-2.f * x);
  return (1.f - e) * __builtin_amdgcn_rcpf(1.f + e);
}

// ---------------------------------------------------------------- mega pack (one dispatch)
// sections by blockIdx.x:
//  [0,448)          Wn2[448][256]
//  [448,960)        Wb2[2][256][448]
//  [960,2240)       Wg2[2][640][448]
//  [2240,3520)      Wstep[2][640][256]
//  [3520,4736)      Whh2[2][608][224]
//  [4736,5760)      Abias/Agi
//  [5760,25856)     Wlin bf16 prepack (if useBf16B)
//  [25856,25858)    argsort per side (256 thr, 2 elems each) + perm->dout
__global__ __launch_bounds__(256) void k_packall(
    const float* __restrict__ aw_s, const float* __restrict__ aw_o,
    const float* __restrict__ sub_wih, const float* __restrict__ ob_wih,
    const float* __restrict__ sub_whh, const float* __restrict__ ob_whh,
    const float* __restrict__ ent, const float* __restrict__ rel,
    const int* __restrict__ trip,
    const float* __restrict__ lin_ob_w, const float* __restrict__ lin_sub_w,
    const int* __restrict__ hlen0, const int* __restrict__ hlen1,
    bf16* __restrict__ Wn2, bf16* __restrict__ Wb2, bf16* __restrict__ Wg2,
    bf16* __restrict__ Wstep, bf16* __restrict__ Whh2,
    bf16* __restrict__ Ab, bf16* __restrict__ Ag,
    bf16* __restrict__ Wlin, int useBf16B,
    int* __restrict__ idxbuf, float* __restrict__ dout)
{
  int bid = blockIdx.x;
  int tid = threadIdx.x;
  if (bid < 448) {
    int r = bid;
    const float* Wa = (r < 200) ? aw_s : aw_o;
    int g = (r < 200) ? r : r - 200;
    bf16* out = Wn2 + (size_t)r * 256;
    for (int k = tid; k < 256; k += 256) {
      float v = (r < 400 && k < 200) ? Wa[(size_t)g * K3 + k] : 0.f;
      out[k] = __float2bfloat16(v);
    }
  } else if (bid < 960) {
    int idx = bid - 448;
    int side = idx >> 8, r = idx & 255;
    const float* W = side ? aw_o : aw_s;
    bf16* out = Wb2 + ((size_t)side * 256 + r) * 448;
    for (int k = tid; k < 448; k += 256) {
      float v = (r < 200 && k < 400) ? W[(size_t)r * K3 + 200 + k] : 0.f;
      out[k] = __float2bfloat16(v);
    }
  } else if (bid < 2240) {
    int idx = bid - 960;
    int side = idx / 640, r = idx % 640;
    const float* W = side ? ob_wih : sub_wih;
    bf16* out = Wg2 + ((size_t)side * 640 + r) * 448;
    for (int k = tid; k < 448; k += 256) {
      float v = (r < 600 && k < 400) ? W[(size_t)r * K3 + 200 + k] : 0.f;
      out[k] = __float2bfloat16(v);
    }
  } else if (bid < 3520) {
    int idx = bid - 2240;
    int side = idx / 640, r = idx % 640;
    const float* W = side ? ob_wih : sub_wih;
    bf16* out = Wstep + ((size_t)side * 640 + r) * 256;
    for (int k = tid; k < 256; k += 256) {
      float v = (r < 600 && k < 200) ? W[(size_t)r * K3 + k] : 0.f;
      out[k] = __float2bfloat16(v);
    }
  } else if (bid < 4736) {
    int idx = bid - 3520;
    int side = idx / 608, r = idx % 608;
    const float* W = side ? ob_whh : sub_whh;
    bf16* out = Whh2 + ((size_t)side * 608 + r) * 224;
    for (int k = tid; k < 224; k += 256) {
      float v = (r < 600 && k < 200) ? W[(size_t)r * H_ + k] : 0.f;
      out[k] = __float2bfloat16(v);
    }
  } else if (bid < 5760) {
    int idx = bid - 4736;
    int side = idx >> 9, b = idx & 511;
    int ids = trip[b * 3 + (side ? 2 : 0)];
    int rid = trip[b * 3 + 1];
    size_t ro = ((size_t)side * B_ + b) * 448;
    for (int k = tid; k < 448; k += 256) {
      float vb = 0.f, vg = 0.f;
      if (k < 200) { float e = ent[(size_t)ids * H_ + k]; vb = e; vg = e; }
      else if (k < 400) {
        vb = ent[(size_t)rid * H_ + (k - 200)];
        vg = rel[(size_t)rid * H_ + (k - 200)];
      }
      Ab[ro + k] = __float2bfloat16(vb);
      Ag[ro + k] = __float2bfloat16(vg);
    }
  } else if (bid < 25856) {
    if (!useBf16B) return;
    int idx = bid - 5760;
    int side = idx / EP_, row = idx % EP_;
    const float* W = side ? lin_sub_w : lin_ob_w;
    bf16* out = Wlin + ((size_t)side * EP_ + row) * 640;
    for (int k = tid; k < 640; k += 256) {
      float v = (row < E_ && k < K3) ? W[(size_t)row * K3 + k] : 0.f;
      out[k] = __float2bfloat16(v);
    }
  } else {
    int side = bid - 25856;
    const int* len = side ? hlen1 : hlen0;
    __shared__ int lens[B_];
    __shared__ int perm[B_];
    lens[tid] = len[tid];
    lens[tid + 256] = len[tid + 256];
    __syncthreads();
    #pragma unroll
    for (int e = 0; e < 2; e++) {
      int i = tid + e * 256;
      int L = lens[i];
      int rank = 0;
      for (int j = 0; j < B_; j++) {
        int Lj = lens[j];
        rank += (Lj > L) || (Lj == L && j < i);
      }
      perm[rank] = i;
    }
    __syncthreads();
    size_t base = 1 + (size_t)2 * B_ * E_ + (side ? 0 : B_);
    idxbuf[side * B_ + tid] = perm[tid];
    idxbuf[side * B_ + tid + 256] = perm[tid + 256];
    dout[base + tid] = (float)perm[tid];
    dout[base + tid + 256] = (float)perm[tid + 256];
  }
}

// ---------------------------------------------------------------- generic MFMA GEMM body
// C[m][n] = sum_k A[m][k]*B[n][k] (+ bias[n]); tile M=128, N=64, BK=64.
template<bool OUTBF, bool AF32>
__device__ __forceinline__ void ggbody(
    bf16 (*As)[72], bf16 (*Bs)[72],
    const void* __restrict__ Aptr, const bf16* __restrict__ Bptr,
    const float* __restrict__ bias0, const float* __restrict__ bias1,
    void* __restrict__ Cptr,
    int M, int Nout, int KP, int Acols,
    long Astride, long Bstride, long Cstride, int Nstride,
    int side, int m0, int n0)
{
  int tid = threadIdx.x;
  int wave = tid >> 6, lane = tid & 63;
  int quad = lane >> 4, l15 = lane & 15;

  f32x4 acc[8];
  #pragma unroll
  for (int mt = 0; mt < 8; mt++) acc[mt] = (f32x4){0,0,0,0};

  int arow = tid >> 1, ac0 = (tid & 1) * 32;
  int gr = m0 + arow; if (gr > M - 1) gr = M - 1;
  int brow = tid >> 2, bc0 = (tid & 3) * 16;

  for (int k0 = 0; k0 < KP; k0 += 64) {
    if (AF32) {
      const float* src = (const float*)Aptr + (size_t)gr * Acols;
      #pragma unroll
      for (int u = 0; u < 8; u++) {
        int kk = k0 + ac0 + u * 4;
        float4 v;
        if (kk + 4 <= Acols) v = *(const float4*)&src[kk];
        else {
          v.x = (kk + 0 < Acols) ? src[kk + 0] : 0.f;
          v.y = (kk + 1 < Acols) ? src[kk + 1] : 0.f;
          v.z = (kk + 2 < Acols) ? src[kk + 2] : 0.f;
          v.w = (kk + 3 < Acols) ? src[kk + 3] : 0.f;
        }
        As[arow][ac0 + u * 4 + 0] = __float2bfloat16(v.x);
        As[arow][ac0 + u * 4 + 1] = __float2bfloat16(v.y);
        As[arow][ac0 + u * 4 + 2] = __float2bfloat16(v.z);
        As[arow][ac0 + u * 4 + 3] = __float2bfloat16(v.w);
      }
    } else {
      const bf16* src = (const bf16*)Aptr + (size_t)side * Astride + (size_t)gr * KP + k0 + ac0;
      #pragma unroll
      for (int u = 0; u < 4; u++)
        *(short8*)&As[arow][ac0 + u * 8] = *(const short8*)&src[u * 8];
    }
    {
      const bf16* src = Bptr + (size_t)side * Bstride + (size_t)(n0 + brow) * KP + k0 + bc0;
      *(short8*)&Bs[brow][bc0]     = *(const short8*)&src[0];
      *(short8*)&Bs[brow][bc0 + 8] = *(const short8*)&src[8];
    }
    __syncthreads();
    #pragma unroll
    for (int ks = 0; ks < 2; ks++) {
      int kk = ks * 32 + quad * 8;
      short8 bfr = *(const short8*)&Bs[wave * 16 + l15][kk];
      #pragma unroll
      for (int mt = 0; mt < 8; mt++) {
        short8 afr = *(const short8*)&As[mt * 16 + l15][kk];
        acc[mt] = __builtin_amdgcn_mfma_f32_16x16x32_bf16(afr, bfr, acc[mt], 0, 0, 0);
      }
    }
    __syncthreads();
  }

  int n = n0 + wave * 16 + l15;
  if (n < Nout) {
    float bv = bias0 ? (side ? bias1[n] : bias0[n]) : 0.f;
    #pragma unroll
    for (int mt = 0; mt < 8; mt++) {
      #pragma unroll
      for (int r = 0; r < 4; r++) {
        int m = m0 + mt * 16 + quad * 4 + r;
        if (m < M) {
          float val = acc[mt][r] + bv;
          if (OUTBF)
            ((bf16*)Cptr)[(size_t)side * Cstride + (size_t)m * Nstride + n] = __float2bfloat16(val);
          else
            ((float*)Cptr)[(size_t)side * Cstride + (size_t)m * Nstride + n] = val;
        }
      }
    }
  }
}

// standalone k_gg (used for giall)
template<bool OUTBF, bool AF32>
__global__ __launch_bounds__(256) void k_gg(
    const void* __restrict__ Aptr, const bf16* __restrict__ Bptr,
    const float* __restrict__ bias0, const float* __restrict__ bias1,
    void* __restrict__ Cptr,
    int M, int Nout, int KP, int Acols,
    long Astride, long Bstride, long Cstride, int Nstride)
{
  __shared__ bf16 As[128][72];
  __shared__ bf16 Bs[64][72];
  ggbody<OUTBF, AF32>(As, Bs, Aptr, Bptr, bias0, bias1, Cptr,
                      M, Nout, KP, Acols, Astride, Bstride, Cstride, Nstride,
                      blockIdx.z, blockIdx.x * 128, blockIdx.y * 64);
}

// ---------------------------------------------------------------- merged mid GEMMs: ep2 + biasb + gibase
// blocks: [0,553)=ep2 (79x7), [553,585)=biasb (4x4x2), [585,665)=gibase (4x10x2)
__global__ __launch_bounds__(256) void k_ggmid(
    const float* __restrict__ ent, const bf16* __restrict__ Wn2, bf16* __restrict__ ep2,
    const bf16* __restrict__ Abias, const bf16* __restrict__ Wb2,
    const float* __restrict__ ab_s, const float* __restrict__ ab_o, float* __restrict__ biasb,
    const bf16* __restrict__ Agi, const bf16* __restrict__ Wg2,
    const float* __restrict__ sub_bih, const float* __restrict__ ob_bih, bf16* __restrict__ gibase)
{
  __shared__ bf16 As[128][72];
  __shared__ bf16 Bs[64][72];
  int bid = blockIdx.x;
  if (bid < 553) {
    int bx = bid % 79, by = bid / 79;
    ggbody<true, true>(As, Bs, (const void*)ent, Wn2, nullptr, nullptr, (void*)ep2,
                       E_, 400, 256, 200, 0L, 0L, 0L, 400, 0, bx * 128, by * 64);
  } else if (bid < 585) {
    int idx = bid - 553;
    int side = idx >> 4; idx &= 15;
    int bx = idx & 3, by = idx >> 2;
    ggbody<false, false>(As, Bs, (const void*)Abias, Wb2, ab_s, ab_o, (void*)biasb,
                         B_, 200, 448, 448, (long)B_ * 448, 256L * 448, (long)B_ * 200, 200,
                         side, bx * 128, by * 64);
  } else {
    int idx = bid - 585;
    int side = idx / 40; idx %= 40;
    int bx = idx & 3, by = idx >> 2;
    ggbody<true, false>(As, Bs, (const void*)Agi, Wg2, sub_bih, ob_bih, (void*)gibase,
                        B_, 600, 448, 448, (long)B_ * 448, 640L * 448, (long)B_ * 600, 600,
                        side, bx * 128, by * 64);
  }
}

// ---------------------------------------------------------------- attention v3: one block per (side,b,t)
__global__ __launch_bounds__(256) void k_attn3(
    const float* __restrict__ ent,
    const int* __restrict__ neigh0, const int* __restrict__ neigh1,
    const int* __restrict__ nlen0, const int* __restrict__ nlen1,
    const int* __restrict__ hlen0, const int* __restrict__ hlen1,
    const float* __restrict__ v0, const float* __restrict__ v1,
    const bf16* __restrict__ ep2, const float* __restrict__ biasb,
    bf16* __restrict__ stepb)
{
  int side = blockIdx.y;
  int bt = blockIdx.x;
  int b = bt / T_, t = bt % T_;
  int hl = (side ? hlen1 : hlen0)[b];
  bf16* srow = stepb + (((size_t)side * B_ + b) * T_ + t) * 256;
  int tid = threadIdx.x;
  if (t >= hl) {     // masked timestep: zero row (uniform branch)
    srow[tid] = __float2bfloat16(0.f);
    return;
  }
  const int* neigh = side ? neigh1 : neigh0;
  const float* v = side ? v1 : v0;
  const float* brow = biasb + ((size_t)side * B_ + b) * H_;
  int nl = (side ? nlen1 : nlen0)[b * T_ + t];

  __shared__ float bsh[H_], vsh[H_], lg[64], wsh[64];
  __shared__ int nb[N_];
  if (tid < H_) { bsh[tid] = brow[tid]; vsh[tid] = v[tid]; }
  if (tid < N_) nb[tid] = neigh[((size_t)b * T_ + t) * N_ + tid];
  __syncthreads();

  int grp = tid >> 4;        // 0..15
  int l16 = tid & 15;

  float bs[13], vs[13];
  #pragma unroll
  for (int i = 0; i < 13; i++) {
    int g = l16 + i * 16;
    bool ok = (g < H_);
    bs[i] = ok ? bsh[g] : 0.f;
    vs[i] = ok ? vsh[g] : 0.f;
  }

  for (int n = grp; n < nl; n += 16) {
    const bf16* er = ep2 + (size_t)nb[n] * 400 + side * 200;
    float acc = 0.f;
    #pragma unroll
    for (int i = 0; i < 13; i++) {
      int g = l16 + i * 16;
      float e = (g < H_) ? b2f(er[g]) : 0.f;
      acc += ftanh(e + bs[i]) * vs[i];
    }
    #pragma unroll
    for (int off = 8; off > 0; off >>= 1) acc += __shfl_down(acc, off, 16);
    if (l16 == 0) lg[n] = acc;
  }
  __syncthreads();

  if (tid < 64) {
    float x = (tid < nl) ? lg[tid] : -1e30f;
    float m = x;
    #pragma unroll
    for (int off = 32; off > 0; off >>= 1) m = fmaxf(m, __shfl_down(m, off));
    m = __shfl(m, 0);
    float e = (tid < nl) ? __expf(x - m) : 0.f;
    float s = e;
    #pragma unroll
    for (int off = 32; off > 0; off >>= 1) s += __shfl_down(s, off);
    s = __shfl(s, 0);
    if (tid < N_) wsh[tid] = e / s;
  }
  __syncthreads();

  int h = tid;
  if (h < H_) {
    float a0 = 0.f, a1 = 0.f, a2 = 0.f, a3 = 0.f;
    int n = 0;
    for (; n + 4 <= nl; n += 4) {
      a0 += wsh[n + 0] * ent[(size_t)nb[n + 0] * H_ + h];
      a1 += wsh[n + 1] * ent[(size_t)nb[n + 1] * H_ + h];
      a2 += wsh[n + 2] * ent[(size_t)nb[n + 2] * H_ + h];
      a3 += wsh[n + 3] * ent[(size_t)nb[n + 3] * H_ + h];
    }
    for (; n < nl; n++) a0 += wsh[n] * ent[(size_t)nb[n] * H_ + h];
    srow[h] = __float2bfloat16((a0 + a1) + (a2 + a3));
  } else {
    srow[h] = __float2bfloat16(0.f);   // pad cols 200..255
  }
}

// ---------------------------------------------------------------- MFMA GRU v4
__global__ __launch_bounds__(832) void k_gru4(
    const bf16* __restrict__ giall, const bf16* __restrict__ gibase,
    const bf16* __restrict__ Whh2,
    const float* __restrict__ bhh0, const float* __restrict__ bhh1,
    const int* __restrict__ len0, const int* __restrict__ len1,
    float* __restrict__ hfin)
{
  int side = blockIdx.y;
  int b0 = blockIdx.x * 16;
  const bf16* gia = giall + ((size_t)side * B_ * T_ + (size_t)b0 * T_) * 600;
  const bf16* gib = gibase + ((size_t)side * B_ + b0) * K3;
  const bf16* Wh  = Whh2 + (size_t)side * 608 * 224;
  const float* bhh = side ? bhh1 : bhh0;
  const int* len = side ? len1 : len0;

  __shared__ __align__(16) bf16 Hs[2][16][232];

  int tid = threadIdx.x;
  int wave = tid >> 6, lane = tid & 63;
  int quad = lane >> 4, l15 = lane & 15;

  for (int i = tid; i < 2 * 16 * 232 / 8; i += 832) ((short8*)&Hs[0][0][0])[i] = (short8)0;

  int j0 = wave * 16;
  int j = j0 + l15;
  bool jok = (j < H_);
  float bhr = 0.f, bhz = 0.f, bhn = 0.f;
  float gr[4] = {}, gz[4] = {}, gn[4] = {};
  int lens4[4];
  #pragma unroll
  for (int r = 0; r < 4; r++) lens4[r] = len[b0 + quad * 4 + r];
  if (jok) {
    bhr = bhh[j]; bhz = bhh[H_ + j]; bhn = bhh[2 * H_ + j];
    #pragma unroll
    for (int r = 0; r < 4; r++) {
      const bf16* g = gib + (size_t)(quad * 4 + r) * K3;
      gr[r] = b2f(g[j]); gz[r] = b2f(g[H_ + j]); gn[r] = b2f(g[2 * H_ + j]);
    }
  }
  const bf16* wr = Wh + (size_t)j * 224;
  const bf16* wz = Wh + (size_t)(200 + j) * 224;
  const bf16* wn = Wh + (size_t)(400 + j) * 224;
  __syncthreads();

  int cur = 0;
  for (int t = 0; t < T_; t++) {
    unsigned short guR[4], guZ[4], guN[4];
    if (jok) {
      #pragma unroll
      for (int r = 0; r < 4; r++) {
        const unsigned short* g =
            (const unsigned short*)(gia + ((size_t)(quad * 4 + r) * T_ + t) * 600);
        guR[r] = g[j]; guZ[r] = g[200 + j]; guN[r] = g[400 + j];
      }
    }
    f32x4 ar = {0,0,0,0}, az = {0,0,0,0}, anh = {0,0,0,0};
    #pragma unroll
    for (int ks = 0; ks < 7; ks++) {
      int kk = ks * 32 + quad * 8;
      short8 a0 = *(const short8*)&Hs[cur][l15][kk];
      short8 br = *(const short8*)&wr[kk];
      short8 bz = *(const short8*)&wz[kk];
      short8 bn = *(const short8*)&wn[kk];
      ar  = __builtin_amdgcn_mfma_f32_16x16x32_bf16(a0, br, ar, 0, 0, 0);
      az  = __builtin_amdgcn_mfma_f32_16x16x32_bf16(a0, bz, az, 0, 0, 0);
      anh = __builtin_amdgcn_mfma_f32_16x16x32_bf16(a0, bn, anh, 0, 0, 0);
    }
    if (jok) {
      #pragma unroll
      for (int r = 0; r < 4; r++) {
        int row = quad * 4 + r;
        float rz  = ar[r] + u2f(guR[r]) + gr[r] + bhr;
        float zz  = az[r] + u2f(guZ[r]) + gz[r] + bhz;
        float inn = u2f(guN[r]) + gn[r];
        float hn  = anh[r] + bhn;
        float rg = fsigm(rz);
        float zg = fsigm(zz);
        float ng = ftanh(inn + rg * hn);
        float hold = b2f(Hs[cur][row][j]);
        float hnew = (1.f - zg) * ng + zg * hold;
        Hs[cur ^ 1][row][j] = __float2bfloat16((t < lens4[r]) ? hnew : hold);
      }
    }
    __syncthreads();
    cur ^= 1;
  }
  for (int i = tid; i < 16 * H_; i += 832) {
    int row = i / H_, jj = i % H_;
    hfin[((size_t)side * B_ + b0 + row) * H_ + jj] = b2f(Hs[cur][row][jj]);
  }
}

// ---------------------------------------------------------------- assemble pred-GEMM input rows (bf16, K padded to 640)
__global__ __launch_bounds__(256) void k_feat(
    const float* __restrict__ ent, const float* __restrict__ rel, const int* __restrict__ trip,
    const int* __restrict__ idxbuf, const float* __restrict__ hfin,
    bf16* __restrict__ xfeat)
{
  int i = blockIdx.x, p = blockIdx.y;
  int bi = idxbuf[(p == 0 ? 1 : 0) * B_ + i];
  int ent_id = (p == 0) ? trip[bi * 3 + 2] : trip[bi * 3 + 0];
  int rid = trip[bi * 3 + 1];
  const float* hsrc = hfin + (size_t)(p == 0 ? 1 : 0) * B_ * H_;
  bf16* x = xfeat + ((size_t)p * B_ + i) * 640;
  int h = threadIdx.x;
  if (h < H_) {
    x[h]          = __float2bfloat16(ent[(size_t)ent_id * H_ + h]);
    x[H_ + h]     = __float2bfloat16(hsrc[(size_t)bi * H_ + h]);
    x[2 * H_ + h] = __float2bfloat16(rel[(size_t)rid * H_ + h]);
  }
  if (h < 40) x[600 + h] = __float2bfloat16(0.f);
}

// ---------------------------------------------------------------- MFMA pred GEMM v9 (bf16 B + fused sumexp, NO atomics)
__global__ __launch_bounds__(512) void k_gemm6(
    const bf16* __restrict__ Abf, const bf16* __restrict__ Wlin,
    const float* __restrict__ bias0, const float* __restrict__ bias1,
    float* __restrict__ dout, float* __restrict__ pexp)
{
  int side = blockIdx.z;
  const bf16* Bm = Wlin + (size_t)side * EP_ * 640;
  const float* bias = side ? bias1 : bias0;
  float* C = dout + 1 + (size_t)side * B_ * E_;
  int mBase = blockIdx.x * 256;
  int m0 = side * B_ + mBase;
  int n0 = blockIdx.y * 64;

  __shared__ bf16 As[256][72];
  __shared__ bf16 Bs[64][72];
  __shared__ float Ps[2][256];   // [wn][row_local] exp partials

  int tid = threadIdx.x;
  int wave = tid >> 6, lane = tid & 63;
  int quad = lane >> 4, l15 = lane & 15;
  int wm = wave >> 1, wn = wave & 1;   // 4x2 wave grid

  f32x4 acc[4][2];
  #pragma unroll
  for (int mt = 0; mt < 4; mt++)
    #pragma unroll
    for (int nt = 0; nt < 2; nt++) acc[mt][nt] = (f32x4){0,0,0,0};

  int arow = tid >> 1, ac0 = (tid & 1) * 32;       // A: 256 rows, 32-elem halves
  int brow = tid >> 3, bc0 = (tid & 7) * 8;        // B: 64 rows, 8 bf16 each
  const bf16* asrc = Abf + (size_t)(m0 + arow) * 640 + ac0;
  const bf16* bsrc = Bm + (size_t)(n0 + brow) * 640 + bc0;

  for (int k0 = 0; k0 < 640; k0 += 64) {
    #pragma unroll
    for (int u = 0; u < 4; u++)
      *(short8*)&As[arow][ac0 + u * 8] = *(const short8*)&asrc[k0 + u * 8];
    *(short8*)&Bs[brow][bc0] = *(const short8*)&bsrc[k0];
    __syncthreads();
    #pragma unroll
    for (int ks = 0; ks < 2; ks++) {
      int kk = ks * 32 + quad * 8;
      short8 bfr[2];
      #pragma unroll
      for (int nt = 0; nt < 2; nt++)
        bfr[nt] = *(const short8*)&Bs[wn * 32 + nt * 16 + l15][kk];
      #pragma unroll
      for (int mt = 0; mt < 4; mt++) {
        short8 afr = *(const short8*)&As[wm * 64 + mt * 16 + l15][kk];
        #pragma unroll
        for (int nt = 0; nt < 2; nt++)
          acc[mt][nt] = __builtin_amdgcn_mfma_f32_16x16x32_bf16(afr, bfr[nt], acc[mt][nt], 0, 0, 0);
      }
    }
    __syncthreads();
  }

  // epilogue: row_local = wm*64 + mt*16 + quad*4 + r; col = n0 + wn*32 + nt*16 + l15
  float bv[2];
  int ncol[2];
  #pragma unroll
  for (int nt = 0; nt < 2; nt++) {
    ncol[nt] = n0 + wn * 32 + nt * 16 + l15;
    bv[nt] = (ncol[nt] < E_) ? bias[ncol[nt]] : 0.f;
  }
  #pragma unroll
  for (int mt = 0; mt < 4; mt++) {
    #pragma unroll
    for (int r = 0; r < 4; r++) {
      int rloc = wm * 64 + mt * 16 + quad * 4 + r;
      int mrow = mBase + rloc;
      float p = 0.f;
      #pragma unroll
      for (int nt = 0; nt < 2; nt++) {
        if (ncol[nt] < E_) {
          float val = acc[mt][nt][r] + bv[nt];
          C[(size_t)mrow * E_ + ncol[nt]] = val;
          p += __expf(val);
        }
      }
      // reduce 32 cols of this row held by this wave (16 lanes x 2 cols)
      #pragma unroll
      for (int off = 8; off > 0; off >>= 1) p += __shfl_down(p, off, 16);
      if (l15 == 0) Ps[wn][rloc] = p;
    }
  }
  __syncthreads();
  if (tid < 256) {
    float p = Ps[0][tid] + Ps[1][tid];
    pexp[((size_t)side * NBLK_ + blockIdx.y) * 512 + mBase + tid] = p;
  }
}

// ---------------------------------------------------------------- MFMA pred GEMM v5 (fp32 B fallback, ws too small)
__global__ __launch_bounds__(512) void k_gemm5(
    const bf16* __restrict__ Abf,
    const float* __restrict__ B0, const float* __restrict__ B1,
    const float* __restrict__ bias0, const float* __restrict__ bias1,
    float* __restrict__ dout, float* __restrict__ pexp)
{
  int side = blockIdx.z;
  const float* Bm = side ? B1 : B0;
  const float* bias = side ? bias1 : bias0;
  float* C = dout + 1 + (size_t)side * B_ * E_;
  int mBase = blockIdx.x * 256;
  int m0 = side * B_ + mBase;
  int n0 = blockIdx.y * 64;

  __shared__ bf16 As[256][72];
  __shared__ bf16 Bs[64][72];
  __shared__ float Ps[2][256];

  int tid = threadIdx.x;
  int wave = tid >> 6, lane = tid & 63;
  int quad = lane >> 4, l15 = lane & 15;
  int wm = wave >> 1, wn = wave & 1;

  f32x4 acc[4][2];
  #pragma unroll
  for (int mt = 0; mt < 4; mt++)
    #pragma unroll
    for (int nt = 0; nt < 2; nt++) acc[mt][nt] = (f32x4){0,0,0,0};

  int arow = tid >> 1, ac0 = (tid & 1) * 32;
  int brow = tid >> 3, bc0 = (tid & 7) * 8;
  const bf16* asrc = Abf + (size_t)(m0 + arow) * 640 + ac0;
  int nsrc = n0 + brow; if (nsrc > E_ - 1) nsrc = E_ - 1;
  const float* bsrc = Bm + (size_t)nsrc * K3 + bc0;

  for (int k0 = 0; k0 < 640; k0 += 64) {
    #pragma unroll
    for (int u = 0; u < 4; u++)
      *(short8*)&As[arow][ac0 + u * 8] = *(const short8*)&asrc[k0 + u * 8];
    {
      int kb = k0 + bc0;
      if (kb + 8 <= K3) {
        float4 v0 = *(const float4*)&bsrc[k0];
        float4 v1 = *(const float4*)&bsrc[k0 + 4];
        Bs[brow][bc0 + 0] = __float2bfloat16(v0.x);
        Bs[brow][bc0 + 1] = __float2bfloat16(v0.y);
        Bs[brow][bc0 + 2] = __float2bfloat16(v0.z);
        Bs[brow][bc0 + 3] = __float2bfloat16(v0.w);
        Bs[brow][bc0 + 4] = __float2bfloat16(v1.x);
        Bs[brow][bc0 + 5] = __float2bfloat16(v1.y);
        Bs[brow][bc0 + 6] = __float2bfloat16(v1.z);
        Bs[brow][bc0 + 7] = __float2bfloat16(v1.w);
      } else {
        #pragma unroll
        for (int u = 0; u < 8; u++) {
          int k = kb + u;
          float v = (k < K3) ? bsrc[k0 + u] : 0.f;
          Bs[brow][bc0 + u] = __float2bfloat16(v);
        }
      }
    }
    __syncthreads();
    #pragma unroll
    for (int ks = 0; ks < 2; ks++) {
      int kk = ks * 32 + quad * 8;
      short8 bfr[2];
      #pragma unroll
      for (int nt = 0; nt < 2; nt++)
        bfr[nt] = *(const short8*)&Bs[wn * 32 + nt * 16 + l15][kk];
      #pragma unroll
      for (int mt = 0; mt < 4; mt++) {
        short8 afr = *(const short8*)&As[wm * 64 + mt * 16 + l15][kk];
        #pragma unroll
        for (int nt = 0; nt < 2; nt++)
          acc[mt][nt] = __builtin_amdgcn_mfma_f32_16x16x32_bf16(afr, bfr[nt], acc[mt][nt], 0, 0, 0);
      }
    }
    __syncthreads();
  }

  float bv[2];
  int ncol[2];
  #pragma unroll
  for (int nt = 0; nt < 2; nt++) {
    ncol[nt] = n0 + wn * 32 + nt * 16 + l15;
    bv[nt] = (ncol[nt] < E_) ? bias[ncol[nt]] : 0.f;
  }
  #pragma unroll
  for (int mt = 0; mt < 4; mt++) {
    #pragma unroll
    for (int r = 0; r < 4; r++) {
      int rloc = wm * 64 + mt * 16 + quad * 4 + r;
      int mrow = mBase + rloc;
      float p = 0.f;
      #pragma unroll
      for (int nt = 0; nt < 2; nt++) {
        if (ncol[nt] < E_) {
          float val = acc[mt][nt][r] + bv[nt];
          C[(size_t)mrow * E_ + ncol[nt]] = val;
          p += __expf(val);
        }
      }
      #pragma unroll
      for (int off = 8; off > 0; off >>= 1) p += __shfl_down(p, off, 16);
      if (l15 == 0) Ps[wn][rloc] = p;
    }
  }
  __syncthreads();
  if (tid < 256) {
    float p = Ps[0][tid] + Ps[1][tid];
    pexp[((size_t)side * NBLK_ + blockIdx.y) * 512 + mBase + tid] = p;
  }
}

// ---------------------------------------------------------------- final CE loss from pexp partials
__global__ __launch_bounds__(1024) void k_loss3(
    const float* __restrict__ dout_ro, const int* __restrict__ trip,
    const int* __restrict__ idxbuf, const float* __restrict__ pexp,
    float* __restrict__ dout)
{
  int tid = threadIdx.x;            // 0..1023
  int p = tid >> 9, i = tid & 511;
  float s = 0.f;
  for (int nb = 0; nb < NBLK_; nb++)
    s += pexp[((size_t)p * NBLK_ + nb) * 512 + i];
  int bi = idxbuf[(p == 0 ? 1 : 0) * B_ + i];
  int label = (p == 0) ? trip[bi * 3 + 0] : trip[bi * 3 + 2];
  float val = dout_ro[1 + (size_t)p * B_ * E_ + (size_t)i * E_ + label];
  float part = -(val - logf(s)) / (float)B_;
  __shared__ float ps[1024];
  ps[tid] = part; __syncthreads();
  for (int st = 512; st > 0; st >>= 1) {
    if (tid < st) ps[tid] += ps[tid + st];
    __syncthreads();
  }
  if (tid == 0) dout[0] = ps[0];
}

// ----------------------------------------------------------------
extern "C" void kernel_launch(void* const* d_in, const int* in_sizes, int n_in,
                              void* d_out, int out_size, void* d_ws, size_t ws_size,
                              hipStream_t stream)
{
  const int* trip = (const int*)d_in[0];
  const int* s_ne = (const int*)d_in[1];
  const int* s_nl = (const int*)d_in[2];
  const int* s_hl = (const int*)d_in[3];
  const int* o_ne = (const int*)d_in[4];
  const int* o_nl = (const int*)d_in[5];
  const int* o_hl = (const int*)d_in[6];
  const float* ent = (const float*)d_in[7];
  const float* rel = (const float*)d_in[8];
  const float* aw_s = (const float*)d_in[9];
  const float* ab_s = (const float*)d_in[10];
  const float* v_s  = (const float*)d_in[11];
  const float* aw_o = (const float*)d_in[12];
  const float* ab_o = (const float*)d_in[13];
  const float* v_o  = (const float*)d_in[14];
  const float* sub_wih = (const float*)d_in[15];
  const float* sub_whh = (const float*)d_in[16];
  const float* sub_bih = (const float*)d_in[17];
  const float* sub_bhh = (const float*)d_in[18];
  const float* ob_wih  = (const float*)d_in[19];
  const float* ob_whh  = (const float*)d_in[20];
  const float* ob_bih  = (const float*)d_in[21];
  const float* ob_bhh  = (const float*)d_in[22];
  const float* lin_sub_w = (const float*)d_in[23];
  const float* lin_sub_b = (const float*)d_in[24];
  const float* lin_ob_w  = (const float*)d_in[25];
  const float* lin_ob_b  = (const float*)d_in[26];
  float* dout = (float*)d_out;

  // workspace carve — base ~35.2 MB, +25.7 MB for bf16 pred weights if it fits
  char* w = (char*)d_ws;
  bf16* ep2     = (bf16*)w;  w += (size_t)E_ * 400 * 2;           //  8,000,000 B
  bf16* stepb   = (bf16*)w;  w += (size_t)2 * B_ * T_ * 256 * 2;  //  5,242,880 B
  float* biasb  = (float*)w; w += (size_t)2 * B_ * H_ * 4;        //    819,200 B
  bf16* gibase  = (bf16*)w;  w += (size_t)2 * B_ * K3 * 2;        //  1,228,800 B
  float* hfin   = (float*)w; w += (size_t)2 * B_ * H_ * 4;        //    819,200 B
  bf16* xfeat   = (bf16*)w;  w += (size_t)1024 * 640 * 2;         //  1,310,720 B
  bf16* Wn2     = (bf16*)w;  w += (size_t)448 * 256 * 2;          //    229,376 B
  bf16* Wb2     = (bf16*)w;  w += (size_t)2 * 256 * 448 * 2;      //    458,752 B
  bf16* Wg2     = (bf16*)w;  w += (size_t)2 * 640 * 448 * 2;      //  1,146,880 B
  bf16* Wstep   = (bf16*)w;  w += (size_t)2 * 640 * 256 * 2;      //    655,360 B
  bf16* Whh2    = (bf16*)w;  w += (size_t)2 * 608 * 224 * 2;      //    544,768 B
  bf16* giall   = (bf16*)w;  w += (size_t)2 * B_ * T_ * 600 * 2;  // 12,288,000 B
  bf16* Abias   = (bf16*)w;  w += (size_t)2 * B_ * 448 * 2;       //    917,504 B
  bf16* Agi     = (bf16*)w;  w += (size_t)2 * B_ * 448 * 2;       //    917,504 B
  float* pexp   = (float*)w; w += (size_t)2 * NBLK_ * 512 * 4;    //    643,072 B
  int* idxbuf   = (int*)w;   w += 4096;
  bf16* Wlin    = (bf16*)w;  w += (size_t)2 * EP_ * 640 * 2;      // 25,722,880 B
  bool useBf16B = ((size_t)(w - (char*)d_ws) <= ws_size);

  // mega pack (+ Wlin prepack + argsort)
  k_packall<<<25858, 256, 0, stream>>>(aw_s, aw_o, sub_wih, ob_wih, sub_whh, ob_whh,
                                       ent, rel, trip, lin_ob_w, lin_sub_w, s_hl, o_hl,
                                       Wn2, Wb2, Wg2, Wstep, Whh2, Abias, Agi,
                                       Wlin, useBf16B ? 1 : 0, idxbuf, dout);
  // merged mid GEMMs: ep2 + biasb + gibase (665 blocks)
  k_ggmid<<<665, 256, 0, stream>>>(ent, Wn2, ep2,
                                   Abias, Wb2, ab_s, ab_o, biasb,
                                   Agi, Wg2, sub_bih, ob_bih, gibase);
  // attention (one block per (side,b,t))
  k_attn3<<<dim3(B_ * T_, 2), 256, 0, stream>>>(ent, s_ne, o_ne, s_nl, o_nl,
                                                s_hl, o_hl, v_s, v_o, ep2, biasb, stepb);
  // giall = step @ Wih[:, :200].T  for all (b,t)  (M=5120/side, N=600, K=256pad)
  k_gg<true, false><<<dim3(40, 10, 2), 256, 0, stream>>>(
      (const void*)stepb, Wstep, nullptr, nullptr, (void*)giall,
      B_ * T_, 600, 256, 256, (long)B_ * T_ * 256, 640L * 256, (long)B_ * T_ * 600, 600);
  // GRU (recurrent part only: K=224)
  k_gru4<<<dim3(B_ / 16, 2), 832, 0, stream>>>(giall, gibase, Whh2, sub_bhh, ob_bhh,
                                               s_hl, o_hl, hfin);
  k_feat<<<dim3(B_, 2), 256, 0, stream>>>(ent, rel, trip, idxbuf, hfin, xfeat);
  // pred GEMM with fused exp-partials (no atomics)
  if (useBf16B)
    k_gemm6<<<dim3(2, NBLK_, 2), 512, 0, stream>>>(
        xfeat, Wlin, lin_ob_b, lin_sub_b, dout, pexp);
  else
    k_gemm5<<<dim3(2, NBLK_, 2), 512, 0, stream>>>(
        xfeat, lin_ob_w, lin_sub_w, lin_ob_b, lin_sub_b, dout, pexp);
  k_loss3<<<1, 1024, 0, stream>>>(dout, trip, idxbuf, pexp, dout);
}

// Round 12
// 350.232 us; speedup vs baseline: 1.2035x; 1.0251x over previous
//
#include <hip/hip_runtime.h>
#include <hip/hip_bf16.h>
#include <math.h>

typedef __hip_bfloat16 bf16;
typedef __attribute__((ext_vector_type(8))) short short8;
typedef __attribute__((ext_vector_type(4))) float f32x4;

#define B_ 512
#define T_ 10
#define N_ 50
#define H_ 200
#define E_ 10000
#define R_ 200
#define K3 600   // 3*H
#define EP_ 10048  // E_ padded to 64 for guard-free B staging
#define NBLK_ 157  // (E_+63)/64 N-blocks in pred GEMM
#define WLINBLK_ 6280  // 2*EP_*640 / (256*8)

__device__ __forceinline__ float b2f(bf16 x){ return __bfloat162float(x); }
__device__ __forceinline__ float u2f(unsigned short u){
  unsigned int x = ((unsigned int)u) << 16;
  return __builtin_bit_cast(float, x);
}
// fast sigmoid/tanh: v_exp_f32 + v_rcp_f32 (~1 ulp), instead of libm calls
__device__ __forceinline__ float fsigm(float x){
  return __builtin_amdgcn_rcpf(1.f + __expf(-x));
}
__device__ __forceinline__ float ftanh(float x){
  x = fminf(15.f, fmaxf(-15.f, x));
  float e = __expf(-2.f * x);
  return (1.f - e) * __builtin_amdgcn_rcpf(1.f + e);
}

// ---------------------------------------------------------------- mega pack (one dispatch)
// sections by blockIdx.x:
//  [0,448)          Wn2[448][256]
//  [448,960)        Wb2[2][256][448]
//  [960,2240)       Wg2[2][640][448]
//  [2240,3520)      Wstep[2][640][256]
//  [3520,4736)      Whh2[2][608][224]
//  [4736,5760)      Abias/Agi
//  [5760,12040)     Wlin bf16 prepack, vectorized: 8 elems/thread, float4x2 -> short8
//  [12040,12042)    argsort per side (256 thr, 2 elems each) + perm->dout
__global__ __launch_bounds__(256) void k_packall(
    const float* __restrict__ aw_s, const float* __restrict__ aw_o,
    const float* __restrict__ sub_wih, const float* __restrict__ ob_wih,
    const float* __restrict__ sub_whh, const float* __restrict__ ob_whh,
    const float* __restrict__ ent, const float* __restrict__ rel,
    const int* __restrict__ trip,
    const float* __restrict__ lin_ob_w, const float* __restrict__ lin_sub_w,
    const int* __restrict__ hlen0, const int* __restrict__ hlen1,
    bf16* __restrict__ Wn2, bf16* __restrict__ Wb2, bf16* __restrict__ Wg2,
    bf16* __restrict__ Wstep, bf16* __restrict__ Whh2,
    bf16* __restrict__ Ab, bf16* __restrict__ Ag,
    bf16* __restrict__ Wlin, int useBf16B,
    int* __restrict__ idxbuf, float* __restrict__ dout)
{
  int bid = blockIdx.x;
  int tid = threadIdx.x;
  if (bid < 448) {
    int r = bid;
    const float* Wa = (r < 200) ? aw_s : aw_o;
    int g = (r < 200) ? r : r - 200;
    bf16* out = Wn2 + (size_t)r * 256;
    for (int k = tid; k < 256; k += 256) {
      float v = (r < 400 && k < 200) ? Wa[(size_t)g * K3 + k] : 0.f;
      out[k] = __float2bfloat16(v);
    }
  } else if (bid < 960) {
    int idx = bid - 448;
    int side = idx >> 8, r = idx & 255;
    const float* W = side ? aw_o : aw_s;
    bf16* out = Wb2 + ((size_t)side * 256 + r) * 448;
    for (int k = tid; k < 448; k += 256) {
      float v = (r < 200 && k < 400) ? W[(size_t)r * K3 + 200 + k] : 0.f;
      out[k] = __float2bfloat16(v);
    }
  } else if (bid < 2240) {
    int idx = bid - 960;
    int side = idx / 640, r = idx % 640;
    const float* W = side ? ob_wih : sub_wih;
    bf16* out = Wg2 + ((size_t)side * 640 + r) * 448;
    for (int k = tid; k < 448; k += 256) {
      float v = (r < 600 && k < 400) ? W[(size_t)r * K3 + 200 + k] : 0.f;
      out[k] = __float2bfloat16(v);
    }
  } else if (bid < 3520) {
    int idx = bid - 2240;
    int side = idx / 640, r = idx % 640;
    const float* W = side ? ob_wih : sub_wih;
    bf16* out = Wstep + ((size_t)side * 640 + r) * 256;
    for (int k = tid; k < 256; k += 256) {
      float v = (r < 600 && k < 200) ? W[(size_t)r * K3 + k] : 0.f;
      out[k] = __float2bfloat16(v);
    }
  } else if (bid < 4736) {
    int idx = bid - 3520;
    int side = idx / 608, r = idx % 608;
    const float* W = side ? ob_whh : sub_whh;
    bf16* out = Whh2 + ((size_t)side * 608 + r) * 224;
    for (int k = tid; k < 224; k += 256) {
      float v = (r < 600 && k < 200) ? W[(size_t)r * H_ + k] : 0.f;
      out[k] = __float2bfloat16(v);
    }
  } else if (bid < 5760) {
    int idx = bid - 4736;
    int side = idx >> 9, b = idx & 511;
    int ids = trip[b * 3 + (side ? 2 : 0)];
    int rid = trip[b * 3 + 1];
    size_t ro = ((size_t)side * B_ + b) * 448;
    for (int k = tid; k < 448; k += 256) {
      float vb = 0.f, vg = 0.f;
      if (k < 200) { float e = ent[(size_t)ids * H_ + k]; vb = e; vg = e; }
      else if (k < 400) {
        vb = ent[(size_t)rid * H_ + (k - 200)];
        vg = rel[(size_t)rid * H_ + (k - 200)];
      }
      Ab[ro + k] = __float2bfloat16(vb);
      Ag[ro + k] = __float2bfloat16(vg);
    }
  } else if (bid < 5760 + WLINBLK_) {
    if (!useBf16B) return;
    // flat vectorized prepack: 8 consecutive bf16 per thread.
    // 600 % 8 == 0 so each chunk is fully in-bounds or fully pad.
    size_t base = ((size_t)(bid - 5760) * 256 + tid) * 8;   // elem offset in [2][EP_][640]
    int side = (int)(base / ((size_t)EP_ * 640));
    size_t rem = base - (size_t)side * EP_ * 640;
    int row = (int)(rem / 640);
    int k = (int)(rem % 640);
    const float* W = side ? lin_sub_w : lin_ob_w;
    short8 outv = (short8)0;
    if (row < E_ && k < K3) {
      const float* src = W + (size_t)row * K3 + k;
      float4 v0 = *(const float4*)&src[0];
      float4 v1 = *(const float4*)&src[4];
      bf16 tmp[8];
      tmp[0] = __float2bfloat16(v0.x); tmp[1] = __float2bfloat16(v0.y);
      tmp[2] = __float2bfloat16(v0.z); tmp[3] = __float2bfloat16(v0.w);
      tmp[4] = __float2bfloat16(v1.x); tmp[5] = __float2bfloat16(v1.y);
      tmp[6] = __float2bfloat16(v1.z); tmp[7] = __float2bfloat16(v1.w);
      outv = *(short8*)tmp;
    }
    *(short8*)&Wlin[base] = outv;
  } else {
    int side = bid - (5760 + WLINBLK_);
    const int* len = side ? hlen1 : hlen0;
    __shared__ int lens[B_];
    __shared__ int perm[B_];
    lens[tid] = len[tid];
    lens[tid + 256] = len[tid + 256];
    __syncthreads();
    #pragma unroll
    for (int e = 0; e < 2; e++) {
      int i = tid + e * 256;
      int L = lens[i];
      int rank = 0;
      for (int j = 0; j < B_; j++) {
        int Lj = lens[j];
        rank += (Lj > L) || (Lj == L && j < i);
      }
      perm[rank] = i;
    }
    __syncthreads();
    size_t base = 1 + (size_t)2 * B_ * E_ + (side ? 0 : B_);
    idxbuf[side * B_ + tid] = perm[tid];
    idxbuf[side * B_ + tid + 256] = perm[tid + 256];
    dout[base + tid] = (float)perm[tid];
    dout[base + tid + 256] = (float)perm[tid + 256];
  }
}

// ---------------------------------------------------------------- generic MFMA GEMM body
// C[m][n] = sum_k A[m][k]*B[n][k] (+ bias[n]); tile M=128, N=64, BK=64.
template<bool OUTBF, bool AF32>
__device__ __forceinline__ void ggbody(
    bf16 (*As)[72], bf16 (*Bs)[72],
    const void* __restrict__ Aptr, const bf16* __restrict__ Bptr,
    const float* __restrict__ bias0, const float* __restrict__ bias1,
    void* __restrict__ Cptr,
    int M, int Nout, int KP, int Acols,
    long Astride, long Bstride, long Cstride, int Nstride,
    int side, int m0, int n0)
{
  int tid = threadIdx.x;
  int wave = tid >> 6, lane = tid & 63;
  int quad = lane >> 4, l15 = lane & 15;

  f32x4 acc[8];
  #pragma unroll
  for (int mt = 0; mt < 8; mt++) acc[mt] = (f32x4){0,0,0,0};

  int arow = tid >> 1, ac0 = (tid & 1) * 32;
  int gr = m0 + arow; if (gr > M - 1) gr = M - 1;
  int brow = tid >> 2, bc0 = (tid & 3) * 16;

  for (int k0 = 0; k0 < KP; k0 += 64) {
    if (AF32) {
      const float* src = (const float*)Aptr + (size_t)gr * Acols;
      #pragma unroll
      for (int u = 0; u < 8; u++) {
        int kk = k0 + ac0 + u * 4;
        float4 v;
        if (kk + 4 <= Acols) v = *(const float4*)&src[kk];
        else {
          v.x = (kk + 0 < Acols) ? src[kk + 0] : 0.f;
          v.y = (kk + 1 < Acols) ? src[kk + 1] : 0.f;
          v.z = (kk + 2 < Acols) ? src[kk + 2] : 0.f;
          v.w = (kk + 3 < Acols) ? src[kk + 3] : 0.f;
        }
        As[arow][ac0 + u * 4 + 0] = __float2bfloat16(v.x);
        As[arow][ac0 + u * 4 + 1] = __float2bfloat16(v.y);
        As[arow][ac0 + u * 4 + 2] = __float2bfloat16(v.z);
        As[arow][ac0 + u * 4 + 3] = __float2bfloat16(v.w);
      }
    } else {
      const bf16* src = (const bf16*)Aptr + (size_t)side * Astride + (size_t)gr * KP + k0 + ac0;
      #pragma unroll
      for (int u = 0; u < 4; u++)
        *(short8*)&As[arow][ac0 + u * 8] = *(const short8*)&src[u * 8];
    }
    {
      const bf16* src = Bptr + (size_t)side * Bstride + (size_t)(n0 + brow) * KP + k0 + bc0;
      *(short8*)&Bs[brow][bc0]     = *(const short8*)&src[0];
      *(short8*)&Bs[brow][bc0 + 8] = *(const short8*)&src[8];
    }
    __syncthreads();
    #pragma unroll
    for (int ks = 0; ks < 2; ks++) {
      int kk = ks * 32 + quad * 8;
      short8 bfr = *(const short8*)&Bs[wave * 16 + l15][kk];
      #pragma unroll
      for (int mt = 0; mt < 8; mt++) {
        short8 afr = *(const short8*)&As[mt * 16 + l15][kk];
        acc[mt] = __builtin_amdgcn_mfma_f32_16x16x32_bf16(afr, bfr, acc[mt], 0, 0, 0);
      }
    }
    __syncthreads();
  }

  int n = n0 + wave * 16 + l15;
  if (n < Nout) {
    float bv = bias0 ? (side ? bias1[n] : bias0[n]) : 0.f;
    #pragma unroll
    for (int mt = 0; mt < 8; mt++) {
      #pragma unroll
      for (int r = 0; r < 4; r++) {
        int m = m0 + mt * 16 + quad * 4 + r;
        if (m < M) {
          float val = acc[mt][r] + bv;
          if (OUTBF)
            ((bf16*)Cptr)[(size_t)side * Cstride + (size_t)m * Nstride + n] = __float2bfloat16(val);
          else
            ((float*)Cptr)[(size_t)side * Cstride + (size_t)m * Nstride + n] = val;
        }
      }
    }
  }
}

// standalone k_gg (used for giall)
template<bool OUTBF, bool AF32>
__global__ __launch_bounds__(256) void k_gg(
    const void* __restrict__ Aptr, const bf16* __restrict__ Bptr,
    const float* __restrict__ bias0, const float* __restrict__ bias1,
    void* __restrict__ Cptr,
    int M, int Nout, int KP, int Acols,
    long Astride, long Bstride, long Cstride, int Nstride)
{
  __shared__ bf16 As[128][72];
  __shared__ bf16 Bs[64][72];
  ggbody<OUTBF, AF32>(As, Bs, Aptr, Bptr, bias0, bias1, Cptr,
                      M, Nout, KP, Acols, Astride, Bstride, Cstride, Nstride,
                      blockIdx.z, blockIdx.x * 128, blockIdx.y * 64);
}

// ---------------------------------------------------------------- merged mid GEMMs: ep2 + biasb + gibase
// blocks: [0,553)=ep2 (79x7), [553,585)=biasb (4x4x2), [585,665)=gibase (4x10x2)
__global__ __launch_bounds__(256) void k_ggmid(
    const float* __restrict__ ent, const bf16* __restrict__ Wn2, bf16* __restrict__ ep2,
    const bf16* __restrict__ Abias, const bf16* __restrict__ Wb2,
    const float* __restrict__ ab_s, const float* __restrict__ ab_o, float* __restrict__ biasb,
    const bf16* __restrict__ Agi, const bf16* __restrict__ Wg2,
    const float* __restrict__ sub_bih, const float* __restrict__ ob_bih, bf16* __restrict__ gibase)
{
  __shared__ bf16 As[128][72];
  __shared__ bf16 Bs[64][72];
  int bid = blockIdx.x;
  if (bid < 553) {
    int bx = bid % 79, by = bid / 79;
    ggbody<true, true>(As, Bs, (const void*)ent, Wn2, nullptr, nullptr, (void*)ep2,
                       E_, 400, 256, 200, 0L, 0L, 0L, 400, 0, bx * 128, by * 64);
  } else if (bid < 585) {
    int idx = bid - 553;
    int side = idx >> 4; idx &= 15;
    int bx = idx & 3, by = idx >> 2;
    ggbody<false, false>(As, Bs, (const void*)Abias, Wb2, ab_s, ab_o, (void*)biasb,
                         B_, 200, 448, 448, (long)B_ * 448, 256L * 448, (long)B_ * 200, 200,
                         side, bx * 128, by * 64);
  } else {
    int idx = bid - 585;
    int side = idx / 40; idx %= 40;
    int bx = idx & 3, by = idx >> 2;
    ggbody<true, false>(As, Bs, (const void*)Agi, Wg2, sub_bih, ob_bih, (void*)gibase,
                        B_, 600, 448, 448, (long)B_ * 448, 640L * 448, (long)B_ * 600, 600,
                        side, bx * 128, by * 64);
  }
}

// ---------------------------------------------------------------- attention v3: one block per (side,b,t)
__global__ __launch_bounds__(256) void k_attn3(
    const float* __restrict__ ent,
    const int* __restrict__ neigh0, const int* __restrict__ neigh1,
    const int* __restrict__ nlen0, const int* __restrict__ nlen1,
    const int* __restrict__ hlen0, const int* __restrict__ hlen1,
    const float* __restrict__ v0, const float* __restrict__ v1,
    const bf16* __restrict__ ep2, const float* __restrict__ biasb,
    bf16* __restrict__ stepb)
{
  int side = blockIdx.y;
  int bt = blockIdx.x;
  int b = bt / T_, t = bt % T_;
  int hl = (side ? hlen1 : hlen0)[b];
  bf16* srow = stepb + (((size_t)side * B_ + b) * T_ + t) * 256;
  int tid = threadIdx.x;
  if (t >= hl) {     // masked timestep: zero row (uniform branch)
    srow[tid] = __float2bfloat16(0.f);
    return;
  }
  const int* neigh = side ? neigh1 : neigh0;
  const float* v = side ? v1 : v0;
  const float* brow = biasb + ((size_t)side * B_ + b) * H_;
  int nl = (side ? nlen1 : nlen0)[b * T_ + t];

  __shared__ float bsh[H_], vsh[H_], lg[64], wsh[64];
  __shared__ int nb[N_];
  if (tid < H_) { bsh[tid] = brow[tid]; vsh[tid] = v[tid]; }
  if (tid < N_) nb[tid] = neigh[((size_t)b * T_ + t) * N_ + tid];
  __syncthreads();

  int grp = tid >> 4;        // 0..15
  int l16 = tid & 15;

  float bs[13], vs[13];
  #pragma unroll
  for (int i = 0; i < 13; i++) {
    int g = l16 + i * 16;
    bool ok = (g < H_);
    bs[i] = ok ? bsh[g] : 0.f;
    vs[i] = ok ? vsh[g] : 0.f;
  }

  for (int n = grp; n < nl; n += 16) {
    const bf16* er = ep2 + (size_t)nb[n] * 400 + side * 200;
    float acc = 0.f;
    #pragma unroll
    for (int i = 0; i < 13; i++) {
      int g = l16 + i * 16;
      float e = (g < H_) ? b2f(er[g]) : 0.f;
      acc += ftanh(e + bs[i]) * vs[i];
    }
    #pragma unroll
    for (int off = 8; off > 0; off >>= 1) acc += __shfl_down(acc, off, 16);
    if (l16 == 0) lg[n] = acc;
  }
  __syncthreads();

  if (tid < 64) {
    float x = (tid < nl) ? lg[tid] : -1e30f;
    float m = x;
    #pragma unroll
    for (int off = 32; off > 0; off >>= 1) m = fmaxf(m, __shfl_down(m, off));
    m = __shfl(m, 0);
    float e = (tid < nl) ? __expf(x - m) : 0.f;
    float s = e;
    #pragma unroll
    for (int off = 32; off > 0; off >>= 1) s += __shfl_down(s, off);
    s = __shfl(s, 0);
    if (tid < N_) wsh[tid] = e / s;
  }
  __syncthreads();

  int h = tid;
  if (h < H_) {
    float a0 = 0.f, a1 = 0.f, a2 = 0.f, a3 = 0.f;
    int n = 0;
    for (; n + 4 <= nl; n += 4) {
      a0 += wsh[n + 0] * ent[(size_t)nb[n + 0] * H_ + h];
      a1 += wsh[n + 1] * ent[(size_t)nb[n + 1] * H_ + h];
      a2 += wsh[n + 2] * ent[(size_t)nb[n + 2] * H_ + h];
      a3 += wsh[n + 3] * ent[(size_t)nb[n + 3] * H_ + h];
    }
    for (; n < nl; n++) a0 += wsh[n] * ent[(size_t)nb[n] * H_ + h];
    srow[h] = __float2bfloat16((a0 + a1) + (a2 + a3));
  } else {
    srow[h] = __float2bfloat16(0.f);   // pad cols 200..255
  }
}

// ---------------------------------------------------------------- MFMA GRU v4
__global__ __launch_bounds__(832) void k_gru4(
    const bf16* __restrict__ giall, const bf16* __restrict__ gibase,
    const bf16* __restrict__ Whh2,
    const float* __restrict__ bhh0, const float* __restrict__ bhh1,
    const int* __restrict__ len0, const int* __restrict__ len1,
    float* __restrict__ hfin)
{
  int side = blockIdx.y;
  int b0 = blockIdx.x * 16;
  const bf16* gia = giall + ((size_t)side * B_ * T_ + (size_t)b0 * T_) * 600;
  const bf16* gib = gibase + ((size_t)side * B_ + b0) * K3;
  const bf16* Wh  = Whh2 + (size_t)side * 608 * 224;
  const float* bhh = side ? bhh1 : bhh0;
  const int* len = side ? len1 : len0;

  __shared__ __align__(16) bf16 Hs[2][16][232];

  int tid = threadIdx.x;
  int wave = tid >> 6, lane = tid & 63;
  int quad = lane >> 4, l15 = lane & 15;

  for (int i = tid; i < 2 * 16 * 232 / 8; i += 832) ((short8*)&Hs[0][0][0])[i] = (short8)0;

  int j0 = wave * 16;
  int j = j0 + l15;
  bool jok = (j < H_);
  float bhr = 0.f, bhz = 0.f, bhn = 0.f;
  float gr[4] = {}, gz[4] = {}, gn[4] = {};
  int lens4[4];
  #pragma unroll
  for (int r = 0; r < 4; r++) lens4[r] = len[b0 + quad * 4 + r];
  if (jok) {
    bhr = bhh[j]; bhz = bhh[H_ + j]; bhn = bhh[2 * H_ + j];
    #pragma unroll
    for (int r = 0; r < 4; r++) {
      const bf16* g = gib + (size_t)(quad * 4 + r) * K3;
      gr[r] = b2f(g[j]); gz[r] = b2f(g[H_ + j]); gn[r] = b2f(g[2 * H_ + j]);
    }
  }
  const bf16* wr = Wh + (size_t)j * 224;
  const bf16* wz = Wh + (size_t)(200 + j) * 224;
  const bf16* wn = Wh + (size_t)(400 + j) * 224;
  __syncthreads();

  int cur = 0;
  for (int t = 0; t < T_; t++) {
    unsigned short guR[4], guZ[4], guN[4];
    if (jok) {
      #pragma unroll
      for (int r = 0; r < 4; r++) {
        const unsigned short* g =
            (const unsigned short*)(gia + ((size_t)(quad * 4 + r) * T_ + t) * 600);
        guR[r] = g[j]; guZ[r] = g[200 + j]; guN[r] = g[400 + j];
      }
    }
    f32x4 ar = {0,0,0,0}, az = {0,0,0,0}, anh = {0,0,0,0};
    #pragma unroll
    for (int ks = 0; ks < 7; ks++) {
      int kk = ks * 32 + quad * 8;
      short8 a0 = *(const short8*)&Hs[cur][l15][kk];
      short8 br = *(const short8*)&wr[kk];
      short8 bz = *(const short8*)&wz[kk];
      short8 bn = *(const short8*)&wn[kk];
      ar  = __builtin_amdgcn_mfma_f32_16x16x32_bf16(a0, br, ar, 0, 0, 0);
      az  = __builtin_amdgcn_mfma_f32_16x16x32_bf16(a0, bz, az, 0, 0, 0);
      anh = __builtin_amdgcn_mfma_f32_16x16x32_bf16(a0, bn, anh, 0, 0, 0);
    }
    if (jok) {
      #pragma unroll
      for (int r = 0; r < 4; r++) {
        int row = quad * 4 + r;
        float rz  = ar[r] + u2f(guR[r]) + gr[r] + bhr;
        float zz  = az[r] + u2f(guZ[r]) + gz[r] + bhz;
        float inn = u2f(guN[r]) + gn[r];
        float hn  = anh[r] + bhn;
        float rg = fsigm(rz);
        float zg = fsigm(zz);
        float ng = ftanh(inn + rg * hn);
        float hold = b2f(Hs[cur][row][j]);
        float hnew = (1.f - zg) * ng + zg * hold;
        Hs[cur ^ 1][row][j] = __float2bfloat16((t < lens4[r]) ? hnew : hold);
      }
    }
    __syncthreads();
    cur ^= 1;
  }
  for (int i = tid; i < 16 * H_; i += 832) {
    int row = i / H_, jj = i % H_;
    hfin[((size_t)side * B_ + b0 + row) * H_ + jj] = b2f(Hs[cur][row][jj]);
  }
}

// ---------------------------------------------------------------- assemble pred-GEMM input rows (bf16, K padded to 640)
__global__ __launch_bounds__(256) void k_feat(
    const float* __restrict__ ent, const float* __restrict__ rel, const int* __restrict__ trip,
    const int* __restrict__ idxbuf, const float* __restrict__ hfin,
    bf16* __restrict__ xfeat)
{
  int i = blockIdx.x, p = blockIdx.y;
  int bi = idxbuf[(p == 0 ? 1 : 0) * B_ + i];
  int ent_id = (p == 0) ? trip[bi * 3 + 2] : trip[bi * 3 + 0];
  int rid = trip[bi * 3 + 1];
  const float* hsrc = hfin + (size_t)(p == 0 ? 1 : 0) * B_ * H_;
  bf16* x = xfeat + ((size_t)p * B_ + i) * 640;
  int h = threadIdx.x;
  if (h < H_) {
    x[h]          = __float2bfloat16(ent[(size_t)ent_id * H_ + h]);
    x[H_ + h]     = __float2bfloat16(hsrc[(size_t)bi * H_ + h]);
    x[2 * H_ + h] = __float2bfloat16(rel[(size_t)rid * H_ + h]);
  }
  if (h < 40) x[600 + h] = __float2bfloat16(0.f);
}

// ---------------------------------------------------------------- MFMA pred GEMM v9 (bf16 B + fused sumexp, NO atomics)
__global__ __launch_bounds__(512) void k_gemm6(
    const bf16* __restrict__ Abf, const bf16* __restrict__ Wlin,
    const float* __restrict__ bias0, const float* __restrict__ bias1,
    float* __restrict__ dout, float* __restrict__ pexp)
{
  int side = blockIdx.z;
  const bf16* Bm = Wlin + (size_t)side * EP_ * 640;
  const float* bias = side ? bias1 : bias0;
  float* C = dout + 1 + (size_t)side * B_ * E_;
  int mBase = blockIdx.x * 256;
  int m0 = side * B_ + mBase;
  int n0 = blockIdx.y * 64;

  __shared__ bf16 As[256][72];
  __shared__ bf16 Bs[64][72];
  __shared__ float Ps[2][256];   // [wn][row_local] exp partials

  int tid = threadIdx.x;
  int wave = tid >> 6, lane = tid & 63;
  int quad = lane >> 4, l15 = lane & 15;
  int wm = wave >> 1, wn = wave & 1;   // 4x2 wave grid

  f32x4 acc[4][2];
  #pragma unroll
  for (int mt = 0; mt < 4; mt++)
    #pragma unroll
    for (int nt = 0; nt < 2; nt++) acc[mt][nt] = (f32x4){0,0,0,0};

  int arow = tid >> 1, ac0 = (tid & 1) * 32;       // A: 256 rows, 32-elem halves
  int brow = tid >> 3, bc0 = (tid & 7) * 8;        // B: 64 rows, 8 bf16 each
  const bf16* asrc = Abf + (size_t)(m0 + arow) * 640 + ac0;
  const bf16* bsrc = Bm + (size_t)(n0 + brow) * 640 + bc0;

  for (int k0 = 0; k0 < 640; k0 += 64) {
    #pragma unroll
    for (int u = 0; u < 4; u++)
      *(short8*)&As[arow][ac0 + u * 8] = *(const short8*)&asrc[k0 + u * 8];
    *(short8*)&Bs[brow][bc0] = *(const short8*)&bsrc[k0];
    __syncthreads();
    #pragma unroll
    for (int ks = 0; ks < 2; ks++) {
      int kk = ks * 32 + quad * 8;
      short8 bfr[2];
      #pragma unroll
      for (int nt = 0; nt < 2; nt++)
        bfr[nt] = *(const short8*)&Bs[wn * 32 + nt * 16 + l15][kk];
      #pragma unroll
      for (int mt = 0; mt < 4; mt++) {
        short8 afr = *(const short8*)&As[wm * 64 + mt * 16 + l15][kk];
        #pragma unroll
        for (int nt = 0; nt < 2; nt++)
          acc[mt][nt] = __builtin_amdgcn_mfma_f32_16x16x32_bf16(afr, bfr[nt], acc[mt][nt], 0, 0, 0);
      }
    }
    __syncthreads();
  }

  // epilogue: row_local = wm*64 + mt*16 + quad*4 + r; col = n0 + wn*32 + nt*16 + l15
  float bv[2];
  int ncol[2];
  #pragma unroll
  for (int nt = 0; nt < 2; nt++) {
    ncol[nt] = n0 + wn * 32 + nt * 16 + l15;
    bv[nt] = (ncol[nt] < E_) ? bias[ncol[nt]] : 0.f;
  }
  #pragma unroll
  for (int mt = 0; mt < 4; mt++) {
    #pragma unroll
    for (int r = 0; r < 4; r++) {
      int rloc = wm * 64 + mt * 16 + quad * 4 + r;
      int mrow = mBase + rloc;
      float p = 0.f;
      #pragma unroll
      for (int nt = 0; nt < 2; nt++) {
        if (ncol[nt] < E_) {
          float val = acc[mt][nt][r] + bv[nt];
          C[(size_t)mrow * E_ + ncol[nt]] = val;
          p += __expf(val);
        }
      }
      // reduce 32 cols of this row held by this wave (16 lanes x 2 cols)
      #pragma unroll
      for (int off = 8; off > 0; off >>= 1) p += __shfl_down(p, off, 16);
      if (l15 == 0) Ps[wn][rloc] = p;
    }
  }
  __syncthreads();
  if (tid < 256) {
    float p = Ps[0][tid] + Ps[1][tid];
    pexp[((size_t)side * NBLK_ + blockIdx.y) * 512 + mBase + tid] = p;
  }
}

// ---------------------------------------------------------------- MFMA pred GEMM v5 (fp32 B fallback, ws too small)
__global__ __launch_bounds__(512) void k_gemm5(
    const bf16* __restrict__ Abf,
    const float* __restrict__ B0, const float* __restrict__ B1,
    const float* __restrict__ bias0, const float* __restrict__ bias1,
    float* __restrict__ dout, float* __restrict__ pexp)
{
  int side = blockIdx.z;
  const float* Bm = side ? B1 : B0;
  const float* bias = side ? bias1 : bias0;
  float* C = dout + 1 + (size_t)side * B_ * E_;
  int mBase = blockIdx.x * 256;
  int m0 = side * B_ + mBase;
  int n0 = blockIdx.y * 64;

  __shared__ bf16 As[256][72];
  __shared__ bf16 Bs[64][72];
  __shared__ float Ps[2][256];

  int tid = threadIdx.x;
  int wave = tid >> 6, lane = tid & 63;
  int quad = lane >> 4, l15 = lane & 15;
  int wm = wave >> 1, wn = wave & 1;

  f32x4 acc[4][2];
  #pragma unroll
  for (int mt = 0; mt < 4; mt++)
    #pragma unroll
    for (int nt = 0; nt < 2; nt++) acc[mt][nt] = (f32x4){0,0,0,0};

  int arow = tid >> 1, ac0 = (tid & 1) * 32;
  int brow = tid >> 3, bc0 = (tid & 7) * 8;
  const bf16* asrc = Abf + (size_t)(m0 + arow) * 640 + ac0;
  int nsrc = n0 + brow; if (nsrc > E_ - 1) nsrc = E_ - 1;
  const float* bsrc = Bm + (size_t)nsrc * K3 + bc0;

  for (int k0 = 0; k0 < 640; k0 += 64) {
    #pragma unroll
    for (int u = 0; u < 4; u++)
      *(short8*)&As[arow][ac0 + u * 8] = *(const short8*)&asrc[k0 + u * 8];
    {
      int kb = k0 + bc0;
      if (kb + 8 <= K3) {
        float4 v0 = *(const float4*)&bsrc[k0];
        float4 v1 = *(const float4*)&bsrc[k0 + 4];
        Bs[brow][bc0 + 0] = __float2bfloat16(v0.x);
        Bs[brow][bc0 + 1] = __float2bfloat16(v0.y);
        Bs[brow][bc0 + 2] = __float2bfloat16(v0.z);
        Bs[brow][bc0 + 3] = __float2bfloat16(v0.w);
        Bs[brow][bc0 + 4] = __float2bfloat16(v1.x);
        Bs[brow][bc0 + 5] = __float2bfloat16(v1.y);
        Bs[brow][bc0 + 6] = __float2bfloat16(v1.z);
        Bs[brow][bc0 + 7] = __float2bfloat16(v1.w);
      } else {
        #pragma unroll
        for (int u = 0; u < 8; u++) {
          int k = kb + u;
          float v = (k < K3) ? bsrc[k0 + u] : 0.f;
          Bs[brow][bc0 + u] = __float2bfloat16(v);
        }
      }
    }
    __syncthreads();
    #pragma unroll
    for (int ks = 0; ks < 2; ks++) {
      int kk = ks * 32 + quad * 8;
      short8 bfr[2];
      #pragma unroll
      for (int nt = 0; nt < 2; nt++)
        bfr[nt] = *(const short8*)&Bs[wn * 32 + nt * 16 + l15][kk];
      #pragma unroll
      for (int mt = 0; mt < 4; mt++) {
        short8 afr = *(const short8*)&As[wm * 64 + mt * 16 + l15][kk];
        #pragma unroll
        for (int nt = 0; nt < 2; nt++)
          acc[mt][nt] = __builtin_amdgcn_mfma_f32_16x16x32_bf16(afr, bfr[nt], acc[mt][nt], 0, 0, 0);
      }
    }
    __syncthreads();
  }

  float bv[2];
  int ncol[2];
  #pragma unroll
  for (int nt = 0; nt < 2; nt++) {
    ncol[nt] = n0 + wn * 32 + nt * 16 + l15;
    bv[nt] = (ncol[nt] < E_) ? bias[ncol[nt]] : 0.f;
  }
  #pragma unroll
  for (int mt = 0; mt < 4; mt++) {
    #pragma unroll
    for (int r = 0; r < 4; r++) {
      int rloc = wm * 64 + mt * 16 + quad * 4 + r;
      int mrow = mBase + rloc;
      float p = 0.f;
      #pragma unroll
      for (int nt = 0; nt < 2; nt++) {
        if (ncol[nt] < E_) {
          float val = acc[mt][nt][r] + bv[nt];
          C[(size_t)mrow * E_ + ncol[nt]] = val;
          p += __expf(val);
        }
      }
      #pragma unroll
      for (int off = 8; off > 0; off >>= 1) p += __shfl_down(p, off, 16);
      if (l15 == 0) Ps[wn][rloc] = p;
    }
  }
  __syncthreads();
  if (tid < 256) {
    float p = Ps[0][tid] + Ps[1][tid];
    pexp[((size_t)side * NBLK_ + blockIdx.y) * 512 + mBase + tid] = p;
  }
}

// ---------------------------------------------------------------- final CE loss from pexp partials
__global__ __launch_bounds__(1024) void k_loss3(
    const float* __restrict__ dout_ro, const int* __restrict__ trip,
    const int* __restrict__ idxbuf, const float* __restrict__ pexp,
    float* __restrict__ dout)
{
  int tid = threadIdx.x;            // 0..1023
  int p = tid >> 9, i = tid & 511;
  float s = 0.f;
  for (int nb = 0; nb < NBLK_; nb++)
    s += pexp[((size_t)p * NBLK_ + nb) * 512 + i];
  int bi = idxbuf[(p == 0 ? 1 : 0) * B_ + i];
  int label = (p == 0) ? trip[bi * 3 + 0] : trip[bi * 3 + 2];
  float val = dout_ro[1 + (size_t)p * B_ * E_ + (size_t)i * E_ + label];
  float part = -(val - logf(s)) / (float)B_;
  __shared__ float ps[1024];
  ps[tid] = part; __syncthreads();
  for (int st = 512; st > 0; st >>= 1) {
    if (tid < st) ps[tid] += ps[tid + st];
    __syncthreads();
  }
  if (tid == 0) dout[0] = ps[0];
}

// ----------------------------------------------------------------
extern "C" void kernel_launch(void* const* d_in, const int* in_sizes, int n_in,
                              void* d_out, int out_size, void* d_ws, size_t ws_size,
                              hipStream_t stream)
{
  const int* trip = (const int*)d_in[0];
  const int* s_ne = (const int*)d_in[1];
  const int* s_nl = (const int*)d_in[2];
  const int* s_hl = (const int*)d_in[3];
  const int* o_ne = (const int*)d_in[4];
  const int* o_nl = (const int*)d_in[5];
  const int* o_hl = (const int*)d_in[6];
  const float* ent = (const float*)d_in[7];
  const float* rel = (const float*)d_in[8];
  const float* aw_s = (const float*)d_in[9];
  const float* ab_s = (const float*)d_in[10];
  const float* v_s  = (const float*)d_in[11];
  const float* aw_o = (const float*)d_in[12];
  const float* ab_o = (const float*)d_in[13];
  const float* v_o  = (const float*)d_in[14];
  const float* sub_wih = (const float*)d_in[15];
  const float* sub_whh = (const float*)d_in[16];
  const float* sub_bih = (const float*)d_in[17];
  const float* sub_bhh = (const float*)d_in[18];
  const float* ob_wih  = (const float*)d_in[19];
  const float* ob_whh  = (const float*)d_in[20];
  const float* ob_bih  = (const float*)d_in[21];
  const float* ob_bhh  = (const float*)d_in[22];
  const float* lin_sub_w = (const float*)d_in[23];
  const float* lin_sub_b = (const float*)d_in[24];
  const float* lin_ob_w  = (const float*)d_in[25];
  const float* lin_ob_b  = (const float*)d_in[26];
  float* dout = (float*)d_out;

  // workspace carve — base ~35.2 MB, +25.7 MB for bf16 pred weights if it fits
  char* w = (char*)d_ws;
  bf16* ep2     = (bf16*)w;  w += (size_t)E_ * 400 * 2;           //  8,000,000 B
  bf16* stepb   = (bf16*)w;  w += (size_t)2 * B_ * T_ * 256 * 2;  //  5,242,880 B
  float* biasb  = (float*)w; w += (size_t)2 * B_ * H_ * 4;        //    819,200 B
  bf16* gibase  = (bf16*)w;  w += (size_t)2 * B_ * K3 * 2;        //  1,228,800 B
  float* hfin   = (float*)w; w += (size_t)2 * B_ * H_ * 4;        //    819,200 B
  bf16* xfeat   = (bf16*)w;  w += (size_t)1024 * 640 * 2;         //  1,310,720 B
  bf16* Wn2     = (bf16*)w;  w += (size_t)448 * 256 * 2;          //    229,376 B
  bf16* Wb2     = (bf16*)w;  w += (size_t)2 * 256 * 448 * 2;      //    458,752 B
  bf16* Wg2     = (bf16*)w;  w += (size_t)2 * 640 * 448 * 2;      //  1,146,880 B
  bf16* Wstep   = (bf16*)w;  w += (size_t)2 * 640 * 256 * 2;      //    655,360 B
  bf16* Whh2    = (bf16*)w;  w += (size_t)2 * 608 * 224 * 2;      //    544,768 B
  bf16* giall   = (bf16*)w;  w += (size_t)2 * B_ * T_ * 600 * 2;  // 12,288,000 B
  bf16* Abias   = (bf16*)w;  w += (size_t)2 * B_ * 448 * 2;       //    917,504 B
  bf16* Agi     = (bf16*)w;  w += (size_t)2 * B_ * 448 * 2;       //    917,504 B
  float* pexp   = (float*)w; w += (size_t)2 * NBLK_ * 512 * 4;    //    643,072 B
  int* idxbuf   = (int*)w;   w += 4096;
  bf16* Wlin    = (bf16*)w;  w += (size_t)2 * EP_ * 640 * 2;      // 25,722,880 B
  bool useBf16B = ((size_t)(w - (char*)d_ws) <= ws_size);

  // mega pack (+ vectorized Wlin prepack + argsort)
  k_packall<<<5760 + WLINBLK_ + 2, 256, 0, stream>>>(
      aw_s, aw_o, sub_wih, ob_wih, sub_whh, ob_whh,
      ent, rel, trip, lin_ob_w, lin_sub_w, s_hl, o_hl,
      Wn2, Wb2, Wg2, Wstep, Whh2, Abias, Agi,
      Wlin, useBf16B ? 1 : 0, idxbuf, dout);
  // merged mid GEMMs: ep2 + biasb + gibase (665 blocks)
  k_ggmid<<<665, 256, 0, stream>>>(ent, Wn2, ep2,
                                   Abias, Wb2, ab_s, ab_o, biasb,
                                   Agi, Wg2, sub_bih, ob_bih, gibase);
  // attention (one block per (side,b,t))
  k_attn3<<<dim3(B_ * T_, 2), 256, 0, stream>>>(ent, s_ne, o_ne, s_nl, o_nl,
                                                s_hl, o_hl, v_s, v_o, ep2, biasb, stepb);
  // giall = step @ Wih[:, :200].T  for all (b,t)  (M=5120/side, N=600, K=256pad)
  k_gg<true, false><<<dim3(40, 10, 2), 256, 0, stream>>>(
      (const void*)stepb, Wstep, nullptr, nullptr, (void*)giall,
      B_ * T_, 600, 256, 256, (long)B_ * T_ * 256, 640L * 256, (long)B_ * T_ * 600, 600);
  // GRU (recurrent part only: K=224)
  k_gru4<<<dim3(B_ / 16, 2), 832, 0, stream>>>(giall, gibase, Whh2, sub_bhh, ob_bhh,
                                               s_hl, o_hl, hfin);
  k_feat<<<dim3(B_, 2), 256, 0, stream>>>(ent, rel, trip, idxbuf, hfin, xfeat);
  // pred GEMM with fused exp-partials (no atomics)
  if (useBf16B)
    k_gemm6<<<dim3(2, NBLK_, 2), 512, 0, stream>>>(
        xfeat, Wlin, lin_ob_b, lin_sub_b, dout, pexp);
  else
    k_gemm5<<<dim3(2, NBLK_, 2), 512, 0, stream>>>(
        xfeat, lin_ob_w, lin_sub_w, lin_ob_b, lin_sub_b, dout, pexp);
  k_loss3<<<1, 1024, 0, stream>>>(dout, trip, idxbuf, pexp, dout);
}

// Round 13
// 343.011 us; speedup vs baseline: 1.2288x; 1.0211x over previous
//
#include <hip/hip_runtime.h>
#include <hip/hip_bf16.h>
#include <math.h>

typedef __hip_bfloat16 bf16;
typedef __attribute__((ext_vector_type(8))) short short8;
typedef __attribute__((ext_vector_type(4))) float f32x4;

#define B_ 512
#define T_ 10
#define N_ 50
#define H_ 200
#define E_ 10000
#define R_ 200
#define K3 600   // 3*H
#define EP_ 10048  // E_ padded to 64 for guard-free B staging
#define NBLK_ 157  // (E_+63)/64 N-blocks in pred GEMM
#define WLINBLK_ 6280  // 2*EP_*640 / (256*8)

__device__ __forceinline__ float b2f(bf16 x){ return __bfloat162float(x); }
__device__ __forceinline__ float u2f(unsigned short u){
  unsigned int x = ((unsigned int)u) << 16;
  return __builtin_bit_cast(float, x);
}
// fast sigmoid/tanh: v_exp_f32 + v_rcp_f32 (~1 ulp), instead of libm calls
__device__ __forceinline__ float fsigm(float x){
  return __builtin_amdgcn_rcpf(1.f + __expf(-x));
}
__device__ __forceinline__ float ftanh(float x){
  x = fminf(15.f, fmaxf(-15.f, x));
  float e = __expf(-2.f * x);
  return (1.f - e) * __builtin_amdgcn_rcpf(1.f + e);
}

// ---------------------------------------------------------------- mega pack (one dispatch)
// sections by blockIdx.x:
//  [0,448)          Wn2[448][256]
//  [448,960)        Wb2[2][256][448]
//  [960,2240)       Wg2[2][640][448]
//  [2240,3520)      Wstep[2][640][256]
//  [3520,4736)      Whh2[2][608][224]
//  [4736,5760)      Abias/Agi
//  [5760,12040)     Wlin bf16 prepack, vectorized: 8 elems/thread, float4x2 -> short8
//  [12040,12042)    argsort per side (256 thr, 2 elems each) + perm->dout
__global__ __launch_bounds__(256) void k_packall(
    const float* __restrict__ aw_s, const float* __restrict__ aw_o,
    const float* __restrict__ sub_wih, const float* __restrict__ ob_wih,
    const float* __restrict__ sub_whh, const float* __restrict__ ob_whh,
    const float* __restrict__ ent, const float* __restrict__ rel,
    const int* __restrict__ trip,
    const float* __restrict__ lin_ob_w, const float* __restrict__ lin_sub_w,
    const int* __restrict__ hlen0, const int* __restrict__ hlen1,
    bf16* __restrict__ Wn2, bf16* __restrict__ Wb2, bf16* __restrict__ Wg2,
    bf16* __restrict__ Wstep, bf16* __restrict__ Whh2,
    bf16* __restrict__ Ab, bf16* __restrict__ Ag,
    bf16* __restrict__ Wlin, int useBf16B,
    int* __restrict__ idxbuf, float* __restrict__ dout)
{
  int bid = blockIdx.x;
  int tid = threadIdx.x;
  if (bid < 448) {
    int r = bid;
    const float* Wa = (r < 200) ? aw_s : aw_o;
    int g = (r < 200) ? r : r - 200;
    bf16* out = Wn2 + (size_t)r * 256;
    for (int k = tid; k < 256; k += 256) {
      float v = (r < 400 && k < 200) ? Wa[(size_t)g * K3 + k] : 0.f;
      out[k] = __float2bfloat16(v);
    }
  } else if (bid < 960) {
    int idx = bid - 448;
    int side = idx >> 8, r = idx & 255;
    const float* W = side ? aw_o : aw_s;
    bf16* out = Wb2 + ((size_t)side * 256 + r) * 448;
    for (int k = tid; k < 448; k += 256) {
      float v = (r < 200 && k < 400) ? W[(size_t)r * K3 + 200 + k] : 0.f;
      out[k] = __float2bfloat16(v);
    }
  } else if (bid < 2240) {
    int idx = bid - 960;
    int side = idx / 640, r = idx % 640;
    const float* W = side ? ob_wih : sub_wih;
    bf16* out = Wg2 + ((size_t)side * 640 + r) * 448;
    for (int k = tid; k < 448; k += 256) {
      float v = (r < 600 && k < 400) ? W[(size_t)r * K3 + 200 + k] : 0.f;
      out[k] = __float2bfloat16(v);
    }
  } else if (bid < 3520) {
    int idx = bid - 2240;
    int side = idx / 640, r = idx % 640;
    const float* W = side ? ob_wih : sub_wih;
    bf16* out = Wstep + ((size_t)side * 640 + r) * 256;
    for (int k = tid; k < 256; k += 256) {
      float v = (r < 600 && k < 200) ? W[(size_t)r * K3 + k] : 0.f;
      out[k] = __float2bfloat16(v);
    }
  } else if (bid < 4736) {
    int idx = bid - 3520;
    int side = idx / 608, r = idx % 608;
    const float* W = side ? ob_whh : sub_whh;
    bf16* out = Whh2 + ((size_t)side * 608 + r) * 224;
    for (int k = tid; k < 224; k += 256) {
      float v = (r < 600 && k < 200) ? W[(size_t)r * H_ + k] : 0.f;
      out[k] = __float2bfloat16(v);
    }
  } else if (bid < 5760) {
    int idx = bid - 4736;
    int side = idx >> 9, b = idx & 511;
    int ids = trip[b * 3 + (side ? 2 : 0)];
    int rid = trip[b * 3 + 1];
    size_t ro = ((size_t)side * B_ + b) * 448;
    for (int k = tid; k < 448; k += 256) {
      float vb = 0.f, vg = 0.f;
      if (k < 200) { float e = ent[(size_t)ids * H_ + k]; vb = e; vg = e; }
      else if (k < 400) {
        vb = ent[(size_t)rid * H_ + (k - 200)];
        vg = rel[(size_t)rid * H_ + (k - 200)];
      }
      Ab[ro + k] = __float2bfloat16(vb);
      Ag[ro + k] = __float2bfloat16(vg);
    }
  } else if (bid < 5760 + WLINBLK_) {
    if (!useBf16B) return;
    // flat vectorized prepack: 8 consecutive bf16 per thread.
    // 600 % 8 == 0 so each chunk is fully in-bounds or fully pad.
    size_t base = ((size_t)(bid - 5760) * 256 + tid) * 8;   // elem offset in [2][EP_][640]
    int side = (int)(base / ((size_t)EP_ * 640));
    size_t rem = base - (size_t)side * EP_ * 640;
    int row = (int)(rem / 640);
    int k = (int)(rem % 640);
    const float* W = side ? lin_sub_w : lin_ob_w;
    short8 outv = (short8)0;
    if (row < E_ && k < K3) {
      const float* src = W + (size_t)row * K3 + k;
      float4 v0 = *(const float4*)&src[0];
      float4 v1 = *(const float4*)&src[4];
      bf16 tmp[8];
      tmp[0] = __float2bfloat16(v0.x); tmp[1] = __float2bfloat16(v0.y);
      tmp[2] = __float2bfloat16(v0.z); tmp[3] = __float2bfloat16(v0.w);
      tmp[4] = __float2bfloat16(v1.x); tmp[5] = __float2bfloat16(v1.y);
      tmp[6] = __float2bfloat16(v1.z); tmp[7] = __float2bfloat16(v1.w);
      outv = *(short8*)tmp;
    }
    *(short8*)&Wlin[base] = outv;
  } else {
    int side = bid - (5760 + WLINBLK_);
    const int* len = side ? hlen1 : hlen0;
    __shared__ int lens[B_];
    __shared__ int perm[B_];
    lens[tid] = len[tid];
    lens[tid + 256] = len[tid + 256];
    __syncthreads();
    #pragma unroll
    for (int e = 0; e < 2; e++) {
      int i = tid + e * 256;
      int L = lens[i];
      int rank = 0;
      for (int j = 0; j < B_; j++) {
        int Lj = lens[j];
        rank += (Lj > L) || (Lj == L && j < i);
      }
      perm[rank] = i;
    }
    __syncthreads();
    size_t base = 1 + (size_t)2 * B_ * E_ + (side ? 0 : B_);
    idxbuf[side * B_ + tid] = perm[tid];
    idxbuf[side * B_ + tid + 256] = perm[tid + 256];
    dout[base + tid] = (float)perm[tid];
    dout[base + tid + 256] = (float)perm[tid + 256];
  }
}

// ---------------------------------------------------------------- generic MFMA GEMM body
// C[m][n] = sum_k A[m][k]*B[n][k] (+ bias[n]); tile M=128, N=64, BK=64.
template<bool OUTBF, bool AF32>
__device__ __forceinline__ void ggbody(
    bf16 (*As)[72], bf16 (*Bs)[72],
    const void* __restrict__ Aptr, const bf16* __restrict__ Bptr,
    const float* __restrict__ bias0, const float* __restrict__ bias1,
    void* __restrict__ Cptr,
    int M, int Nout, int KP, int Acols,
    long Astride, long Bstride, long Cstride, int Nstride,
    int side, int m0, int n0)
{
  int tid = threadIdx.x;
  int wave = tid >> 6, lane = tid & 63;
  int quad = lane >> 4, l15 = lane & 15;

  f32x4 acc[8];
  #pragma unroll
  for (int mt = 0; mt < 8; mt++) acc[mt] = (f32x4){0,0,0,0};

  int arow = tid >> 1, ac0 = (tid & 1) * 32;
  int gr = m0 + arow; if (gr > M - 1) gr = M - 1;
  int brow = tid >> 2, bc0 = (tid & 3) * 16;

  for (int k0 = 0; k0 < KP; k0 += 64) {
    if (AF32) {
      const float* src = (const float*)Aptr + (size_t)gr * Acols;
      #pragma unroll
      for (int u = 0; u < 8; u++) {
        int kk = k0 + ac0 + u * 4;
        float4 v;
        if (kk + 4 <= Acols) v = *(const float4*)&src[kk];
        else {
          v.x = (kk + 0 < Acols) ? src[kk + 0] : 0.f;
          v.y = (kk + 1 < Acols) ? src[kk + 1] : 0.f;
          v.z = (kk + 2 < Acols) ? src[kk + 2] : 0.f;
          v.w = (kk + 3 < Acols) ? src[kk + 3] : 0.f;
        }
        As[arow][ac0 + u * 4 + 0] = __float2bfloat16(v.x);
        As[arow][ac0 + u * 4 + 1] = __float2bfloat16(v.y);
        As[arow][ac0 + u * 4 + 2] = __float2bfloat16(v.z);
        As[arow][ac0 + u * 4 + 3] = __float2bfloat16(v.w);
      }
    } else {
      const bf16* src = (const bf16*)Aptr + (size_t)side * Astride + (size_t)gr * KP + k0 + ac0;
      #pragma unroll
      for (int u = 0; u < 4; u++)
        *(short8*)&As[arow][ac0 + u * 8] = *(const short8*)&src[u * 8];
    }
    {
      const bf16* src = Bptr + (size_t)side * Bstride + (size_t)(n0 + brow) * KP + k0 + bc0;
      *(short8*)&Bs[brow][bc0]     = *(const short8*)&src[0];
      *(short8*)&Bs[brow][bc0 + 8] = *(const short8*)&src[8];
    }
    __syncthreads();
    #pragma unroll
    for (int ks = 0; ks < 2; ks++) {
      int kk = ks * 32 + quad * 8;
      short8 bfr = *(const short8*)&Bs[wave * 16 + l15][kk];
      #pragma unroll
      for (int mt = 0; mt < 8; mt++) {
        short8 afr = *(const short8*)&As[mt * 16 + l15][kk];
        acc[mt] = __builtin_amdgcn_mfma_f32_16x16x32_bf16(afr, bfr, acc[mt], 0, 0, 0);
      }
    }
    __syncthreads();
  }

  int n = n0 + wave * 16 + l15;
  if (n < Nout) {
    float bv = bias0 ? (side ? bias1[n] : bias0[n]) : 0.f;
    #pragma unroll
    for (int mt = 0; mt < 8; mt++) {
      #pragma unroll
      for (int r = 0; r < 4; r++) {
        int m = m0 + mt * 16 + quad * 4 + r;
        if (m < M) {
          float val = acc[mt][r] + bv;
          if (OUTBF)
            ((bf16*)Cptr)[(size_t)side * Cstride + (size_t)m * Nstride + n] = __float2bfloat16(val);
          else
            ((float*)Cptr)[(size_t)side * Cstride + (size_t)m * Nstride + n] = val;
        }
      }
    }
  }
}

// standalone k_gg (used for giall)
template<bool OUTBF, bool AF32>
__global__ __launch_bounds__(256) void k_gg(
    const void* __restrict__ Aptr, const bf16* __restrict__ Bptr,
    const float* __restrict__ bias0, const float* __restrict__ bias1,
    void* __restrict__ Cptr,
    int M, int Nout, int KP, int Acols,
    long Astride, long Bstride, long Cstride, int Nstride)
{
  __shared__ bf16 As[128][72];
  __shared__ bf16 Bs[64][72];
  ggbody<OUTBF, AF32>(As, Bs, Aptr, Bptr, bias0, bias1, Cptr,
                      M, Nout, KP, Acols, Astride, Bstride, Cstride, Nstride,
                      blockIdx.z, blockIdx.x * 128, blockIdx.y * 64);
}

// ---------------------------------------------------------------- merged mid GEMMs: ep2 + biasb + gibase
// blocks: [0,553)=ep2 (79x7), [553,585)=biasb (4x4x2), [585,665)=gibase (4x10x2)
__global__ __launch_bounds__(256) void k_ggmid(
    const float* __restrict__ ent, const bf16* __restrict__ Wn2, bf16* __restrict__ ep2,
    const bf16* __restrict__ Abias, const bf16* __restrict__ Wb2,
    const float* __restrict__ ab_s, const float* __restrict__ ab_o, float* __restrict__ biasb,
    const bf16* __restrict__ Agi, const bf16* __restrict__ Wg2,
    const float* __restrict__ sub_bih, const float* __restrict__ ob_bih, bf16* __restrict__ gibase)
{
  __shared__ bf16 As[128][72];
  __shared__ bf16 Bs[64][72];
  int bid = blockIdx.x;
  if (bid < 553) {
    int bx = bid % 79, by = bid / 79;
    ggbody<true, true>(As, Bs, (const void*)ent, Wn2, nullptr, nullptr, (void*)ep2,
                       E_, 400, 256, 200, 0L, 0L, 0L, 400, 0, bx * 128, by * 64);
  } else if (bid < 585) {
    int idx = bid - 553;
    int side = idx >> 4; idx &= 15;
    int bx = idx & 3, by = idx >> 2;
    ggbody<false, false>(As, Bs, (const void*)Abias, Wb2, ab_s, ab_o, (void*)biasb,
                         B_, 200, 448, 448, (long)B_ * 448, 256L * 448, (long)B_ * 200, 200,
                         side, bx * 128, by * 64);
  } else {
    int idx = bid - 585;
    int side = idx / 40; idx %= 40;
    int bx = idx & 3, by = idx >> 2;
    ggbody<true, false>(As, Bs, (const void*)Agi, Wg2, sub_bih, ob_bih, (void*)gibase,
                        B_, 600, 448, 448, (long)B_ * 448, 640L * 448, (long)B_ * 600, 600,
                        side, bx * 128, by * 64);
  }
}

// ---------------------------------------------------------------- attention v3: one block per (side,b,t)
__global__ __launch_bounds__(256) void k_attn3(
    const float* __restrict__ ent,
    const int* __restrict__ neigh0, const int* __restrict__ neigh1,
    const int* __restrict__ nlen0, const int* __restrict__ nlen1,
    const int* __restrict__ hlen0, const int* __restrict__ hlen1,
    const float* __restrict__ v0, const float* __restrict__ v1,
    const bf16* __restrict__ ep2, const float* __restrict__ biasb,
    bf16* __restrict__ stepb)
{
  int side = blockIdx.y;
  int bt = blockIdx.x;
  int b = bt / T_, t = bt % T_;
  int hl = (side ? hlen1 : hlen0)[b];
  bf16* srow = stepb + (((size_t)side * B_ + b) * T_ + t) * 256;
  int tid = threadIdx.x;
  if (t >= hl) {     // masked timestep: zero row (uniform branch)
    srow[tid] = __float2bfloat16(0.f);
    return;
  }
  const int* neigh = side ? neigh1 : neigh0;
  const float* v = side ? v1 : v0;
  const float* brow = biasb + ((size_t)side * B_ + b) * H_;
  int nl = (side ? nlen1 : nlen0)[b * T_ + t];

  __shared__ float bsh[H_], vsh[H_], lg[64], wsh[64];
  __shared__ int nb[N_];
  if (tid < H_) { bsh[tid] = brow[tid]; vsh[tid] = v[tid]; }
  if (tid < N_) nb[tid] = neigh[((size_t)b * T_ + t) * N_ + tid];
  __syncthreads();

  int grp = tid >> 4;        // 0..15
  int l16 = tid & 15;

  float bs[13], vs[13];
  #pragma unroll
  for (int i = 0; i < 13; i++) {
    int g = l16 + i * 16;
    bool ok = (g < H_);
    bs[i] = ok ? bsh[g] : 0.f;
    vs[i] = ok ? vsh[g] : 0.f;
  }

  for (int n = grp; n < nl; n += 16) {
    const bf16* er = ep2 + (size_t)nb[n] * 400 + side * 200;
    float acc = 0.f;
    #pragma unroll
    for (int i = 0; i < 13; i++) {
      int g = l16 + i * 16;
      float e = (g < H_) ? b2f(er[g]) : 0.f;
      acc += ftanh(e + bs[i]) * vs[i];
    }
    #pragma unroll
    for (int off = 8; off > 0; off >>= 1) acc += __shfl_down(acc, off, 16);
    if (l16 == 0) lg[n] = acc;
  }
  __syncthreads();

  if (tid < 64) {
    float x = (tid < nl) ? lg[tid] : -1e30f;
    float m = x;
    #pragma unroll
    for (int off = 32; off > 0; off >>= 1) m = fmaxf(m, __shfl_down(m, off));
    m = __shfl(m, 0);
    float e = (tid < nl) ? __expf(x - m) : 0.f;
    float s = e;
    #pragma unroll
    for (int off = 32; off > 0; off >>= 1) s += __shfl_down(s, off);
    s = __shfl(s, 0);
    if (tid < N_) wsh[tid] = e / s;
  }
  __syncthreads();

  int h = tid;
  if (h < H_) {
    float a0 = 0.f, a1 = 0.f, a2 = 0.f, a3 = 0.f;
    int n = 0;
    for (; n + 4 <= nl; n += 4) {
      a0 += wsh[n + 0] * ent[(size_t)nb[n + 0] * H_ + h];
      a1 += wsh[n + 1] * ent[(size_t)nb[n + 1] * H_ + h];
      a2 += wsh[n + 2] * ent[(size_t)nb[n + 2] * H_ + h];
      a3 += wsh[n + 3] * ent[(size_t)nb[n + 3] * H_ + h];
    }
    for (; n < nl; n++) a0 += wsh[n] * ent[(size_t)nb[n] * H_ + h];
    srow[h] = __float2bfloat16((a0 + a1) + (a2 + a3));
  } else {
    srow[h] = __float2bfloat16(0.f);   // pad cols 200..255
  }
}

// ---------------------------------------------------------------- MFMA GRU v4
__global__ __launch_bounds__(832) void k_gru4(
    const bf16* __restrict__ giall, const bf16* __restrict__ gibase,
    const bf16* __restrict__ Whh2,
    const float* __restrict__ bhh0, const float* __restrict__ bhh1,
    const int* __restrict__ len0, const int* __restrict__ len1,
    float* __restrict__ hfin)
{
  int side = blockIdx.y;
  int b0 = blockIdx.x * 16;
  const bf16* gia = giall + ((size_t)side * B_ * T_ + (size_t)b0 * T_) * 600;
  const bf16* gib = gibase + ((size_t)side * B_ + b0) * K3;
  const bf16* Wh  = Whh2 + (size_t)side * 608 * 224;
  const float* bhh = side ? bhh1 : bhh0;
  const int* len = side ? len1 : len0;

  __shared__ __align__(16) bf16 Hs[2][16][232];

  int tid = threadIdx.x;
  int wave = tid >> 6, lane = tid & 63;
  int quad = lane >> 4, l15 = lane & 15;

  for (int i = tid; i < 2 * 16 * 232 / 8; i += 832) ((short8*)&Hs[0][0][0])[i] = (short8)0;

  int j0 = wave * 16;
  int j = j0 + l15;
  bool jok = (j < H_);
  float bhr = 0.f, bhz = 0.f, bhn = 0.f;
  float gr[4] = {}, gz[4] = {}, gn[4] = {};
  int lens4[4];
  #pragma unroll
  for (int r = 0; r < 4; r++) lens4[r] = len[b0 + quad * 4 + r];
  if (jok) {
    bhr = bhh[j]; bhz = bhh[H_ + j]; bhn = bhh[2 * H_ + j];
    #pragma unroll
    for (int r = 0; r < 4; r++) {
      const bf16* g = gib + (size_t)(quad * 4 + r) * K3;
      gr[r] = b2f(g[j]); gz[r] = b2f(g[H_ + j]); gn[r] = b2f(g[2 * H_ + j]);
    }
  }
  const bf16* wr = Wh + (size_t)j * 224;
  const bf16* wz = Wh + (size_t)(200 + j) * 224;
  const bf16* wn = Wh + (size_t)(400 + j) * 224;
  __syncthreads();

  int cur = 0;
  for (int t = 0; t < T_; t++) {
    unsigned short guR[4], guZ[4], guN[4];
    if (jok) {
      #pragma unroll
      for (int r = 0; r < 4; r++) {
        const unsigned short* g =
            (const unsigned short*)(gia + ((size_t)(quad * 4 + r) * T_ + t) * 600);
        guR[r] = g[j]; guZ[r] = g[200 + j]; guN[r] = g[400 + j];
      }
    }
    f32x4 ar = {0,0,0,0}, az = {0,0,0,0}, anh = {0,0,0,0};
    #pragma unroll
    for (int ks = 0; ks < 7; ks++) {
      int kk = ks * 32 + quad * 8;
      short8 a0 = *(const short8*)&Hs[cur][l15][kk];
      short8 br = *(const short8*)&wr[kk];
      short8 bz = *(const short8*)&wz[kk];
      short8 bn = *(const short8*)&wn[kk];
      ar  = __builtin_amdgcn_mfma_f32_16x16x32_bf16(a0, br, ar, 0, 0, 0);
      az  = __builtin_amdgcn_mfma_f32_16x16x32_bf16(a0, bz, az, 0, 0, 0);
      anh = __builtin_amdgcn_mfma_f32_16x16x32_bf16(a0, bn, anh, 0, 0, 0);
    }
    if (jok) {
      #pragma unroll
      for (int r = 0; r < 4; r++) {
        int row = quad * 4 + r;
        float rz  = ar[r] + u2f(guR[r]) + gr[r] + bhr;
        float zz  = az[r] + u2f(guZ[r]) + gz[r] + bhz;
        float inn = u2f(guN[r]) + gn[r];
        float hn  = anh[r] + bhn;
        float rg = fsigm(rz);
        float zg = fsigm(zz);
        float ng = ftanh(inn + rg * hn);
        float hold = b2f(Hs[cur][row][j]);
        float hnew = (1.f - zg) * ng + zg * hold;
        Hs[cur ^ 1][row][j] = __float2bfloat16((t < lens4[r]) ? hnew : hold);
      }
    }
    __syncthreads();
    cur ^= 1;
  }
  for (int i = tid; i < 16 * H_; i += 832) {
    int row = i / H_, jj = i % H_;
    hfin[((size_t)side * B_ + b0 + row) * H_ + jj] = b2f(Hs[cur][row][jj]);
  }
}

// ---------------------------------------------------------------- assemble pred-GEMM input rows (bf16, K padded to 640)
__global__ __launch_bounds__(256) void k_feat(
    const float* __restrict__ ent, const float* __restrict__ rel, const int* __restrict__ trip,
    const int* __restrict__ idxbuf, const float* __restrict__ hfin,
    bf16* __restrict__ xfeat)
{
  int i = blockIdx.x, p = blockIdx.y;
  int bi = idxbuf[(p == 0 ? 1 : 0) * B_ + i];
  int ent_id = (p == 0) ? trip[bi * 3 + 2] : trip[bi * 3 + 0];
  int rid = trip[bi * 3 + 1];
  const float* hsrc = hfin + (size_t)(p == 0 ? 1 : 0) * B_ * H_;
  bf16* x = xfeat + ((size_t)p * B_ + i) * 640;
  int h = threadIdx.x;
  if (h < H_) {
    x[h]          = __float2bfloat16(ent[(size_t)ent_id * H_ + h]);
    x[H_ + h]     = __float2bfloat16(hsrc[(size_t)bi * H_ + h]);
    x[2 * H_ + h] = __float2bfloat16(rel[(size_t)rid * H_ + h]);
  }
  if (h < 40) x[600 + h] = __float2bfloat16(0.f);
}

// ---------------------------------------------------------------- MFMA pred GEMM v10 (bf16 B + fused sumexp, 128M tile)
// tile 128M x 64N x 64K, 256 threads / 4 waves (2Mx2N), wave = 64Mx32N -> acc[4][2].
// LDS 27.6 KB -> 5 blocks/CU; grid (4,157,2)=1256 blocks kills the 2.45-blocks/CU
// grid-quantization hole of the 256M version. Same fused exp-partial epilogue.
__global__ __launch_bounds__(256) void k_gemm7(
    const bf16* __restrict__ Abf, const bf16* __restrict__ Wlin,
    const float* __restrict__ bias0, const float* __restrict__ bias1,
    float* __restrict__ dout, float* __restrict__ pexp)
{
  int side = blockIdx.z;
  const bf16* Bm = Wlin + (size_t)side * EP_ * 640;
  const float* bias = side ? bias1 : bias0;
  float* C = dout + 1 + (size_t)side * B_ * E_;
  int mBase = blockIdx.x * 128;
  int m0 = side * B_ + mBase;
  int n0 = blockIdx.y * 64;

  __shared__ bf16 As[128][72];
  __shared__ bf16 Bs[64][72];
  __shared__ float Ps[2][128];   // [wn][row_local] exp partials

  int tid = threadIdx.x;
  int wave = tid >> 6, lane = tid & 63;
  int quad = lane >> 4, l15 = lane & 15;
  int wm = wave >> 1, wn = wave & 1;   // 2x2 wave grid

  f32x4 acc[4][2];
  #pragma unroll
  for (int mt = 0; mt < 4; mt++)
    #pragma unroll
    for (int nt = 0; nt < 2; nt++) acc[mt][nt] = (f32x4){0,0,0,0};

  int arow = tid >> 1, ac0 = (tid & 1) * 32;       // A: 128 rows, 32-elem halves
  int brow = tid >> 2, bc0 = (tid & 3) * 16;       // B: 64 rows, 16 bf16 each
  const bf16* asrc = Abf + (size_t)(m0 + arow) * 640 + ac0;
  const bf16* bsrc = Bm + (size_t)(n0 + brow) * 640 + bc0;

  for (int k0 = 0; k0 < 640; k0 += 64) {
    #pragma unroll
    for (int u = 0; u < 4; u++)
      *(short8*)&As[arow][ac0 + u * 8] = *(const short8*)&asrc[k0 + u * 8];
    *(short8*)&Bs[brow][bc0]     = *(const short8*)&bsrc[k0];
    *(short8*)&Bs[brow][bc0 + 8] = *(const short8*)&bsrc[k0 + 8];
    __syncthreads();
    #pragma unroll
    for (int ks = 0; ks < 2; ks++) {
      int kk = ks * 32 + quad * 8;
      short8 bfr[2];
      #pragma unroll
      for (int nt = 0; nt < 2; nt++)
        bfr[nt] = *(const short8*)&Bs[wn * 32 + nt * 16 + l15][kk];
      #pragma unroll
      for (int mt = 0; mt < 4; mt++) {
        short8 afr = *(const short8*)&As[wm * 64 + mt * 16 + l15][kk];
        #pragma unroll
        for (int nt = 0; nt < 2; nt++)
          acc[mt][nt] = __builtin_amdgcn_mfma_f32_16x16x32_bf16(afr, bfr[nt], acc[mt][nt], 0, 0, 0);
      }
    }
    __syncthreads();
  }

  // epilogue: row_local = wm*64 + mt*16 + quad*4 + r; col = n0 + wn*32 + nt*16 + l15
  float bv[2];
  int ncol[2];
  #pragma unroll
  for (int nt = 0; nt < 2; nt++) {
    ncol[nt] = n0 + wn * 32 + nt * 16 + l15;
    bv[nt] = (ncol[nt] < E_) ? bias[ncol[nt]] : 0.f;
  }
  #pragma unroll
  for (int mt = 0; mt < 4; mt++) {
    #pragma unroll
    for (int r = 0; r < 4; r++) {
      int rloc = wm * 64 + mt * 16 + quad * 4 + r;
      int mrow = mBase + rloc;
      float p = 0.f;
      #pragma unroll
      for (int nt = 0; nt < 2; nt++) {
        if (ncol[nt] < E_) {
          float val = acc[mt][nt][r] + bv[nt];
          C[(size_t)mrow * E_ + ncol[nt]] = val;
          p += __expf(val);
        }
      }
      // reduce 32 cols of this row held by this wave (16 lanes x 2 cols)
      #pragma unroll
      for (int off = 8; off > 0; off >>= 1) p += __shfl_down(p, off, 16);
      if (l15 == 0) Ps[wn][rloc] = p;
    }
  }
  __syncthreads();
  if (tid < 128) {
    float p = Ps[0][tid] + Ps[1][tid];
    pexp[((size_t)side * NBLK_ + blockIdx.y) * 512 + mBase + tid] = p;
  }
}

// ---------------------------------------------------------------- MFMA pred GEMM fallback (fp32 B, ws too small), 128M tile
__global__ __launch_bounds__(256) void k_gemm5(
    const bf16* __restrict__ Abf,
    const float* __restrict__ B0, const float* __restrict__ B1,
    const float* __restrict__ bias0, const float* __restrict__ bias1,
    float* __restrict__ dout, float* __restrict__ pexp)
{
  int side = blockIdx.z;
  const float* Bm = side ? B1 : B0;
  const float* bias = side ? bias1 : bias0;
  float* C = dout + 1 + (size_t)side * B_ * E_;
  int mBase = blockIdx.x * 128;
  int m0 = side * B_ + mBase;
  int n0 = blockIdx.y * 64;

  __shared__ bf16 As[128][72];
  __shared__ bf16 Bs[64][72];
  __shared__ float Ps[2][128];

  int tid = threadIdx.x;
  int wave = tid >> 6, lane = tid & 63;
  int quad = lane >> 4, l15 = lane & 15;
  int wm = wave >> 1, wn = wave & 1;

  f32x4 acc[4][2];
  #pragma unroll
  for (int mt = 0; mt < 4; mt++)
    #pragma unroll
    for (int nt = 0; nt < 2; nt++) acc[mt][nt] = (f32x4){0,0,0,0};

  int arow = tid >> 1, ac0 = (tid & 1) * 32;
  int brow = tid >> 2, bc0 = (tid & 3) * 16;
  const bf16* asrc = Abf + (size_t)(m0 + arow) * 640 + ac0;
  int nsrc = n0 + brow; if (nsrc > E_ - 1) nsrc = E_ - 1;
  const float* bsrc = Bm + (size_t)nsrc * K3 + bc0;

  for (int k0 = 0; k0 < 640; k0 += 64) {
    #pragma unroll
    for (int u = 0; u < 4; u++)
      *(short8*)&As[arow][ac0 + u * 8] = *(const short8*)&asrc[k0 + u * 8];
    {
      int kb = k0 + bc0;
      if (kb + 16 <= K3) {
        #pragma unroll
        for (int u = 0; u < 16; u += 4) {
          float4 v = *(const float4*)&bsrc[k0 + u];
          Bs[brow][bc0 + u + 0] = __float2bfloat16(v.x);
          Bs[brow][bc0 + u + 1] = __float2bfloat16(v.y);
          Bs[brow][bc0 + u + 2] = __float2bfloat16(v.z);
          Bs[brow][bc0 + u + 3] = __float2bfloat16(v.w);
        }
      } else {
        #pragma unroll
        for (int u = 0; u < 16; u++) {
          int k = kb + u;
          float v = (k < K3) ? bsrc[k0 + u] : 0.f;
          Bs[brow][bc0 + u] = __float2bfloat16(v);
        }
      }
    }
    __syncthreads();
    #pragma unroll
    for (int ks = 0; ks < 2; ks++) {
      int kk = ks * 32 + quad * 8;
      short8 bfr[2];
      #pragma unroll
      for (int nt = 0; nt < 2; nt++)
        bfr[nt] = *(const short8*)&Bs[wn * 32 + nt * 16 + l15][kk];
      #pragma unroll
      for (int mt = 0; mt < 4; mt++) {
        short8 afr = *(const short8*)&As[wm * 64 + mt * 16 + l15][kk];
        #pragma unroll
        for (int nt = 0; nt < 2; nt++)
          acc[mt][nt] = __builtin_amdgcn_mfma_f32_16x16x32_bf16(afr, bfr[nt], acc[mt][nt], 0, 0, 0);
      }
    }
    __syncthreads();
  }

  float bv[2];
  int ncol[2];
  #pragma unroll
  for (int nt = 0; nt < 2; nt++) {
    ncol[nt] = n0 + wn * 32 + nt * 16 + l15;
    bv[nt] = (ncol[nt] < E_) ? bias[ncol[nt]] : 0.f;
  }
  #pragma unroll
  for (int mt = 0; mt < 4; mt++) {
    #pragma unroll
    for (int r = 0; r < 4; r++) {
      int rloc = wm * 64 + mt * 16 + quad * 4 + r;
      int mrow = mBase + rloc;
      float p = 0.f;
      #pragma unroll
      for (int nt = 0; nt < 2; nt++) {
        if (ncol[nt] < E_) {
          float val = acc[mt][nt][r] + bv[nt];
          C[(size_t)mrow * E_ + ncol[nt]] = val;
          p += __expf(val);
        }
      }
      #pragma unroll
      for (int off = 8; off > 0; off >>= 1) p += __shfl_down(p, off, 16);
      if (l15 == 0) Ps[wn][rloc] = p;
    }
  }
  __syncthreads();
  if (tid < 128) {
    float p = Ps[0][tid] + Ps[1][tid];
    pexp[((size_t)side * NBLK_ + blockIdx.y) * 512 + mBase + tid] = p;
  }
}

// ---------------------------------------------------------------- final CE loss from pexp partials
__global__ __launch_bounds__(1024) void k_loss3(
    const float* __restrict__ dout_ro, const int* __restrict__ trip,
    const int* __restrict__ idxbuf, const float* __restrict__ pexp,
    float* __restrict__ dout)
{
  int tid = threadIdx.x;            // 0..1023
  int p = tid >> 9, i = tid & 511;
  float s = 0.f;
  for (int nb = 0; nb < NBLK_; nb++)
    s += pexp[((size_t)p * NBLK_ + nb) * 512 + i];
  int bi = idxbuf[(p == 0 ? 1 : 0) * B_ + i];
  int label = (p == 0) ? trip[bi * 3 + 0] : trip[bi * 3 + 2];
  float val = dout_ro[1 + (size_t)p * B_ * E_ + (size_t)i * E_ + label];
  float part = -(val - logf(s)) / (float)B_;
  __shared__ float ps[1024];
  ps[tid] = part; __syncthreads();
  for (int st = 512; st > 0; st >>= 1) {
    if (tid < st) ps[tid] += ps[tid + st];
    __syncthreads();
  }
  if (tid == 0) dout[0] = ps[0];
}

// ----------------------------------------------------------------
extern "C" void kernel_launch(void* const* d_in, const int* in_sizes, int n_in,
                              void* d_out, int out_size, void* d_ws, size_t ws_size,
                              hipStream_t stream)
{
  const int* trip = (const int*)d_in[0];
  const int* s_ne = (const int*)d_in[1];
  const int* s_nl = (const int*)d_in[2];
  const int* s_hl = (const int*)d_in[3];
  const int* o_ne = (const int*)d_in[4];
  const int* o_nl = (const int*)d_in[5];
  const int* o_hl = (const int*)d_in[6];
  const float* ent = (const float*)d_in[7];
  const float* rel = (const float*)d_in[8];
  const float* aw_s = (const float*)d_in[9];
  const float* ab_s = (const float*)d_in[10];
  const float* v_s  = (const float*)d_in[11];
  const float* aw_o = (const float*)d_in[12];
  const float* ab_o = (const float*)d_in[13];
  const float* v_o  = (const float*)d_in[14];
  const float* sub_wih = (const float*)d_in[15];
  const float* sub_whh = (const float*)d_in[16];
  const float* sub_bih = (const float*)d_in[17];
  const float* sub_bhh = (const float*)d_in[18];
  const float* ob_wih  = (const float*)d_in[19];
  const float* ob_whh  = (const float*)d_in[20];
  const float* ob_bih  = (const float*)d_in[21];
  const float* ob_bhh  = (const float*)d_in[22];
  const float* lin_sub_w = (const float*)d_in[23];
  const float* lin_sub_b = (const float*)d_in[24];
  const float* lin_ob_w  = (const float*)d_in[25];
  const float* lin_ob_b  = (const float*)d_in[26];
  float* dout = (float*)d_out;

  // workspace carve — base ~35.2 MB, +25.7 MB for bf16 pred weights if it fits
  char* w = (char*)d_ws;
  bf16* ep2     = (bf16*)w;  w += (size_t)E_ * 400 * 2;           //  8,000,000 B
  bf16* stepb   = (bf16*)w;  w += (size_t)2 * B_ * T_ * 256 * 2;  //  5,242,880 B
  float* biasb  = (float*)w; w += (size_t)2 * B_ * H_ * 4;        //    819,200 B
  bf16* gibase  = (bf16*)w;  w += (size_t)2 * B_ * K3 * 2;        //  1,228,800 B
  float* hfin   = (float*)w; w += (size_t)2 * B_ * H_ * 4;        //    819,200 B
  bf16* xfeat   = (bf16*)w;  w += (size_t)1024 * 640 * 2;         //  1,310,720 B
  bf16* Wn2     = (bf16*)w;  w += (size_t)448 * 256 * 2;          //    229,376 B
  bf16* Wb2     = (bf16*)w;  w += (size_t)2 * 256 * 448 * 2;      //    458,752 B
  bf16* Wg2     = (bf16*)w;  w += (size_t)2 * 640 * 448 * 2;      //  1,146,880 B
  bf16* Wstep   = (bf16*)w;  w += (size_t)2 * 640 * 256 * 2;      //    655,360 B
  bf16* Whh2    = (bf16*)w;  w += (size_t)2 * 608 * 224 * 2;      //    544,768 B
  bf16* giall   = (bf16*)w;  w += (size_t)2 * B_ * T_ * 600 * 2;  // 12,288,000 B
  bf16* Abias   = (bf16*)w;  w += (size_t)2 * B_ * 448 * 2;       //    917,504 B
  bf16* Agi     = (bf16*)w;  w += (size_t)2 * B_ * 448 * 2;       //    917,504 B
  float* pexp   = (float*)w; w += (size_t)2 * NBLK_ * 512 * 4;    //    643,072 B
  int* idxbuf   = (int*)w;   w += 4096;
  bf16* Wlin    = (bf16*)w;  w += (size_t)2 * EP_ * 640 * 2;      // 25,722,880 B
  bool useBf16B = ((size_t)(w - (char*)d_ws) <= ws_size);

  // mega pack (+ vectorized Wlin prepack + argsort)
  k_packall<<<5760 + WLINBLK_ + 2, 256, 0, stream>>>(
      aw_s, aw_o, sub_wih, ob_wih, sub_whh, ob_whh,
      ent, rel, trip, lin_ob_w, lin_sub_w, s_hl, o_hl,
      Wn2, Wb2, Wg2, Wstep, Whh2, Abias, Agi,
      Wlin, useBf16B ? 1 : 0, idxbuf, dout);
  // merged mid GEMMs: ep2 + biasb + gibase (665 blocks)
  k_ggmid<<<665, 256, 0, stream>>>(ent, Wn2, ep2,
                                   Abias, Wb2, ab_s, ab_o, biasb,
                                   Agi, Wg2, sub_bih, ob_bih, gibase);
  // attention (one block per (side,b,t))
  k_attn3<<<dim3(B_ * T_, 2), 256, 0, stream>>>(ent, s_ne, o_ne, s_nl, o_nl,
                                                s_hl, o_hl, v_s, v_o, ep2, biasb, stepb);
  // giall = step @ Wih[:, :200].T  for all (b,t)  (M=5120/side, N=600, K=256pad)
  k_gg<true, false><<<dim3(40, 10, 2), 256, 0, stream>>>(
      (const void*)stepb, Wstep, nullptr, nullptr, (void*)giall,
      B_ * T_, 600, 256, 256, (long)B_ * T_ * 256, 640L * 256, (long)B_ * T_ * 600, 600);
  // GRU (recurrent part only: K=224)
  k_gru4<<<dim3(B_ / 16, 2), 832, 0, stream>>>(giall, gibase, Whh2, sub_bhh, ob_bhh,
                                               s_hl, o_hl, hfin);
  k_feat<<<dim3(B_, 2), 256, 0, stream>>>(ent, rel, trip, idxbuf, hfin, xfeat);
  // pred GEMM with fused exp-partials (no atomics), 128M tile for full occupancy
  if (useBf16B)
    k_gemm7<<<dim3(4, NBLK_, 2), 256, 0, stream>>>(
        xfeat, Wlin, lin_ob_b, lin_sub_b, dout, pexp);
  else
    k_gemm5<<<dim3(4, NBLK_, 2), 256, 0, stream>>>(
        xfeat, lin_ob_w, lin_sub_w, lin_ob_b, lin_sub_b, dout, pexp);
  k_loss3<<<1, 1024, 0, stream>>>(dout, trip, idxbuf, pexp, dout);
}

// Round 14
// 340.530 us; speedup vs baseline: 1.2378x; 1.0073x over previous
//
#include <hip/hip_runtime.h>
#include <hip/hip_bf16.h>
#include <math.h>

typedef __hip_bfloat16 bf16;
typedef __attribute__((ext_vector_type(8))) short short8;
typedef __attribute__((ext_vector_type(4))) float f32x4;

#define B_ 512
#define T_ 10
#define N_ 50
#define H_ 200
#define E_ 10000
#define R_ 200
#define K3 600   // 3*H
#define EP_ 10048  // E_ padded to 64 for guard-free B staging
#define NBLK_ 157  // (E_+63)/64 N-blocks in pred GEMM
#define WLINBLK_ 1570  // 2*EP_*640 / (256*8*4): 4 chunk-groups per thread

__device__ __forceinline__ float b2f(bf16 x){ return __bfloat162float(x); }
__device__ __forceinline__ float u2f(unsigned short u){
  unsigned int x = ((unsigned int)u) << 16;
  return __builtin_bit_cast(float, x);
}
// fast sigmoid/tanh: v_exp_f32 + v_rcp_f32 (~1 ulp), instead of libm calls
__device__ __forceinline__ float fsigm(float x){
  return __builtin_amdgcn_rcpf(1.f + __expf(-x));
}
__device__ __forceinline__ float ftanh(float x){
  x = fminf(15.f, fmaxf(-15.f, x));
  float e = __expf(-2.f * x);
  return (1.f - e) * __builtin_amdgcn_rcpf(1.f + e);
}

// ---------------------------------------------------------------- mega pack (one dispatch)
// sections by blockIdx.x:
//  [0,448)          Wn2[448][256]
//  [448,960)        Wb2[2][256][448]
//  [960,2240)       Wg2[2][640][448]
//  [2240,3520)      Wstep[2][640][256]
//  [3520,4736)      Whh2[2][608][224]
//  [4736,5760)      Abias/Agi
//  [5760,7330)      Wlin bf16 prepack: 4 strided chunk-groups/thread (32 elems),
//                   8x float4 loads + 4x short8 stores in flight per thread
//  [7330,7332)      argsort per side (256 thr, 2 elems each) + perm->dout
__global__ __launch_bounds__(256) void k_packall(
    const float* __restrict__ aw_s, const float* __restrict__ aw_o,
    const float* __restrict__ sub_wih, const float* __restrict__ ob_wih,
    const float* __restrict__ sub_whh, const float* __restrict__ ob_whh,
    const float* __restrict__ ent, const float* __restrict__ rel,
    const int* __restrict__ trip,
    const float* __restrict__ lin_ob_w, const float* __restrict__ lin_sub_w,
    const int* __restrict__ hlen0, const int* __restrict__ hlen1,
    bf16* __restrict__ Wn2, bf16* __restrict__ Wb2, bf16* __restrict__ Wg2,
    bf16* __restrict__ Wstep, bf16* __restrict__ Whh2,
    bf16* __restrict__ Ab, bf16* __restrict__ Ag,
    bf16* __restrict__ Wlin, int useBf16B,
    int* __restrict__ idxbuf, float* __restrict__ dout)
{
  int bid = blockIdx.x;
  int tid = threadIdx.x;
  if (bid < 448) {
    int r = bid;
    const float* Wa = (r < 200) ? aw_s : aw_o;
    int g = (r < 200) ? r : r - 200;
    bf16* out = Wn2 + (size_t)r * 256;
    for (int k = tid; k < 256; k += 256) {
      float v = (r < 400 && k < 200) ? Wa[(size_t)g * K3 + k] : 0.f;
      out[k] = __float2bfloat16(v);
    }
  } else if (bid < 960) {
    int idx = bid - 448;
    int side = idx >> 8, r = idx & 255;
    const float* W = side ? aw_o : aw_s;
    bf16* out = Wb2 + ((size_t)side * 256 + r) * 448;
    for (int k = tid; k < 448; k += 256) {
      float v = (r < 200 && k < 400) ? W[(size_t)r * K3 + 200 + k] : 0.f;
      out[k] = __float2bfloat16(v);
    }
  } else if (bid < 2240) {
    int idx = bid - 960;
    int side = idx / 640, r = idx % 640;
    const float* W = side ? ob_wih : sub_wih;
    bf16* out = Wg2 + ((size_t)side * 640 + r) * 448;
    for (int k = tid; k < 448; k += 256) {
      float v = (r < 600 && k < 400) ? W[(size_t)r * K3 + 200 + k] : 0.f;
      out[k] = __float2bfloat16(v);
    }
  } else if (bid < 3520) {
    int idx = bid - 2240;
    int side = idx / 640, r = idx % 640;
    const float* W = side ? ob_wih : sub_wih;
    bf16* out = Wstep + ((size_t)side * 640 + r) * 256;
    for (int k = tid; k < 256; k += 256) {
      float v = (r < 600 && k < 200) ? W[(size_t)r * K3 + k] : 0.f;
      out[k] = __float2bfloat16(v);
    }
  } else if (bid < 4736) {
    int idx = bid - 3520;
    int side = idx / 608, r = idx % 608;
    const float* W = side ? ob_whh : sub_whh;
    bf16* out = Whh2 + ((size_t)side * 608 + r) * 224;
    for (int k = tid; k < 224; k += 256) {
      float v = (r < 600 && k < 200) ? W[(size_t)r * H_ + k] : 0.f;
      out[k] = __float2bfloat16(v);
    }
  } else if (bid < 5760) {
    int idx = bid - 4736;
    int side = idx >> 9, b = idx & 511;
    int ids = trip[b * 3 + (side ? 2 : 0)];
    int rid = trip[b * 3 + 1];
    size_t ro = ((size_t)side * B_ + b) * 448;
    for (int k = tid; k < 448; k += 256) {
      float vb = 0.f, vg = 0.f;
      if (k < 200) { float e = ent[(size_t)ids * H_ + k]; vb = e; vg = e; }
      else if (k < 400) {
        vb = ent[(size_t)rid * H_ + (k - 200)];
        vg = rel[(size_t)rid * H_ + (k - 200)];
      }
      Ab[ro + k] = __float2bfloat16(vb);
      Ag[ro + k] = __float2bfloat16(vg);
    }
  } else if (bid < 5760 + WLINBLK_) {
    if (!useBf16B) return;
    // vectorized prepack, 4 strided chunk-groups per thread (32 bf16 total).
    // 600 % 8 == 0 so each 8-chunk is fully in-bounds or fully pad.
    size_t chunk0 = (size_t)(bid - 5760) * 256 + tid;
    #pragma unroll
    for (int g = 0; g < 4; g++) {
      size_t base = (chunk0 + (size_t)g * WLINBLK_ * 256) * 8;  // elem offset in [2][EP_][640]
      int side = (int)(base / ((size_t)EP_ * 640));
      size_t rem = base - (size_t)side * EP_ * 640;
      int row = (int)(rem / 640);
      int k = (int)(rem % 640);
      const float* W = side ? lin_sub_w : lin_ob_w;
      short8 outv = (short8)0;
      if (row < E_ && k < K3) {
        const float* src = W + (size_t)row * K3 + k;
        float4 v0 = *(const float4*)&src[0];
        float4 v1 = *(const float4*)&src[4];
        bf16 tmp[8];
        tmp[0] = __float2bfloat16(v0.x); tmp[1] = __float2bfloat16(v0.y);
        tmp[2] = __float2bfloat16(v0.z); tmp[3] = __float2bfloat16(v0.w);
        tmp[4] = __float2bfloat16(v1.x); tmp[5] = __float2bfloat16(v1.y);
        tmp[6] = __float2bfloat16(v1.z); tmp[7] = __float2bfloat16(v1.w);
        outv = *(short8*)tmp;
      }
      *(short8*)&Wlin[base] = outv;
    }
  } else {
    int side = bid - (5760 + WLINBLK_);
    const int* len = side ? hlen1 : hlen0;
    __shared__ int lens[B_];
    __shared__ int perm[B_];
    lens[tid] = len[tid];
    lens[tid + 256] = len[tid + 256];
    __syncthreads();
    #pragma unroll
    for (int e = 0; e < 2; e++) {
      int i = tid + e * 256;
      int L = lens[i];
      int rank = 0;
      for (int j = 0; j < B_; j++) {
        int Lj = lens[j];
        rank += (Lj > L) || (Lj == L && j < i);
      }
      perm[rank] = i;
    }
    __syncthreads();
    size_t base = 1 + (size_t)2 * B_ * E_ + (side ? 0 : B_);
    idxbuf[side * B_ + tid] = perm[tid];
    idxbuf[side * B_ + tid + 256] = perm[tid + 256];
    dout[base + tid] = (float)perm[tid];
    dout[base + tid + 256] = (float)perm[tid + 256];
  }
}

// ---------------------------------------------------------------- generic MFMA GEMM body
// C[m][n] = sum_k A[m][k]*B[n][k] (+ bias[n]); tile M=128, N=64, BK=64.
template<bool OUTBF, bool AF32>
__device__ __forceinline__ void ggbody(
    bf16 (*As)[72], bf16 (*Bs)[72],
    const void* __restrict__ Aptr, const bf16* __restrict__ Bptr,
    const float* __restrict__ bias0, const float* __restrict__ bias1,
    void* __restrict__ Cptr,
    int M, int Nout, int KP, int Acols,
    long Astride, long Bstride, long Cstride, int Nstride,
    int side, int m0, int n0)
{
  int tid = threadIdx.x;
  int wave = tid >> 6, lane = tid & 63;
  int quad = lane >> 4, l15 = lane & 15;

  f32x4 acc[8];
  #pragma unroll
  for (int mt = 0; mt < 8; mt++) acc[mt] = (f32x4){0,0,0,0};

  int arow = tid >> 1, ac0 = (tid & 1) * 32;
  int gr = m0 + arow; if (gr > M - 1) gr = M - 1;
  int brow = tid >> 2, bc0 = (tid & 3) * 16;

  for (int k0 = 0; k0 < KP; k0 += 64) {
    if (AF32) {
      const float* src = (const float*)Aptr + (size_t)gr * Acols;
      #pragma unroll
      for (int u = 0; u < 8; u++) {
        int kk = k0 + ac0 + u * 4;
        float4 v;
        if (kk + 4 <= Acols) v = *(const float4*)&src[kk];
        else {
          v.x = (kk + 0 < Acols) ? src[kk + 0] : 0.f;
          v.y = (kk + 1 < Acols) ? src[kk + 1] : 0.f;
          v.z = (kk + 2 < Acols) ? src[kk + 2] : 0.f;
          v.w = (kk + 3 < Acols) ? src[kk + 3] : 0.f;
        }
        As[arow][ac0 + u * 4 + 0] = __float2bfloat16(v.x);
        As[arow][ac0 + u * 4 + 1] = __float2bfloat16(v.y);
        As[arow][ac0 + u * 4 + 2] = __float2bfloat16(v.z);
        As[arow][ac0 + u * 4 + 3] = __float2bfloat16(v.w);
      }
    } else {
      const bf16* src = (const bf16*)Aptr + (size_t)side * Astride + (size_t)gr * KP + k0 + ac0;
      #pragma unroll
      for (int u = 0; u < 4; u++)
        *(short8*)&As[arow][ac0 + u * 8] = *(const short8*)&src[u * 8];
    }
    {
      const bf16* src = Bptr + (size_t)side * Bstride + (size_t)(n0 + brow) * KP + k0 + bc0;
      *(short8*)&Bs[brow][bc0]     = *(const short8*)&src[0];
      *(short8*)&Bs[brow][bc0 + 8] = *(const short8*)&src[8];
    }
    __syncthreads();
    #pragma unroll
    for (int ks = 0; ks < 2; ks++) {
      int kk = ks * 32 + quad * 8;
      short8 bfr = *(const short8*)&Bs[wave * 16 + l15][kk];
      #pragma unroll
      for (int mt = 0; mt < 8; mt++) {
        short8 afr = *(const short8*)&As[mt * 16 + l15][kk];
        acc[mt] = __builtin_amdgcn_mfma_f32_16x16x32_bf16(afr, bfr, acc[mt], 0, 0, 0);
      }
    }
    __syncthreads();
  }

  int n = n0 + wave * 16 + l15;
  if (n < Nout) {
    float bv = bias0 ? (side ? bias1[n] : bias0[n]) : 0.f;
    #pragma unroll
    for (int mt = 0; mt < 8; mt++) {
      #pragma unroll
      for (int r = 0; r < 4; r++) {
        int m = m0 + mt * 16 + quad * 4 + r;
        if (m < M) {
          float val = acc[mt][r] + bv;
          if (OUTBF)
            ((bf16*)Cptr)[(size_t)side * Cstride + (size_t)m * Nstride + n] = __float2bfloat16(val);
          else
            ((float*)Cptr)[(size_t)side * Cstride + (size_t)m * Nstride + n] = val;
        }
      }
    }
  }
}

// standalone k_gg (used for giall)
template<bool OUTBF, bool AF32>
__global__ __launch_bounds__(256) void k_gg(
    const void* __restrict__ Aptr, const bf16* __restrict__ Bptr,
    const float* __restrict__ bias0, const float* __restrict__ bias1,
    void* __restrict__ Cptr,
    int M, int Nout, int KP, int Acols,
    long Astride, long Bstride, long Cstride, int Nstride)
{
  __shared__ bf16 As[128][72];
  __shared__ bf16 Bs[64][72];
  ggbody<OUTBF, AF32>(As, Bs, Aptr, Bptr, bias0, bias1, Cptr,
                      M, Nout, KP, Acols, Astride, Bstride, Cstride, Nstride,
                      blockIdx.z, blockIdx.x * 128, blockIdx.y * 64);
}

// ---------------------------------------------------------------- merged mid GEMMs: ep2 + biasb + gibase
// blocks: [0,553)=ep2 (79x7), [553,585)=biasb (4x4x2), [585,665)=gibase (4x10x2)
__global__ __launch_bounds__(256) void k_ggmid(
    const float* __restrict__ ent, const bf16* __restrict__ Wn2, bf16* __restrict__ ep2,
    const bf16* __restrict__ Abias, const bf16* __restrict__ Wb2,
    const float* __restrict__ ab_s, const float* __restrict__ ab_o, float* __restrict__ biasb,
    const bf16* __restrict__ Agi, const bf16* __restrict__ Wg2,
    const float* __restrict__ sub_bih, const float* __restrict__ ob_bih, bf16* __restrict__ gibase)
{
  __shared__ bf16 As[128][72];
  __shared__ bf16 Bs[64][72];
  int bid = blockIdx.x;
  if (bid < 553) {
    int bx = bid % 79, by = bid / 79;
    ggbody<true, true>(As, Bs, (const void*)ent, Wn2, nullptr, nullptr, (void*)ep2,
                       E_, 400, 256, 200, 0L, 0L, 0L, 400, 0, bx * 128, by * 64);
  } else if (bid < 585) {
    int idx = bid - 553;
    int side = idx >> 4; idx &= 15;
    int bx = idx & 3, by = idx >> 2;
    ggbody<false, false>(As, Bs, (const void*)Abias, Wb2, ab_s, ab_o, (void*)biasb,
                         B_, 200, 448, 448, (long)B_ * 448, 256L * 448, (long)B_ * 200, 200,
                         side, bx * 128, by * 64);
  } else {
    int idx = bid - 585;
    int side = idx / 40; idx %= 40;
    int bx = idx & 3, by = idx >> 2;
    ggbody<true, false>(As, Bs, (const void*)Agi, Wg2, sub_bih, ob_bih, (void*)gibase,
                        B_, 600, 448, 448, (long)B_ * 448, 640L * 448, (long)B_ * 600, 600,
                        side, bx * 128, by * 64);
  }
}

// ---------------------------------------------------------------- attention v3: one block per (side,b,t)
__global__ __launch_bounds__(256) void k_attn3(
    const float* __restrict__ ent,
    const int* __restrict__ neigh0, const int* __restrict__ neigh1,
    const int* __restrict__ nlen0, const int* __restrict__ nlen1,
    const int* __restrict__ hlen0, const int* __restrict__ hlen1,
    const float* __restrict__ v0, const float* __restrict__ v1,
    const bf16* __restrict__ ep2, const float* __restrict__ biasb,
    bf16* __restrict__ stepb)
{
  int side = blockIdx.y;
  int bt = blockIdx.x;
  int b = bt / T_, t = bt % T_;
  int hl = (side ? hlen1 : hlen0)[b];
  bf16* srow = stepb + (((size_t)side * B_ + b) * T_ + t) * 256;
  int tid = threadIdx.x;
  if (t >= hl) {     // masked timestep: zero row (uniform branch)
    srow[tid] = __float2bfloat16(0.f);
    return;
  }
  const int* neigh = side ? neigh1 : neigh0;
  const float* v = side ? v1 : v0;
  const float* brow = biasb + ((size_t)side * B_ + b) * H_;
  int nl = (side ? nlen1 : nlen0)[b * T_ + t];

  __shared__ float bsh[H_], vsh[H_], lg[64], wsh[64];
  __shared__ int nb[N_];
  if (tid < H_) { bsh[tid] = brow[tid]; vsh[tid] = v[tid]; }
  if (tid < N_) nb[tid] = neigh[((size_t)b * T_ + t) * N_ + tid];
  __syncthreads();

  int grp = tid >> 4;        // 0..15
  int l16 = tid & 15;

  float bs[13], vs[13];
  #pragma unroll
  for (int i = 0; i < 13; i++) {
    int g = l16 + i * 16;
    bool ok = (g < H_);
    bs[i] = ok ? bsh[g] : 0.f;
    vs[i] = ok ? vsh[g] : 0.f;
  }

  for (int n = grp; n < nl; n += 16) {
    const bf16* er = ep2 + (size_t)nb[n] * 400 + side * 200;
    float acc = 0.f;
    #pragma unroll
    for (int i = 0; i < 13; i++) {
      int g = l16 + i * 16;
      float e = (g < H_) ? b2f(er[g]) : 0.f;
      acc += ftanh(e + bs[i]) * vs[i];
    }
    #pragma unroll
    for (int off = 8; off > 0; off >>= 1) acc += __shfl_down(acc, off, 16);
    if (l16 == 0) lg[n] = acc;
  }
  __syncthreads();

  if (tid < 64) {
    float x = (tid < nl) ? lg[tid] : -1e30f;
    float m = x;
    #pragma unroll
    for (int off = 32; off > 0; off >>= 1) m = fmaxf(m, __shfl_down(m, off));
    m = __shfl(m, 0);
    float e = (tid < nl) ? __expf(x - m) : 0.f;
    float s = e;
    #pragma unroll
    for (int off = 32; off > 0; off >>= 1) s += __shfl_down(s, off);
    s = __shfl(s, 0);
    if (tid < N_) wsh[tid] = e / s;
  }
  __syncthreads();

  int h = tid;
  if (h < H_) {
    float a0 = 0.f, a1 = 0.f, a2 = 0.f, a3 = 0.f;
    int n = 0;
    for (; n + 4 <= nl; n += 4) {
      a0 += wsh[n + 0] * ent[(size_t)nb[n + 0] * H_ + h];
      a1 += wsh[n + 1] * ent[(size_t)nb[n + 1] * H_ + h];
      a2 += wsh[n + 2] * ent[(size_t)nb[n + 2] * H_ + h];
      a3 += wsh[n + 3] * ent[(size_t)nb[n + 3] * H_ + h];
    }
    for (; n < nl; n++) a0 += wsh[n] * ent[(size_t)nb[n] * H_ + h];
    srow[h] = __float2bfloat16((a0 + a1) + (a2 + a3));
  } else {
    srow[h] = __float2bfloat16(0.f);   // pad cols 200..255
  }
}

// ---------------------------------------------------------------- MFMA GRU v4
__global__ __launch_bounds__(832) void k_gru4(
    const bf16* __restrict__ giall, const bf16* __restrict__ gibase,
    const bf16* __restrict__ Whh2,
    const float* __restrict__ bhh0, const float* __restrict__ bhh1,
    const int* __restrict__ len0, const int* __restrict__ len1,
    float* __restrict__ hfin)
{
  int side = blockIdx.y;
  int b0 = blockIdx.x * 16;
  const bf16* gia = giall + ((size_t)side * B_ * T_ + (size_t)b0 * T_) * 600;
  const bf16* gib = gibase + ((size_t)side * B_ + b0) * K3;
  const bf16* Wh  = Whh2 + (size_t)side * 608 * 224;
  const float* bhh = side ? bhh1 : bhh0;
  const int* len = side ? len1 : len0;

  __shared__ __align__(16) bf16 Hs[2][16][232];

  int tid = threadIdx.x;
  int wave = tid >> 6, lane = tid & 63;
  int quad = lane >> 4, l15 = lane & 15;

  for (int i = tid; i < 2 * 16 * 232 / 8; i += 832) ((short8*)&Hs[0][0][0])[i] = (short8)0;

  int j0 = wave * 16;
  int j = j0 + l15;
  bool jok = (j < H_);
  float bhr = 0.f, bhz = 0.f, bhn = 0.f;
  float gr[4] = {}, gz[4] = {}, gn[4] = {};
  int lens4[4];
  #pragma unroll
  for (int r = 0; r < 4; r++) lens4[r] = len[b0 + quad * 4 + r];
  if (jok) {
    bhr = bhh[j]; bhz = bhh[H_ + j]; bhn = bhh[2 * H_ + j];
    #pragma unroll
    for (int r = 0; r < 4; r++) {
      const bf16* g = gib + (size_t)(quad * 4 + r) * K3;
      gr[r] = b2f(g[j]); gz[r] = b2f(g[H_ + j]); gn[r] = b2f(g[2 * H_ + j]);
    }
  }
  const bf16* wr = Wh + (size_t)j * 224;
  const bf16* wz = Wh + (size_t)(200 + j) * 224;
  const bf16* wn = Wh + (size_t)(400 + j) * 224;
  __syncthreads();

  int cur = 0;
  for (int t = 0; t < T_; t++) {
    unsigned short guR[4], guZ[4], guN[4];
    if (jok) {
      #pragma unroll
      for (int r = 0; r < 4; r++) {
        const unsigned short* g =
            (const unsigned short*)(gia + ((size_t)(quad * 4 + r) * T_ + t) * 600);
        guR[r] = g[j]; guZ[r] = g[200 + j]; guN[r] = g[400 + j];
      }
    }
    f32x4 ar = {0,0,0,0}, az = {0,0,0,0}, anh = {0,0,0,0};
    #pragma unroll
    for (int ks = 0; ks < 7; ks++) {
      int kk = ks * 32 + quad * 8;
      short8 a0 = *(const short8*)&Hs[cur][l15][kk];
      short8 br = *(const short8*)&wr[kk];
      short8 bz = *(const short8*)&wz[kk];
      short8 bn = *(const short8*)&wn[kk];
      ar  = __builtin_amdgcn_mfma_f32_16x16x32_bf16(a0, br, ar, 0, 0, 0);
      az  = __builtin_amdgcn_mfma_f32_16x16x32_bf16(a0, bz, az, 0, 0, 0);
      anh = __builtin_amdgcn_mfma_f32_16x16x32_bf16(a0, bn, anh, 0, 0, 0);
    }
    if (jok) {
      #pragma unroll
      for (int r = 0; r < 4; r++) {
        int row = quad * 4 + r;
        float rz  = ar[r] + u2f(guR[r]) + gr[r] + bhr;
        float zz  = az[r] + u2f(guZ[r]) + gz[r] + bhz;
        float inn = u2f(guN[r]) + gn[r];
        float hn  = anh[r] + bhn;
        float rg = fsigm(rz);
        float zg = fsigm(zz);
        float ng = ftanh(inn + rg * hn);
        float hold = b2f(Hs[cur][row][j]);
        float hnew = (1.f - zg) * ng + zg * hold;
        Hs[cur ^ 1][row][j] = __float2bfloat16((t < lens4[r]) ? hnew : hold);
      }
    }
    __syncthreads();
    cur ^= 1;
  }
  for (int i = tid; i < 16 * H_; i += 832) {
    int row = i / H_, jj = i % H_;
    hfin[((size_t)side * B_ + b0 + row) * H_ + jj] = b2f(Hs[cur][row][jj]);
  }
}

// ---------------------------------------------------------------- assemble pred-GEMM input rows (bf16, K padded to 640)
__global__ __launch_bounds__(256) void k_feat(
    const float* __restrict__ ent, const float* __restrict__ rel, const int* __restrict__ trip,
    const int* __restrict__ idxbuf, const float* __restrict__ hfin,
    bf16* __restrict__ xfeat)
{
  int i = blockIdx.x, p = blockIdx.y;
  int bi = idxbuf[(p == 0 ? 1 : 0) * B_ + i];
  int ent_id = (p == 0) ? trip[bi * 3 + 2] : trip[bi * 3 + 0];
  int rid = trip[bi * 3 + 1];
  const float* hsrc = hfin + (size_t)(p == 0 ? 1 : 0) * B_ * H_;
  bf16* x = xfeat + ((size_t)p * B_ + i) * 640;
  int h = threadIdx.x;
  if (h < H_) {
    x[h]          = __float2bfloat16(ent[(size_t)ent_id * H_ + h]);
    x[H_ + h]     = __float2bfloat16(hsrc[(size_t)bi * H_ + h]);
    x[2 * H_ + h] = __float2bfloat16(rel[(size_t)rid * H_ + h]);
  }
  if (h < 40) x[600 + h] = __float2bfloat16(0.f);
}

// ---------------------------------------------------------------- MFMA pred GEMM v10 (bf16 B + fused sumexp, 128M tile)
// tile 128M x 64N x 64K, 256 threads / 4 waves (2Mx2N), wave = 64Mx32N -> acc[4][2].
__global__ __launch_bounds__(256) void k_gemm7(
    const bf16* __restrict__ Abf, const bf16* __restrict__ Wlin,
    const float* __restrict__ bias0, const float* __restrict__ bias1,
    float* __restrict__ dout, float* __restrict__ pexp)
{
  int side = blockIdx.z;
  const bf16* Bm = Wlin + (size_t)side * EP_ * 640;
  const float* bias = side ? bias1 : bias0;
  float* C = dout + 1 + (size_t)side * B_ * E_;
  int mBase = blockIdx.x * 128;
  int m0 = side * B_ + mBase;
  int n0 = blockIdx.y * 64;

  __shared__ bf16 As[128][72];
  __shared__ bf16 Bs[64][72];
  __shared__ float Ps[2][128];   // [wn][row_local] exp partials

  int tid = threadIdx.x;
  int wave = tid >> 6, lane = tid & 63;
  int quad = lane >> 4, l15 = lane & 15;
  int wm = wave >> 1, wn = wave & 1;   // 2x2 wave grid

  f32x4 acc[4][2];
  #pragma unroll
  for (int mt = 0; mt < 4; mt++)
    #pragma unroll
    for (int nt = 0; nt < 2; nt++) acc[mt][nt] = (f32x4){0,0,0,0};

  int arow = tid >> 1, ac0 = (tid & 1) * 32;       // A: 128 rows, 32-elem halves
  int brow = tid >> 2, bc0 = (tid & 3) * 16;       // B: 64 rows, 16 bf16 each
  const bf16* asrc = Abf + (size_t)(m0 + arow) * 640 + ac0;
  const bf16* bsrc = Bm + (size_t)(n0 + brow) * 640 + bc0;

  for (int k0 = 0; k0 < 640; k0 += 64) {
    #pragma unroll
    for (int u = 0; u < 4; u++)
      *(short8*)&As[arow][ac0 + u * 8] = *(const short8*)&asrc[k0 + u * 8];
    *(short8*)&Bs[brow][bc0]     = *(const short8*)&bsrc[k0];
    *(short8*)&Bs[brow][bc0 + 8] = *(const short8*)&bsrc[k0 + 8];
    __syncthreads();
    #pragma unroll
    for (int ks = 0; ks < 2; ks++) {
      int kk = ks * 32 + quad * 8;
      short8 bfr[2];
      #pragma unroll
      for (int nt = 0; nt < 2; nt++)
        bfr[nt] = *(const short8*)&Bs[wn * 32 + nt * 16 + l15][kk];
      #pragma unroll
      for (int mt = 0; mt < 4; mt++) {
        short8 afr = *(const short8*)&As[wm * 64 + mt * 16 + l15][kk];
        #pragma unroll
        for (int nt = 0; nt < 2; nt++)
          acc[mt][nt] = __builtin_amdgcn_mfma_f32_16x16x32_bf16(afr, bfr[nt], acc[mt][nt], 0, 0, 0);
      }
    }
    __syncthreads();
  }

  // epilogue: row_local = wm*64 + mt*16 + quad*4 + r; col = n0 + wn*32 + nt*16 + l15
  float bv[2];
  int ncol[2];
  #pragma unroll
  for (int nt = 0; nt < 2; nt++) {
    ncol[nt] = n0 + wn * 32 + nt * 16 + l15;
    bv[nt] = (ncol[nt] < E_) ? bias[ncol[nt]] : 0.f;
  }
  #pragma unroll
  for (int mt = 0; mt < 4; mt++) {
    #pragma unroll
    for (int r = 0; r < 4; r++) {
      int rloc = wm * 64 + mt * 16 + quad * 4 + r;
      int mrow = mBase + rloc;
      float p = 0.f;
      #pragma unroll
      for (int nt = 0; nt < 2; nt++) {
        if (ncol[nt] < E_) {
          float val = acc[mt][nt][r] + bv[nt];
          C[(size_t)mrow * E_ + ncol[nt]] = val;
          p += __expf(val);
        }
      }
      // reduce 32 cols of this row held by this wave (16 lanes x 2 cols)
      #pragma unroll
      for (int off = 8; off > 0; off >>= 1) p += __shfl_down(p, off, 16);
      if (l15 == 0) Ps[wn][rloc] = p;
    }
  }
  __syncthreads();
  if (tid < 128) {
    float p = Ps[0][tid] + Ps[1][tid];
    pexp[((size_t)side * NBLK_ + blockIdx.y) * 512 + mBase + tid] = p;
  }
}

// ---------------------------------------------------------------- MFMA pred GEMM fallback (fp32 B, ws too small), 128M tile
__global__ __launch_bounds__(256) void k_gemm5(
    const bf16* __restrict__ Abf,
    const float* __restrict__ B0, const float* __restrict__ B1,
    const float* __restrict__ bias0, const float* __restrict__ bias1,
    float* __restrict__ dout, float* __restrict__ pexp)
{
  int side = blockIdx.z;
  const float* Bm = side ? B1 : B0;
  const float* bias = side ? bias1 : bias0;
  float* C = dout + 1 + (size_t)side * B_ * E_;
  int mBase = blockIdx.x * 128;
  int m0 = side * B_ + mBase;
  int n0 = blockIdx.y * 64;

  __shared__ bf16 As[128][72];
  __shared__ bf16 Bs[64][72];
  __shared__ float Ps[2][128];

  int tid = threadIdx.x;
  int wave = tid >> 6, lane = tid & 63;
  int quad = lane >> 4, l15 = lane & 15;
  int wm = wave >> 1, wn = wave & 1;

  f32x4 acc[4][2];
  #pragma unroll
  for (int mt = 0; mt < 4; mt++)
    #pragma unroll
    for (int nt = 0; nt < 2; nt++) acc[mt][nt] = (f32x4){0,0,0,0};

  int arow = tid >> 1, ac0 = (tid & 1) * 32;
  int brow = tid >> 2, bc0 = (tid & 3) * 16;
  const bf16* asrc = Abf + (size_t)(m0 + arow) * 640 + ac0;
  int nsrc = n0 + brow; if (nsrc > E_ - 1) nsrc = E_ - 1;
  const float* bsrc = Bm + (size_t)nsrc * K3 + bc0;

  for (int k0 = 0; k0 < 640; k0 += 64) {
    #pragma unroll
    for (int u = 0; u < 4; u++)
      *(short8*)&As[arow][ac0 + u * 8] = *(const short8*)&asrc[k0 + u * 8];
    {
      int kb = k0 + bc0;
      if (kb + 16 <= K3) {
        #pragma unroll
        for (int u = 0; u < 16; u += 4) {
          float4 v = *(const float4*)&bsrc[k0 + u];
          Bs[brow][bc0 + u + 0] = __float2bfloat16(v.x);
          Bs[brow][bc0 + u + 1] = __float2bfloat16(v.y);
          Bs[brow][bc0 + u + 2] = __float2bfloat16(v.z);
          Bs[brow][bc0 + u + 3] = __float2bfloat16(v.w);
        }
      } else {
        #pragma unroll
        for (int u = 0; u < 16; u++) {
          int k = kb + u;
          float v = (k < K3) ? bsrc[k0 + u] : 0.f;
          Bs[brow][bc0 + u] = __float2bfloat16(v);
        }
      }
    }
    __syncthreads();
    #pragma unroll
    for (int ks = 0; ks < 2; ks++) {
      int kk = ks * 32 + quad * 8;
      short8 bfr[2];
      #pragma unroll
      for (int nt = 0; nt < 2; nt++)
        bfr[nt] = *(const short8*)&Bs[wn * 32 + nt * 16 + l15][kk];
      #pragma unroll
      for (int mt = 0; mt < 4; mt++) {
        short8 afr = *(const short8*)&As[wm * 64 + mt * 16 + l15][kk];
        #pragma unroll
        for (int nt = 0; nt < 2; nt++)
          acc[mt][nt] = __builtin_amdgcn_mfma_f32_16x16x32_bf16(afr, bfr[nt], acc[mt][nt], 0, 0, 0);
      }
    }
    __syncthreads();
  }

  float bv[2];
  int ncol[2];
  #pragma unroll
  for (int nt = 0; nt < 2; nt++) {
    ncol[nt] = n0 + wn * 32 + nt * 16 + l15;
    bv[nt] = (ncol[nt] < E_) ? bias[ncol[nt]] : 0.f;
  }
  #pragma unroll
  for (int mt = 0; mt < 4; mt++) {
    #pragma unroll
    for (int r = 0; r < 4; r++) {
      int rloc = wm * 64 + mt * 16 + quad * 4 + r;
      int mrow = mBase + rloc;
      float p = 0.f;
      #pragma unroll
      for (int nt = 0; nt < 2; nt++) {
        if (ncol[nt] < E_) {
          float val = acc[mt][nt][r] + bv[nt];
          C[(size_t)mrow * E_ + ncol[nt]] = val;
          p += __expf(val);
        }
      }
      #pragma unroll
      for (int off = 8; off > 0; off >>= 1) p += __shfl_down(p, off, 16);
      if (l15 == 0) Ps[wn][rloc] = p;
    }
  }
  __syncthreads();
  if (tid < 128) {
    float p = Ps[0][tid] + Ps[1][tid];
    pexp[((size_t)side * NBLK_ + blockIdx.y) * 512 + mBase + tid] = p;
  }
}

// ---------------------------------------------------------------- final CE loss from pexp partials
__global__ __launch_bounds__(1024) void k_loss3(
    const float* __restrict__ dout_ro, const int* __restrict__ trip,
    const int* __restrict__ idxbuf, const float* __restrict__ pexp,
    float* __restrict__ dout)
{
  int tid = threadIdx.x;            // 0..1023
  int p = tid >> 9, i = tid & 511;
  float s = 0.f;
  for (int nb = 0; nb < NBLK_; nb++)
    s += pexp[((size_t)p * NBLK_ + nb) * 512 + i];
  int bi = idxbuf[(p == 0 ? 1 : 0) * B_ + i];
  int label = (p == 0) ? trip[bi * 3 + 0] : trip[bi * 3 + 2];
  float val = dout_ro[1 + (size_t)p * B_ * E_ + (size_t)i * E_ + label];
  float part = -(val - logf(s)) / (float)B_;
  __shared__ float ps[1024];
  ps[tid] = part; __syncthreads();
  for (int st = 512; st > 0; st >>= 1) {
    if (tid < st) ps[tid] += ps[tid + st];
    __syncthreads();
  }
  if (tid == 0) dout[0] = ps[0];
}

// ----------------------------------------------------------------
extern "C" void kernel_launch(void* const* d_in, const int* in_sizes, int n_in,
                              void* d_out, int out_size, void* d_ws, size_t ws_size,
                              hipStream_t stream)
{
  const int* trip = (const int*)d_in[0];
  const int* s_ne = (const int*)d_in[1];
  const int* s_nl = (const int*)d_in[2];
  const int* s_hl = (const int*)d_in[3];
  const int* o_ne = (const int*)d_in[4];
  const int* o_nl = (const int*)d_in[5];
  const int* o_hl = (const int*)d_in[6];
  const float* ent = (const float*)d_in[7];
  const float* rel = (const float*)d_in[8];
  const float* aw_s = (const float*)d_in[9];
  const float* ab_s = (const float*)d_in[10];
  const float* v_s  = (const float*)d_in[11];
  const float* aw_o = (const float*)d_in[12];
  const float* ab_o = (const float*)d_in[13];
  const float* v_o  = (const float*)d_in[14];
  const float* sub_wih = (const float*)d_in[15];
  const float* sub_whh = (const float*)d_in[16];
  const float* sub_bih = (const float*)d_in[17];
  const float* sub_bhh = (const float*)d_in[18];
  const float* ob_wih  = (const float*)d_in[19];
  const float* ob_whh  = (const float*)d_in[20];
  const float* ob_bih  = (const float*)d_in[21];
  const float* ob_bhh  = (const float*)d_in[22];
  const float* lin_sub_w = (const float*)d_in[23];
  const float* lin_sub_b = (const float*)d_in[24];
  const float* lin_ob_w  = (const float*)d_in[25];
  const float* lin_ob_b  = (const float*)d_in[26];
  float* dout = (float*)d_out;

  // workspace carve — base ~35.2 MB, +25.7 MB for bf16 pred weights if it fits
  char* w = (char*)d_ws;
  bf16* ep2     = (bf16*)w;  w += (size_t)E_ * 400 * 2;           //  8,000,000 B
  bf16* stepb   = (bf16*)w;  w += (size_t)2 * B_ * T_ * 256 * 2;  //  5,242,880 B
  float* biasb  = (float*)w; w += (size_t)2 * B_ * H_ * 4;        //    819,200 B
  bf16* gibase  = (bf16*)w;  w += (size_t)2 * B_ * K3 * 2;        //  1,228,800 B
  float* hfin   = (float*)w; w += (size_t)2 * B_ * H_ * 4;        //    819,200 B
  bf16* xfeat   = (bf16*)w;  w += (size_t)1024 * 640 * 2;         //  1,310,720 B
  bf16* Wn2     = (bf16*)w;  w += (size_t)448 * 256 * 2;          //    229,376 B
  bf16* Wb2     = (bf16*)w;  w += (size_t)2 * 256 * 448 * 2;      //    458,752 B
  bf16* Wg2     = (bf16*)w;  w += (size_t)2 * 640 * 448 * 2;      //  1,146,880 B
  bf16* Wstep   = (bf16*)w;  w += (size_t)2 * 640 * 256 * 2;      //    655,360 B
  bf16* Whh2    = (bf16*)w;  w += (size_t)2 * 608 * 224 * 2;      //    544,768 B
  bf16* giall   = (bf16*)w;  w += (size_t)2 * B_ * T_ * 600 * 2;  // 12,288,000 B
  bf16* Abias   = (bf16*)w;  w += (size_t)2 * B_ * 448 * 2;       //    917,504 B
  bf16* Agi     = (bf16*)w;  w += (size_t)2 * B_ * 448 * 2;       //    917,504 B
  float* pexp   = (float*)w; w += (size_t)2 * NBLK_ * 512 * 4;    //    643,072 B
  int* idxbuf   = (int*)w;   w += 4096;
  bf16* Wlin    = (bf16*)w;  w += (size_t)2 * EP_ * 640 * 2;      // 25,722,880 B
  bool useBf16B = ((size_t)(w - (char*)d_ws) <= ws_size);

  // mega pack (+ vectorized Wlin prepack + argsort)
  k_packall<<<5760 + WLINBLK_ + 2, 256, 0, stream>>>(
      aw_s, aw_o, sub_wih, ob_wih, sub_whh, ob_whh,
      ent, rel, trip, lin_ob_w, lin_sub_w, s_hl, o_hl,
      Wn2, Wb2, Wg2, Wstep, Whh2, Abias, Agi,
      Wlin, useBf16B ? 1 : 0, idxbuf, dout);
  // merged mid GEMMs: ep2 + biasb + gibase (665 blocks)
  k_ggmid<<<665, 256, 0, stream>>>(ent, Wn2, ep2,
                                   Abias, Wb2, ab_s, ab_o, biasb,
                                   Agi, Wg2, sub_bih, ob_bih, gibase);
  // attention (one block per (side,b,t))
  k_attn3<<<dim3(B_ * T_, 2), 256, 0, stream>>>(ent, s_ne, o_ne, s_nl, o_nl,
                                                s_hl, o_hl, v_s, v_o, ep2, biasb, stepb);
  // giall = step @ Wih[:, :200].T  for all (b,t)  (M=5120/side, N=600, K=256pad)
  k_gg<true, false><<<dim3(40, 10, 2), 256, 0, stream>>>(
      (const void*)stepb, Wstep, nullptr, nullptr, (void*)giall,
      B_ * T_, 600, 256, 256, (long)B_ * T_ * 256, 640L * 256, (long)B_ * T_ * 600, 600);
  // GRU (recurrent part only: K=224)
  k_gru4<<<dim3(B_ / 16, 2), 832, 0, stream>>>(giall, gibase, Whh2, sub_bhh, ob_bhh,
                                               s_hl, o_hl, hfin);
  k_feat<<<dim3(B_, 2), 256, 0, stream>>>(ent, rel, trip, idxbuf, hfin, xfeat);
  // pred GEMM with fused exp-partials (no atomics), 128M tile for full occupancy
  if (useBf16B)
    k_gemm7<<<dim3(4, NBLK_, 2), 256, 0, stream>>>(
        xfeat, Wlin, lin_ob_b, lin_sub_b, dout, pexp);
  else
    k_gemm5<<<dim3(4, NBLK_, 2), 256, 0, stream>>>(
        xfeat, lin_ob_w, lin_sub_w, lin_ob_b, lin_sub_b, dout, pexp);
  k_loss3<<<1, 1024, 0, stream>>>(dout, trip, idxbuf, pexp, dout);
}